// Round 1
// baseline (1303.100 us; speedup 1.0000x reference)
//
#include <hip/hip_runtime.h>
#include <math.h>

#define NN 100000
#define NE 1600000
#define D 128
#define DOUT 40

// component extract with compile-time index (folds under #pragma unroll)
#define C4(v, i) ((i) == 0 ? (v).x : (i) == 1 ? (v).y : (i) == 2 ? (v).z : (v).w)

// ---------------- CSR build ----------------
__global__ void count_kernel(const int* __restrict__ dst, int* __restrict__ cnt) {
  int e = blockIdx.x * 256 + threadIdx.x;
  if (e < NE) atomicAdd(&cnt[dst[e]], 1);
}

__global__ void scan1_kernel(const int* __restrict__ cnt, int* __restrict__ row_start,
                             int* __restrict__ bsums, float* __restrict__ inv_deg) {
  __shared__ int s[256];
  int t = threadIdx.x;
  int i = blockIdx.x * 256 + t;
  int c = (i < NN) ? cnt[i] : 0;
  if (i < NN) inv_deg[i] = 1.0f / (float)(c > 1 ? c : 1);
  s[t] = c;
  __syncthreads();
  for (int off = 1; off < 256; off <<= 1) {
    int v = (t >= off) ? s[t - off] : 0;
    __syncthreads();
    s[t] += v;
    __syncthreads();
  }
  if (i < NN) row_start[i] = s[t] - c;  // block-local exclusive
  if (t == 255) bsums[blockIdx.x] = s[255];
}

__global__ void scan2_kernel(int* __restrict__ bsums, int nb) {
  __shared__ int s[512];
  int t = threadIdx.x;
  int v = (t < nb) ? bsums[t] : 0;
  s[t] = v;
  __syncthreads();
  for (int off = 1; off < 512; off <<= 1) {
    int u = (t >= off) ? s[t - off] : 0;
    __syncthreads();
    s[t] += u;
    __syncthreads();
  }
  if (t < nb) bsums[t] = s[t] - v;  // exclusive
}

__global__ void scan3_kernel(int* __restrict__ row_start, const int* __restrict__ bsums,
                             int* __restrict__ cursor) {
  int i = blockIdx.x * 256 + threadIdx.x;
  if (i < NN) {
    int v = row_start[i] + bsums[blockIdx.x];
    row_start[i] = v;
    cursor[i] = v;
  }
  if (i == 0) row_start[NN] = NE;
}

__global__ void scatter_kernel(const int* __restrict__ src, const int* __restrict__ dst,
                               int* __restrict__ cursor, int* __restrict__ nbr) {
  int e = blockIdx.x * 256 + threadIdx.x;
  if (e < NE) {
    int d = dst[e];
    int p = atomicAdd(&cursor[d], 1);
    nbr[p] = src[e];
  }
}

// ---------------- mean aggregation (CSR, no atomics) ----------------
// 32 lanes per node, float4 per lane covers the 128-float row.
__global__ __launch_bounds__(256) void agg_kernel(const float* __restrict__ X,
                                                  float* __restrict__ out,
                                                  const int* __restrict__ row_start,
                                                  const int* __restrict__ nbr,
                                                  const float* __restrict__ inv_deg) {
  int g = blockIdx.x * 8 + (threadIdx.x >> 5);
  int lane = threadIdx.x & 31;
  if (g >= NN) return;
  int p0 = row_start[g];
  int p1 = row_start[g + 1];
  float4 acc = make_float4(0.f, 0.f, 0.f, 0.f);
  for (int p = p0; p < p1; ++p) {
    int s = nbr[p];
    float4 v = *(const float4*)(X + (size_t)s * D + lane * 4);
    acc.x += v.x; acc.y += v.y; acc.z += v.z; acc.w += v.w;
  }
  float id = inv_deg[g];
  acc.x *= id; acc.y *= id; acc.z *= id; acc.w *= id;
  *(float4*)(out + (size_t)g * D + lane * 4) = acc;
}

// ---------------- layer 0/1: out = relu(A@Wl^T + H@Wr^T + b) ----------------
// block = 256 thr (tr 0..15 x tc 0..15), tile = 64 rows x 128 cols, 4x8 acc/thread
__global__ __launch_bounds__(256) void sage_gemm128_kernel(
    const float* __restrict__ A, const float* __restrict__ H,
    const float* __restrict__ Wl, const float* __restrict__ Wr,
    const float* __restrict__ bias, float* __restrict__ out) {
  __shared__ float As[64][20];    // +4 pad keeps float4 align, breaks bank stride
  __shared__ float Hs[64][20];
  __shared__ float Wls[16][132];  // Wls[kk][j] = Wl[j][k0+kk]
  __shared__ float Wrs[16][132];

  int t = threadIdx.x;
  int tr = t >> 4, tc = t & 15;
  int r0 = blockIdx.x * 64;

  float acc[4][8];
#pragma unroll
  for (int u = 0; u < 4; ++u)
#pragma unroll
    for (int v = 0; v < 8; ++v) acc[u][v] = 0.f;

  for (int k0 = 0; k0 < D; k0 += 16) {
    // stage A/H tile
    {
      int row = t >> 2, c4 = t & 3;
      int gr = r0 + row;
      float4 a4, h4;
      if (gr < NN) {
        a4 = *(const float4*)(A + (size_t)gr * D + k0 + c4 * 4);
        h4 = *(const float4*)(H + (size_t)gr * D + k0 + c4 * 4);
      } else {
        a4 = make_float4(0.f, 0.f, 0.f, 0.f);
        h4 = a4;
      }
      *(float4*)&As[row][c4 * 4] = a4;
      *(float4*)&Hs[row][c4 * 4] = h4;
    }
    // stage weights transposed: 512 float4 per matrix, 2 per thread
#pragma unroll
    for (int q = 0; q < 2; ++q) {
      int lin = q * 256 + t;
      int j = lin >> 2, c4 = lin & 3;
      float4 wl4 = *(const float4*)(Wl + j * D + k0 + c4 * 4);
      float4 wr4 = *(const float4*)(Wr + j * D + k0 + c4 * 4);
      Wls[c4 * 4 + 0][j] = wl4.x; Wls[c4 * 4 + 1][j] = wl4.y;
      Wls[c4 * 4 + 2][j] = wl4.z; Wls[c4 * 4 + 3][j] = wl4.w;
      Wrs[c4 * 4 + 0][j] = wr4.x; Wrs[c4 * 4 + 1][j] = wr4.y;
      Wrs[c4 * 4 + 2][j] = wr4.z; Wrs[c4 * 4 + 3][j] = wr4.w;
    }
    __syncthreads();

#pragma unroll
    for (int kk4 = 0; kk4 < 4; ++kk4) {
      float4 aq[4], hq[4];
#pragma unroll
      for (int u = 0; u < 4; ++u) {
        aq[u] = *(const float4*)&As[tr * 4 + u][kk4 * 4];
        hq[u] = *(const float4*)&Hs[tr * 4 + u][kk4 * 4];
      }
#pragma unroll
      for (int kk = 0; kk < 4; ++kk) {
        int k = kk4 * 4 + kk;
        float4 wlA = *(const float4*)&Wls[k][tc * 8];
        float4 wlB = *(const float4*)&Wls[k][tc * 8 + 4];
        float4 wrA = *(const float4*)&Wrs[k][tc * 8];
        float4 wrB = *(const float4*)&Wrs[k][tc * 8 + 4];
#pragma unroll
        for (int u = 0; u < 4; ++u) {
          float a_ = C4(aq[u], kk);
          float h_ = C4(hq[u], kk);
          acc[u][0] += a_ * wlA.x + h_ * wrA.x;
          acc[u][1] += a_ * wlA.y + h_ * wrA.y;
          acc[u][2] += a_ * wlA.z + h_ * wrA.z;
          acc[u][3] += a_ * wlA.w + h_ * wrA.w;
          acc[u][4] += a_ * wlB.x + h_ * wrB.x;
          acc[u][5] += a_ * wlB.y + h_ * wrB.y;
          acc[u][6] += a_ * wlB.z + h_ * wrB.z;
          acc[u][7] += a_ * wlB.w + h_ * wrB.w;
        }
      }
    }
    __syncthreads();
  }

  float4 bA = *(const float4*)(bias + tc * 8);
  float4 bB = *(const float4*)(bias + tc * 8 + 4);
#pragma unroll
  for (int u = 0; u < 4; ++u) {
    int gr = r0 + tr * 4 + u;
    if (gr < NN) {
      float4 o0, o1;
      o0.x = fmaxf(acc[u][0] + bA.x, 0.f);
      o0.y = fmaxf(acc[u][1] + bA.y, 0.f);
      o0.z = fmaxf(acc[u][2] + bA.z, 0.f);
      o0.w = fmaxf(acc[u][3] + bA.w, 0.f);
      o1.x = fmaxf(acc[u][4] + bB.x, 0.f);
      o1.y = fmaxf(acc[u][5] + bB.y, 0.f);
      o1.z = fmaxf(acc[u][6] + bB.z, 0.f);
      o1.w = fmaxf(acc[u][7] + bB.w, 0.f);
      *(float4*)(out + (size_t)gr * D + tc * 8) = o0;
      *(float4*)(out + (size_t)gr * D + tc * 8 + 4) = o1;
    }
  }
}

// ---------------- layer 2: z = A@Wl2^T + H@Wr2^T + b2, out = log_softmax(z) ----------------
// one wave per row; lanes 0..39 own output columns
__global__ __launch_bounds__(256) void sage_out_kernel(
    const float* __restrict__ A, const float* __restrict__ H,
    const float* __restrict__ Wl, const float* __restrict__ Wr,
    const float* __restrict__ bias, float* __restrict__ out) {
  __shared__ float Wls[DOUT][129];  // pad 129 -> bank (j+k)%32, conflict-free
  __shared__ float Wrs[DOUT][129];
  int t = threadIdx.x;
  // stage weights: 40*128 = 1280 float4-loads per matrix / 4 = 5 iters
#pragma unroll
  for (int q = 0; q < 5; ++q) {
    int lin = q * 256 + t;  // 0..1279
    int j = lin >> 5;
    int c4 = lin & 31;
    float4 wl4 = *(const float4*)(Wl + j * D + c4 * 4);
    float4 wr4 = *(const float4*)(Wr + j * D + c4 * 4);
    Wls[j][c4 * 4 + 0] = wl4.x; Wls[j][c4 * 4 + 1] = wl4.y;
    Wls[j][c4 * 4 + 2] = wl4.z; Wls[j][c4 * 4 + 3] = wl4.w;
    Wrs[j][c4 * 4 + 0] = wr4.x; Wrs[j][c4 * 4 + 1] = wr4.y;
    Wrs[j][c4 * 4 + 2] = wr4.z; Wrs[j][c4 * 4 + 3] = wr4.w;
  }
  __syncthreads();

  int lane = t & 63;
  int j = lane;
  int jc = (j < DOUT) ? j : 0;
  float bj = (j < DOUT) ? bias[j] : 0.f;
  int wid = (blockIdx.x * 256 + t) >> 6;
  int nwaves = (gridDim.x * 256) >> 6;

  for (int r = wid; r < NN; r += nwaves) {
    const float* Ar = A + (size_t)r * D;
    const float* Hr = H + (size_t)r * D;
    float accv = 0.f;
#pragma unroll 4
    for (int k = 0; k < D; k += 4) {
      float4 a4 = *(const float4*)(Ar + k);  // same addr all lanes -> broadcast
      float4 h4 = *(const float4*)(Hr + k);
      accv += a4.x * Wls[jc][k + 0] + a4.y * Wls[jc][k + 1] +
              a4.z * Wls[jc][k + 2] + a4.w * Wls[jc][k + 3];
      accv += h4.x * Wrs[jc][k + 0] + h4.y * Wrs[jc][k + 1] +
              h4.z * Wrs[jc][k + 2] + h4.w * Wrs[jc][k + 3];
    }
    float z = accv + bj;
    float zm = (j < DOUT) ? z : -INFINITY;
#pragma unroll
    for (int off = 32; off > 0; off >>= 1) zm = fmaxf(zm, __shfl_xor(zm, off));
    float ex = (j < DOUT) ? expf(z - zm) : 0.f;
    float s = ex;
#pragma unroll
    for (int off = 32; off > 0; off >>= 1) s += __shfl_xor(s, off);
    float lse = zm + logf(s);
    if (j < DOUT) out[(size_t)r * DOUT + j] = z - lse;
  }
}

// ---------------- launch ----------------
extern "C" void kernel_launch(void* const* d_in, const int* in_sizes, int n_in,
                              void* d_out, int out_size, void* d_ws, size_t ws_size,
                              hipStream_t stream) {
  const float* x   = (const float*)d_in[0];
  const int* esrc  = (const int*)d_in[1];
  const int* edst  = (const int*)d_in[2];
  const float* Wl0 = (const float*)d_in[3];
  const float* Wr0 = (const float*)d_in[4];
  const float* b0  = (const float*)d_in[5];
  const float* Wl1 = (const float*)d_in[6];
  const float* Wr1 = (const float*)d_in[7];
  const float* b1  = (const float*)d_in[8];
  const float* Wl2 = (const float*)d_in[9];
  const float* Wr2 = (const float*)d_in[10];
  const float* b2  = (const float*)d_in[11];
  float* out = (float*)d_out;

  char* ws = (char*)d_ws;
  size_t off = 0;
  auto carve = [&](size_t bytes) -> char* {
    char* p = ws + off;
    off = (off + bytes + 255) & ~(size_t)255;
    return p;
  };
  int* cnt        = (int*)carve((size_t)NN * 4);        // reused as cursor
  int* row_start  = (int*)carve((size_t)(NN + 1) * 4);
  int* nbr        = (int*)carve((size_t)NE * 4);
  float* inv_deg  = (float*)carve((size_t)NN * 4);
  int* bsums      = (int*)carve(512 * 4);
  float* bufA     = (float*)carve((size_t)NN * D * 4);
  float* bufB     = (float*)carve((size_t)NN * D * 4);
  float* bufC     = (float*)carve((size_t)NN * D * 4);
  if (off > ws_size) return;  // workspace too small -> visible failure

  const int GRID_E = (NE + 255) / 256;
  const int NB = (NN + 255) / 256;          // 391 <= 512
  const int GRID_AGG = (NN + 7) / 8;
  const int GRID_GEMM = (NN + 63) / 64;

  // CSR build
  hipMemsetAsync(cnt, 0, (size_t)NN * 4, stream);
  count_kernel<<<GRID_E, 256, 0, stream>>>(edst, cnt);
  scan1_kernel<<<NB, 256, 0, stream>>>(cnt, row_start, bsums, inv_deg);
  scan2_kernel<<<1, 512, 0, stream>>>(bsums, NB);
  scan3_kernel<<<NB, 256, 0, stream>>>(row_start, bsums, cnt /*cursor*/);
  scatter_kernel<<<GRID_E, 256, 0, stream>>>(esrc, edst, cnt /*cursor*/, nbr);

  // layer 0
  agg_kernel<<<GRID_AGG, 256, 0, stream>>>(x, bufA, row_start, nbr, inv_deg);
  sage_gemm128_kernel<<<GRID_GEMM, 256, 0, stream>>>(bufA, x, Wl0, Wr0, b0, bufB);
  // layer 1
  agg_kernel<<<GRID_AGG, 256, 0, stream>>>(bufB, bufA, row_start, nbr, inv_deg);
  sage_gemm128_kernel<<<GRID_GEMM, 256, 0, stream>>>(bufA, bufB, Wl1, Wr1, b1, bufC);
  // layer 2 + log_softmax
  agg_kernel<<<GRID_AGG, 256, 0, stream>>>(bufC, bufA, row_start, nbr, inv_deg);
  sage_out_kernel<<<1024, 256, 0, stream>>>(bufA, bufC, Wl2, Wr2, b2, out);
}

// Round 2
// 921.442 us; speedup vs baseline: 1.4142x; 1.4142x over previous
//
#include <hip/hip_runtime.h>
#include <math.h>

#define NN 100000
#define NE 1600000
#define D 128
#define DOUT 40

typedef __attribute__((ext_vector_type(8))) short short8v;   // 8 bf16 (4 VGPR)
typedef __attribute__((ext_vector_type(4))) float f32x4;

// f32 -> bf16 (rtne) bit pattern
__device__ __forceinline__ unsigned short f2bf(float f) {
  unsigned u = __float_as_uint(f);
  unsigned r = (u + 0x7fffu + ((u >> 16) & 1u)) >> 16;
  return (unsigned short)r;
}
__device__ __forceinline__ float bf2f(unsigned short s) {
  return __uint_as_float(((unsigned)s) << 16);
}

// ---------------- CSR build ----------------
__global__ void count_kernel(const int* __restrict__ dst, int* __restrict__ cnt) {
  int e = blockIdx.x * 256 + threadIdx.x;
  if (e < NE) atomicAdd(&cnt[dst[e]], 1);
}

__global__ void scan1_kernel(const int* __restrict__ cnt, int* __restrict__ row_start,
                             int* __restrict__ bsums, float* __restrict__ inv_deg) {
  __shared__ int s[256];
  int t = threadIdx.x;
  int i = blockIdx.x * 256 + t;
  int c = (i < NN) ? cnt[i] : 0;
  if (i < NN) inv_deg[i] = 1.0f / (float)(c > 1 ? c : 1);
  s[t] = c;
  __syncthreads();
  for (int off = 1; off < 256; off <<= 1) {
    int v = (t >= off) ? s[t - off] : 0;
    __syncthreads();
    s[t] += v;
    __syncthreads();
  }
  if (i < NN) row_start[i] = s[t] - c;
  if (t == 255) bsums[blockIdx.x] = s[255];
}

__global__ void scan2_kernel(int* __restrict__ bsums, int nb) {
  __shared__ int s[512];
  int t = threadIdx.x;
  int v = (t < nb) ? bsums[t] : 0;
  s[t] = v;
  __syncthreads();
  for (int off = 1; off < 512; off <<= 1) {
    int u = (t >= off) ? s[t - off] : 0;
    __syncthreads();
    s[t] += u;
    __syncthreads();
  }
  if (t < nb) bsums[t] = s[t] - v;
}

__global__ void scan3_kernel(int* __restrict__ row_start, const int* __restrict__ bsums,
                             int* __restrict__ cursor) {
  int i = blockIdx.x * 256 + threadIdx.x;
  if (i < NN) {
    int v = row_start[i] + bsums[blockIdx.x];
    row_start[i] = v;
    cursor[i] = v;
  }
  if (i == 0) row_start[NN] = NE;
}

__global__ void scatter_kernel(const int* __restrict__ src, const int* __restrict__ dst,
                               int* __restrict__ cursor, int* __restrict__ nbr) {
  int e = blockIdx.x * 256 + threadIdx.x;
  if (e < NE) {
    int d = dst[e];
    int p = atomicAdd(&cursor[d], 1);
    nbr[p] = src[e];
  }
}

// ---------------- mean aggregation (CSR, no atomics) ----------------
__global__ __launch_bounds__(256) void agg_kernel(const float* __restrict__ X,
                                                  float* __restrict__ out,
                                                  const int* __restrict__ row_start,
                                                  const int* __restrict__ nbr,
                                                  const float* __restrict__ inv_deg) {
  int g = blockIdx.x * 8 + (threadIdx.x >> 5);
  int lane = threadIdx.x & 31;
  if (g >= NN) return;
  int p0 = row_start[g];
  int p1 = row_start[g + 1];
  float4 acc = make_float4(0.f, 0.f, 0.f, 0.f);
  for (int p = p0; p < p1; ++p) {
    int s = nbr[p];
    float4 v = *(const float4*)(X + (size_t)s * D + lane * 4);
    acc.x += v.x; acc.y += v.y; acc.z += v.z; acc.w += v.w;
  }
  float id = inv_deg[g];
  acc.x *= id; acc.y *= id; acc.z *= id; acc.w *= id;
  *(float4*)(out + (size_t)g * D + lane * 4) = acc;
}

// ---------------- weight prep: fragment-ordered hi/lo bf16 planes ----------------
// Bcat[k][c] = (k<128 ? Wl[c][k] : Wr[c][k-128]),   k in [0,256), c in [0,128)
// Frag layout: plane[((s*8 + n)*64 + l)] = 8 bf16: Bcat[s*32 + (l>>4)*8 + i][n*16 + (l&15)]
__global__ __launch_bounds__(64) void prep_w_kernel(const float* __restrict__ Wl,
                                                    const float* __restrict__ Wr,
                                                    short8v* __restrict__ hi,
                                                    short8v* __restrict__ lo) {
  int s = blockIdx.x >> 3;
  int n = blockIdx.x & 7;
  int l = threadIdx.x;
  int k0 = s * 32 + (l >> 4) * 8;   // multiple of 8; 8 consecutive k on one side
  int c = n * 16 + (l & 15);
  const float* W = (k0 < 128) ? Wl : Wr;
  int kb = (k0 < 128) ? k0 : k0 - 128;
  short hv[8], lv[8];
#pragma unroll
  for (int i = 0; i < 8; ++i) {
    float v = W[c * 128 + kb + i];
    unsigned short h = f2bf(v);
    hv[i] = (short)h;
    lv[i] = (short)f2bf(v - bf2f(h));
  }
  int idx = blockIdx.x * 64 + l;
  hi[idx] = (short8v){hv[0], hv[1], hv[2], hv[3], hv[4], hv[5], hv[6], hv[7]};
  lo[idx] = (short8v){lv[0], lv[1], lv[2], lv[3], lv[4], lv[5], lv[6], lv[7]};
}

// ---------------- layers 0/1: out = relu([A|H] @ Bcat + b), bf16x3 MFMA ----------------
// block = 256 thr = 4 waves; tile 128 rows x 128 cols; wave: 32 rows (2 row-frags) x 8 col-frags
__global__ __launch_bounds__(256) void mfma_gemm_kernel(
    const float* __restrict__ A, const float* __restrict__ H,
    const short8v* __restrict__ Bhi, const short8v* __restrict__ Blo,
    const float* __restrict__ bias, float* __restrict__ out) {
  __shared__ float As[128][36];  // stride 36 floats (144B): bank-even, 16B-aligned

  int t = threadIdx.x;
  int w = t >> 6, l = t & 63;
  int R0 = blockIdx.x * 128;

  f32x4 acc[2][8];
#pragma unroll
  for (int m = 0; m < 2; ++m)
#pragma unroll
    for (int n = 0; n < 8; ++n) acc[m][n] = (f32x4){0.f, 0.f, 0.f, 0.f};

  int c4 = t & 7;       // staging col (float4)
  int rb = t >> 3;      // staging row base 0..31
  int lc = l & 15;      // frag col / row-in-stripe
  int lg = l >> 4;      // frag k-group

  for (int s = 0; s < 8; ++s) {
    const float* src = (s < 4) ? A : H;
    int koff = (s & 3) * 32;
    // stage 128 rows x 32 cols f32
#pragma unroll
    for (int q = 0; q < 4; ++q) {
      int row = rb + 32 * q;
      int gr = R0 + row;
      float4 v = make_float4(0.f, 0.f, 0.f, 0.f);
      if (gr < NN) v = *(const float4*)(src + (size_t)gr * D + koff + c4 * 4);
      *(float4*)&As[row][c4 * 4] = v;
    }
    __syncthreads();

    // B frags (global, L2-resident, coalesced 16B/lane)
    short8v bh[8], bl[8];
#pragma unroll
    for (int n = 0; n < 8; ++n) {
      int idx = (s * 8 + n) * 64 + l;
      bh[n] = Bhi[idx];
      bl[n] = Blo[idx];
    }

    // A frags from LDS, split hi/lo in registers
    short8v ah[2], al[2];
#pragma unroll
    for (int m = 0; m < 2; ++m) {
      int r = w * 32 + m * 16 + lc;
      const float* pr = &As[r][lg * 8];
      float4 v0 = *(const float4*)pr;
      float4 v1 = *(const float4*)(pr + 4);
      float vv[8] = {v0.x, v0.y, v0.z, v0.w, v1.x, v1.y, v1.z, v1.w};
      short hv[8], lv[8];
#pragma unroll
      for (int i = 0; i < 8; ++i) {
        unsigned short h = f2bf(vv[i]);
        hv[i] = (short)h;
        lv[i] = (short)f2bf(vv[i] - bf2f(h));
      }
      ah[m] = (short8v){hv[0], hv[1], hv[2], hv[3], hv[4], hv[5], hv[6], hv[7]};
      al[m] = (short8v){lv[0], lv[1], lv[2], lv[3], lv[4], lv[5], lv[6], lv[7]};
    }

#pragma unroll
    for (int n = 0; n < 8; ++n)
#pragma unroll
      for (int m = 0; m < 2; ++m) {
        acc[m][n] = __builtin_amdgcn_mfma_f32_16x16x32_bf16(ah[m], bh[n], acc[m][n], 0, 0, 0);
        acc[m][n] = __builtin_amdgcn_mfma_f32_16x16x32_bf16(al[m], bh[n], acc[m][n], 0, 0, 0);
        acc[m][n] = __builtin_amdgcn_mfma_f32_16x16x32_bf16(ah[m], bl[n], acc[m][n], 0, 0, 0);
      }
    __syncthreads();
  }

  // epilogue: bias + relu; C/D layout col=l&15, row=(l>>4)*4+j
  float bcol[8];
#pragma unroll
  for (int n = 0; n < 8; ++n) bcol[n] = bias[n * 16 + lc];
#pragma unroll
  for (int m = 0; m < 2; ++m)
#pragma unroll
    for (int n = 0; n < 8; ++n) {
      int col = n * 16 + lc;
#pragma unroll
      for (int j = 0; j < 4; ++j) {
        int gr = R0 + w * 32 + m * 16 + lg * 4 + j;
        if (gr < NN) out[(size_t)gr * D + col] = fmaxf(acc[m][n][j] + bcol[n], 0.f);
      }
    }
}

// ---------------- layer 2: z = A@Wl2^T + H@Wr2^T + b2, out = log_softmax(z) ----------------
__global__ __launch_bounds__(256) void sage_out_kernel(
    const float* __restrict__ A, const float* __restrict__ H,
    const float* __restrict__ Wl, const float* __restrict__ Wr,
    const float* __restrict__ bias, float* __restrict__ out) {
  __shared__ float Wls[DOUT][129];
  __shared__ float Wrs[DOUT][129];
  int t = threadIdx.x;
#pragma unroll
  for (int q = 0; q < 5; ++q) {
    int lin = q * 256 + t;  // 0..1279
    int j = lin >> 5;
    int c4 = lin & 31;
    float4 wl4 = *(const float4*)(Wl + j * D + c4 * 4);
    float4 wr4 = *(const float4*)(Wr + j * D + c4 * 4);
    Wls[j][c4 * 4 + 0] = wl4.x; Wls[j][c4 * 4 + 1] = wl4.y;
    Wls[j][c4 * 4 + 2] = wl4.z; Wls[j][c4 * 4 + 3] = wl4.w;
    Wrs[j][c4 * 4 + 0] = wr4.x; Wrs[j][c4 * 4 + 1] = wr4.y;
    Wrs[j][c4 * 4 + 2] = wr4.z; Wrs[j][c4 * 4 + 3] = wr4.w;
  }
  __syncthreads();

  int lane = t & 63;
  int j = lane;
  int jc = (j < DOUT) ? j : 0;
  float bj = (j < DOUT) ? bias[j] : 0.f;
  int wid = (blockIdx.x * 256 + t) >> 6;
  int nwaves = (gridDim.x * 256) >> 6;

  for (int r = wid; r < NN; r += nwaves) {
    const float* Ar = A + (size_t)r * D;
    const float* Hr = H + (size_t)r * D;
    float accv = 0.f;
#pragma unroll 4
    for (int k = 0; k < D; k += 4) {
      float4 a4 = *(const float4*)(Ar + k);
      float4 h4 = *(const float4*)(Hr + k);
      accv += a4.x * Wls[jc][k + 0] + a4.y * Wls[jc][k + 1] +
              a4.z * Wls[jc][k + 2] + a4.w * Wls[jc][k + 3];
      accv += h4.x * Wrs[jc][k + 0] + h4.y * Wrs[jc][k + 1] +
              h4.z * Wrs[jc][k + 2] + h4.w * Wrs[jc][k + 3];
    }
    float z = accv + bj;
    float zm = (j < DOUT) ? z : -INFINITY;
#pragma unroll
    for (int off = 32; off > 0; off >>= 1) zm = fmaxf(zm, __shfl_xor(zm, off));
    float ex = (j < DOUT) ? expf(z - zm) : 0.f;
    float s = ex;
#pragma unroll
    for (int off = 32; off > 0; off >>= 1) s += __shfl_xor(s, off);
    float lse = zm + logf(s);
    if (j < DOUT) out[(size_t)r * DOUT + j] = z - lse;
  }
}

// ---------------- launch ----------------
extern "C" void kernel_launch(void* const* d_in, const int* in_sizes, int n_in,
                              void* d_out, int out_size, void* d_ws, size_t ws_size,
                              hipStream_t stream) {
  const float* x   = (const float*)d_in[0];
  const int* esrc  = (const int*)d_in[1];
  const int* edst  = (const int*)d_in[2];
  const float* Wl0 = (const float*)d_in[3];
  const float* Wr0 = (const float*)d_in[4];
  const float* b0  = (const float*)d_in[5];
  const float* Wl1 = (const float*)d_in[6];
  const float* Wr1 = (const float*)d_in[7];
  const float* b1  = (const float*)d_in[8];
  const float* Wl2 = (const float*)d_in[9];
  const float* Wr2 = (const float*)d_in[10];
  const float* b2  = (const float*)d_in[11];
  float* out = (float*)d_out;

  char* ws = (char*)d_ws;
  size_t off = 0;
  auto carve = [&](size_t bytes) -> char* {
    char* p = ws + off;
    off = (off + bytes + 255) & ~(size_t)255;
    return p;
  };
  int* cnt        = (int*)carve((size_t)NN * 4);        // reused as cursor
  int* row_start  = (int*)carve((size_t)(NN + 1) * 4);
  int* nbr        = (int*)carve((size_t)NE * 4);
  float* inv_deg  = (float*)carve((size_t)NN * 4);
  int* bsums      = (int*)carve(512 * 4);
  short8v* B0hi   = (short8v*)carve((size_t)64 * 64 * 16);
  short8v* B0lo   = (short8v*)carve((size_t)64 * 64 * 16);
  short8v* B1hi   = (short8v*)carve((size_t)64 * 64 * 16);
  short8v* B1lo   = (short8v*)carve((size_t)64 * 64 * 16);
  float* bufA     = (float*)carve((size_t)NN * D * 4);
  float* bufB     = (float*)carve((size_t)NN * D * 4);
  float* bufC     = (float*)carve((size_t)NN * D * 4);
  if (off > ws_size) return;

  const int GRID_E = (NE + 255) / 256;
  const int NB = (NN + 255) / 256;
  const int GRID_AGG = (NN + 7) / 8;
  const int GRID_GEMM = (NN + 127) / 128;

  // CSR build
  hipMemsetAsync(cnt, 0, (size_t)NN * 4, stream);
  count_kernel<<<GRID_E, 256, 0, stream>>>(edst, cnt);
  scan1_kernel<<<NB, 256, 0, stream>>>(cnt, row_start, bsums, inv_deg);
  scan2_kernel<<<1, 512, 0, stream>>>(bsums, NB);
  scan3_kernel<<<NB, 256, 0, stream>>>(row_start, bsums, cnt /*cursor*/);
  scatter_kernel<<<GRID_E, 256, 0, stream>>>(esrc, edst, cnt /*cursor*/, nbr);

  // weight prep (fragment-ordered hi/lo planes)
  prep_w_kernel<<<64, 64, 0, stream>>>(Wl0, Wr0, B0hi, B0lo);
  prep_w_kernel<<<64, 64, 0, stream>>>(Wl1, Wr1, B1hi, B1lo);

  // layer 0
  agg_kernel<<<GRID_AGG, 256, 0, stream>>>(x, bufA, row_start, nbr, inv_deg);
  mfma_gemm_kernel<<<GRID_GEMM, 256, 0, stream>>>(bufA, x, B0hi, B0lo, b0, bufB);
  // layer 1
  agg_kernel<<<GRID_AGG, 256, 0, stream>>>(bufB, bufA, row_start, nbr, inv_deg);
  mfma_gemm_kernel<<<GRID_GEMM, 256, 0, stream>>>(bufA, bufB, B1hi, B1lo, b1, bufC);
  // layer 2 + log_softmax
  agg_kernel<<<GRID_AGG, 256, 0, stream>>>(bufC, bufA, row_start, nbr, inv_deg);
  sage_out_kernel<<<1024, 256, 0, stream>>>(bufA, bufC, Wl2, Wr2, b2, out);
}

// Round 3
// 716.279 us; speedup vs baseline: 1.8193x; 1.2864x over previous
//
#include <hip/hip_runtime.h>
#include <math.h>

#define NN 100000
#define NE 1600000
#define D 128
#define DOUT 40

typedef __attribute__((ext_vector_type(8))) short short8v;   // 8 bf16 (4 VGPR)
typedef __attribute__((ext_vector_type(4))) float f32x4;

// f32 -> bf16 (rtne) bit pattern
__device__ __forceinline__ unsigned short f2bf(float f) {
  unsigned u = __float_as_uint(f);
  unsigned r = (u + 0x7fffu + ((u >> 16) & 1u)) >> 16;
  return (unsigned short)r;
}
__device__ __forceinline__ float bf2f(unsigned short s) {
  return __uint_as_float(((unsigned)s) << 16);
}

// ---------------- CSR build ----------------
__global__ void count_kernel(const int* __restrict__ dst, int* __restrict__ cnt) {
  int e = blockIdx.x * 256 + threadIdx.x;
  if (e < NE) atomicAdd(&cnt[dst[e]], 1);
}

__global__ void scan1_kernel(const int* __restrict__ cnt, int* __restrict__ row_start,
                             int* __restrict__ bsums, float* __restrict__ inv_deg) {
  __shared__ int s[256];
  int t = threadIdx.x;
  int i = blockIdx.x * 256 + t;
  int c = (i < NN) ? cnt[i] : 0;
  if (i < NN) inv_deg[i] = 1.0f / (float)(c > 1 ? c : 1);
  s[t] = c;
  __syncthreads();
  for (int off = 1; off < 256; off <<= 1) {
    int v = (t >= off) ? s[t - off] : 0;
    __syncthreads();
    s[t] += v;
    __syncthreads();
  }
  if (i < NN) row_start[i] = s[t] - c;
  if (t == 255) bsums[blockIdx.x] = s[255];
}

__global__ void scan2_kernel(int* __restrict__ bsums, int nb) {
  __shared__ int s[512];
  int t = threadIdx.x;
  int v = (t < nb) ? bsums[t] : 0;
  s[t] = v;
  __syncthreads();
  for (int off = 1; off < 512; off <<= 1) {
    int u = (t >= off) ? s[t - off] : 0;
    __syncthreads();
    s[t] += u;
    __syncthreads();
  }
  if (t < nb) bsums[t] = s[t] - v;
}

__global__ void scan3_kernel(int* __restrict__ row_start, const int* __restrict__ bsums,
                             int* __restrict__ cursor) {
  int i = blockIdx.x * 256 + threadIdx.x;
  if (i < NN) {
    int v = row_start[i] + bsums[blockIdx.x];
    row_start[i] = v;
    cursor[i] = v;
  }
  if (i == 0) row_start[NN] = NE;
}

__global__ void scatter_kernel(const int* __restrict__ src, const int* __restrict__ dst,
                               int* __restrict__ cursor, int* __restrict__ nbr) {
  int e = blockIdx.x * 256 + threadIdx.x;
  if (e < NE) {
    int d = dst[e];
    int p = atomicAdd(&cursor[d], 1);
    nbr[p] = src[e];
  }
}

// ---------------- mean aggregation (CSR, no atomics) ----------------
__global__ __launch_bounds__(256) void agg_kernel(const float* __restrict__ X,
                                                  float* __restrict__ out,
                                                  const int* __restrict__ row_start,
                                                  const int* __restrict__ nbr,
                                                  const float* __restrict__ inv_deg) {
  int g = blockIdx.x * 8 + (threadIdx.x >> 5);
  int lane = threadIdx.x & 31;
  if (g >= NN) return;
  int p0 = row_start[g];
  int p1 = row_start[g + 1];
  float4 acc = make_float4(0.f, 0.f, 0.f, 0.f);
  for (int p = p0; p < p1; ++p) {
    int s = nbr[p];
    float4 v = *(const float4*)(X + (size_t)s * D + lane * 4);
    acc.x += v.x; acc.y += v.y; acc.z += v.z; acc.w += v.w;
  }
  float id = inv_deg[g];
  acc.x *= id; acc.y *= id; acc.z *= id; acc.w *= id;
  *(float4*)(out + (size_t)g * D + lane * 4) = acc;
}

// ---------------- weight prep: fragment-ordered hi/lo bf16 planes (layers 0/1) ----------------
// Bcat[k][c] = (k<128 ? Wl[c][k] : Wr[c][k-128]),   k in [0,256), c in [0,128)
// plane[((s*8 + n)*64 + l)] = 8 bf16: Bcat[s*32 + (l>>4)*8 + i][n*16 + (l&15)]
__global__ __launch_bounds__(64) void prep_w_kernel(const float* __restrict__ Wl,
                                                    const float* __restrict__ Wr,
                                                    short8v* __restrict__ hi,
                                                    short8v* __restrict__ lo) {
  int s = blockIdx.x >> 3;
  int n = blockIdx.x & 7;
  int l = threadIdx.x;
  int k0 = s * 32 + (l >> 4) * 8;
  int c = n * 16 + (l & 15);
  const float* W = (k0 < 128) ? Wl : Wr;
  int kb = (k0 < 128) ? k0 : k0 - 128;
  short hv[8], lv[8];
#pragma unroll
  for (int i = 0; i < 8; ++i) {
    float v = W[c * 128 + kb + i];
    unsigned short h = f2bf(v);
    hv[i] = (short)h;
    lv[i] = (short)f2bf(v - bf2f(h));
  }
  int idx = blockIdx.x * 64 + l;
  hi[idx] = (short8v){hv[0], hv[1], hv[2], hv[3], hv[4], hv[5], hv[6], hv[7]};
  lo[idx] = (short8v){lv[0], lv[1], lv[2], lv[3], lv[4], lv[5], lv[6], lv[7]};
}

// ---------------- weight prep for layer 2: N padded 40 -> 48 (3 frags) ----------------
// plane[((s*3 + n)*64 + l)] = 8 bf16: Bcat2[s*32 + (l>>4)*8 + i][n*16 + (l&15)], 0 if col>=40
__global__ __launch_bounds__(64) void prep_w2_kernel(const float* __restrict__ Wl,
                                                     const float* __restrict__ Wr,
                                                     short8v* __restrict__ hi,
                                                     short8v* __restrict__ lo) {
  int s = blockIdx.x / 3;
  int n = blockIdx.x % 3;
  int l = threadIdx.x;
  int k0 = s * 32 + (l >> 4) * 8;
  int c = n * 16 + (l & 15);
  const float* W = (k0 < 128) ? Wl : Wr;
  int kb = (k0 < 128) ? k0 : k0 - 128;
  short hv[8], lv[8];
#pragma unroll
  for (int i = 0; i < 8; ++i) {
    float v = (c < DOUT) ? W[c * 128 + kb + i] : 0.f;
    unsigned short h = f2bf(v);
    hv[i] = (short)h;
    lv[i] = (short)f2bf(v - bf2f(h));
  }
  int idx = blockIdx.x * 64 + l;
  hi[idx] = (short8v){hv[0], hv[1], hv[2], hv[3], hv[4], hv[5], hv[6], hv[7]};
  lo[idx] = (short8v){lv[0], lv[1], lv[2], lv[3], lv[4], lv[5], lv[6], lv[7]};
}

// ---------------- layers 0/1: out = relu([A|H] @ Bcat + b), bf16x3 MFMA ----------------
__global__ __launch_bounds__(256) void mfma_gemm_kernel(
    const float* __restrict__ A, const float* __restrict__ H,
    const short8v* __restrict__ Bhi, const short8v* __restrict__ Blo,
    const float* __restrict__ bias, float* __restrict__ out) {
  __shared__ float As[128][36];

  int t = threadIdx.x;
  int w = t >> 6, l = t & 63;
  int R0 = blockIdx.x * 128;

  f32x4 acc[2][8];
#pragma unroll
  for (int m = 0; m < 2; ++m)
#pragma unroll
    for (int n = 0; n < 8; ++n) acc[m][n] = (f32x4){0.f, 0.f, 0.f, 0.f};

  int c4 = t & 7;
  int rb = t >> 3;
  int lc = l & 15;
  int lg = l >> 4;

  for (int s = 0; s < 8; ++s) {
    const float* src = (s < 4) ? A : H;
    int koff = (s & 3) * 32;
#pragma unroll
    for (int q = 0; q < 4; ++q) {
      int row = rb + 32 * q;
      int gr = R0 + row;
      float4 v = make_float4(0.f, 0.f, 0.f, 0.f);
      if (gr < NN) v = *(const float4*)(src + (size_t)gr * D + koff + c4 * 4);
      *(float4*)&As[row][c4 * 4] = v;
    }
    __syncthreads();

    short8v bh[8], bl[8];
#pragma unroll
    for (int n = 0; n < 8; ++n) {
      int idx = (s * 8 + n) * 64 + l;
      bh[n] = Bhi[idx];
      bl[n] = Blo[idx];
    }

    short8v ah[2], al[2];
#pragma unroll
    for (int m = 0; m < 2; ++m) {
      int r = w * 32 + m * 16 + lc;
      const float* pr = &As[r][lg * 8];
      float4 v0 = *(const float4*)pr;
      float4 v1 = *(const float4*)(pr + 4);
      float vv[8] = {v0.x, v0.y, v0.z, v0.w, v1.x, v1.y, v1.z, v1.w};
      short hv[8], lv[8];
#pragma unroll
      for (int i = 0; i < 8; ++i) {
        unsigned short h = f2bf(vv[i]);
        hv[i] = (short)h;
        lv[i] = (short)f2bf(vv[i] - bf2f(h));
      }
      ah[m] = (short8v){hv[0], hv[1], hv[2], hv[3], hv[4], hv[5], hv[6], hv[7]};
      al[m] = (short8v){lv[0], lv[1], lv[2], lv[3], lv[4], lv[5], lv[6], lv[7]};
    }

#pragma unroll
    for (int n = 0; n < 8; ++n)
#pragma unroll
      for (int m = 0; m < 2; ++m) {
        acc[m][n] = __builtin_amdgcn_mfma_f32_16x16x32_bf16(ah[m], bh[n], acc[m][n], 0, 0, 0);
        acc[m][n] = __builtin_amdgcn_mfma_f32_16x16x32_bf16(al[m], bh[n], acc[m][n], 0, 0, 0);
        acc[m][n] = __builtin_amdgcn_mfma_f32_16x16x32_bf16(ah[m], bl[n], acc[m][n], 0, 0, 0);
      }
    __syncthreads();
  }

  float bcol[8];
#pragma unroll
  for (int n = 0; n < 8; ++n) bcol[n] = bias[n * 16 + lc];
#pragma unroll
  for (int m = 0; m < 2; ++m)
#pragma unroll
    for (int n = 0; n < 8; ++n) {
      int col = n * 16 + lc;
#pragma unroll
      for (int j = 0; j < 4; ++j) {
        int gr = R0 + w * 32 + m * 16 + lg * 4 + j;
        if (gr < NN) out[(size_t)gr * D + col] = fmaxf(acc[m][n][j] + bcol[n], 0.f);
      }
    }
}

// ---------------- layer 2: z = [A|H] @ Bcat2 + b2, out = log_softmax(z), MFMA ----------------
// tile 128 rows x 48 cols (40 used); per wave 32 rows x 48 cols; fused row softmax via shfl
__global__ __launch_bounds__(256) void mfma_out_kernel(
    const float* __restrict__ A, const float* __restrict__ H,
    const short8v* __restrict__ Bhi, const short8v* __restrict__ Blo,
    const float* __restrict__ bias, float* __restrict__ out) {
  __shared__ float As[128][36];

  int t = threadIdx.x;
  int w = t >> 6, l = t & 63;
  int R0 = blockIdx.x * 128;

  f32x4 acc[2][3];
#pragma unroll
  for (int m = 0; m < 2; ++m)
#pragma unroll
    for (int n = 0; n < 3; ++n) acc[m][n] = (f32x4){0.f, 0.f, 0.f, 0.f};

  int c4 = t & 7;
  int rb = t >> 3;
  int lc = l & 15;
  int lg = l >> 4;

  for (int s = 0; s < 8; ++s) {
    const float* src = (s < 4) ? A : H;
    int koff = (s & 3) * 32;
#pragma unroll
    for (int q = 0; q < 4; ++q) {
      int row = rb + 32 * q;
      int gr = R0 + row;
      float4 v = make_float4(0.f, 0.f, 0.f, 0.f);
      if (gr < NN) v = *(const float4*)(src + (size_t)gr * D + koff + c4 * 4);
      *(float4*)&As[row][c4 * 4] = v;
    }
    __syncthreads();

    short8v bh[3], bl[3];
#pragma unroll
    for (int n = 0; n < 3; ++n) {
      int idx = (s * 3 + n) * 64 + l;
      bh[n] = Bhi[idx];
      bl[n] = Blo[idx];
    }

    short8v ah[2], al[2];
#pragma unroll
    for (int m = 0; m < 2; ++m) {
      int r = w * 32 + m * 16 + lc;
      const float* pr = &As[r][lg * 8];
      float4 v0 = *(const float4*)pr;
      float4 v1 = *(const float4*)(pr + 4);
      float vv[8] = {v0.x, v0.y, v0.z, v0.w, v1.x, v1.y, v1.z, v1.w};
      short hv[8], lv[8];
#pragma unroll
      for (int i = 0; i < 8; ++i) {
        unsigned short h = f2bf(vv[i]);
        hv[i] = (short)h;
        lv[i] = (short)f2bf(vv[i] - bf2f(h));
      }
      ah[m] = (short8v){hv[0], hv[1], hv[2], hv[3], hv[4], hv[5], hv[6], hv[7]};
      al[m] = (short8v){lv[0], lv[1], lv[2], lv[3], lv[4], lv[5], lv[6], lv[7]};
    }

#pragma unroll
    for (int n = 0; n < 3; ++n)
#pragma unroll
      for (int m = 0; m < 2; ++m) {
        acc[m][n] = __builtin_amdgcn_mfma_f32_16x16x32_bf16(ah[m], bh[n], acc[m][n], 0, 0, 0);
        acc[m][n] = __builtin_amdgcn_mfma_f32_16x16x32_bf16(al[m], bh[n], acc[m][n], 0, 0, 0);
        acc[m][n] = __builtin_amdgcn_mfma_f32_16x16x32_bf16(ah[m], bl[n], acc[m][n], 0, 0, 0);
      }
    __syncthreads();
  }

  // epilogue: bias + log_softmax per row, row lives in one 16-lane group (3 vals/lane)
  float bcol[3];
#pragma unroll
  for (int n = 0; n < 3; ++n) {
    int col = n * 16 + lc;
    bcol[n] = (col < DOUT) ? bias[col] : 0.f;
  }
#pragma unroll
  for (int m = 0; m < 2; ++m)
#pragma unroll
    for (int j = 0; j < 4; ++j) {
      int r = R0 + w * 32 + m * 16 + lg * 4 + j;
      float z[3];
      float zm = -INFINITY;
#pragma unroll
      for (int n = 0; n < 3; ++n) {
        int col = n * 16 + lc;
        z[n] = acc[m][n][j] + bcol[n];
        if (col < DOUT) zm = fmaxf(zm, z[n]);
      }
#pragma unroll
      for (int off = 1; off < 16; off <<= 1) zm = fmaxf(zm, __shfl_xor(zm, off));
      float ssum = 0.f;
#pragma unroll
      for (int n = 0; n < 3; ++n) {
        int col = n * 16 + lc;
        if (col < DOUT) ssum += expf(z[n] - zm);
      }
#pragma unroll
      for (int off = 1; off < 16; off <<= 1) ssum += __shfl_xor(ssum, off);
      float lse = zm + logf(ssum);
      if (r < NN) {
#pragma unroll
        for (int n = 0; n < 3; ++n) {
          int col = n * 16 + lc;
          if (col < DOUT) out[(size_t)r * DOUT + col] = z[n] - lse;
        }
      }
    }
}

// ---------------- launch ----------------
extern "C" void kernel_launch(void* const* d_in, const int* in_sizes, int n_in,
                              void* d_out, int out_size, void* d_ws, size_t ws_size,
                              hipStream_t stream) {
  const float* x   = (const float*)d_in[0];
  const int* esrc  = (const int*)d_in[1];
  const int* edst  = (const int*)d_in[2];
  const float* Wl0 = (const float*)d_in[3];
  const float* Wr0 = (const float*)d_in[4];
  const float* b0  = (const float*)d_in[5];
  const float* Wl1 = (const float*)d_in[6];
  const float* Wr1 = (const float*)d_in[7];
  const float* b1  = (const float*)d_in[8];
  const float* Wl2 = (const float*)d_in[9];
  const float* Wr2 = (const float*)d_in[10];
  const float* b2  = (const float*)d_in[11];
  float* out = (float*)d_out;

  char* ws = (char*)d_ws;
  size_t off = 0;
  auto carve = [&](size_t bytes) -> char* {
    char* p = ws + off;
    off = (off + bytes + 255) & ~(size_t)255;
    return p;
  };
  int* cnt        = (int*)carve((size_t)NN * 4);        // reused as cursor
  int* row_start  = (int*)carve((size_t)(NN + 1) * 4);
  int* nbr        = (int*)carve((size_t)NE * 4);
  float* inv_deg  = (float*)carve((size_t)NN * 4);
  int* bsums      = (int*)carve(512 * 4);
  short8v* B0hi   = (short8v*)carve((size_t)64 * 64 * 16);
  short8v* B0lo   = (short8v*)carve((size_t)64 * 64 * 16);
  short8v* B1hi   = (short8v*)carve((size_t)64 * 64 * 16);
  short8v* B1lo   = (short8v*)carve((size_t)64 * 64 * 16);
  short8v* B2hi   = (short8v*)carve((size_t)24 * 64 * 16);
  short8v* B2lo   = (short8v*)carve((size_t)24 * 64 * 16);
  float* bufA     = (float*)carve((size_t)NN * D * 4);
  float* bufB     = (float*)carve((size_t)NN * D * 4);
  float* bufC     = (float*)carve((size_t)NN * D * 4);
  if (off > ws_size) return;

  const int GRID_E = (NE + 255) / 256;
  const int NB = (NN + 255) / 256;
  const int GRID_AGG = (NN + 7) / 8;
  const int GRID_GEMM = (NN + 127) / 128;

  // CSR build
  hipMemsetAsync(cnt, 0, (size_t)NN * 4, stream);
  count_kernel<<<GRID_E, 256, 0, stream>>>(edst, cnt);
  scan1_kernel<<<NB, 256, 0, stream>>>(cnt, row_start, bsums, inv_deg);
  scan2_kernel<<<1, 512, 0, stream>>>(bsums, NB);
  scan3_kernel<<<NB, 256, 0, stream>>>(row_start, bsums, cnt /*cursor*/);
  scatter_kernel<<<GRID_E, 256, 0, stream>>>(esrc, edst, cnt /*cursor*/, nbr);

  // weight prep (fragment-ordered hi/lo planes)
  prep_w_kernel<<<64, 64, 0, stream>>>(Wl0, Wr0, B0hi, B0lo);
  prep_w_kernel<<<64, 64, 0, stream>>>(Wl1, Wr1, B1hi, B1lo);
  prep_w2_kernel<<<24, 64, 0, stream>>>(Wl2, Wr2, B2hi, B2lo);

  // layer 0
  agg_kernel<<<GRID_AGG, 256, 0, stream>>>(x, bufA, row_start, nbr, inv_deg);
  mfma_gemm_kernel<<<GRID_GEMM, 256, 0, stream>>>(bufA, x, B0hi, B0lo, b0, bufB);
  // layer 1
  agg_kernel<<<GRID_AGG, 256, 0, stream>>>(bufB, bufA, row_start, nbr, inv_deg);
  mfma_gemm_kernel<<<GRID_GEMM, 256, 0, stream>>>(bufA, bufB, B1hi, B1lo, b1, bufC);
  // layer 2 + log_softmax
  agg_kernel<<<GRID_AGG, 256, 0, stream>>>(bufC, bufA, row_start, nbr, inv_deg);
  mfma_out_kernel<<<GRID_GEMM, 256, 0, stream>>>(bufA, bufC, B2hi, B2lo, b2, out);
}

// Round 4
// 413.117 us; speedup vs baseline: 3.1543x; 1.7338x over previous
//
#include <hip/hip_runtime.h>
#include <math.h>

#define NN 100000
#define NE 1600000
#define D 128
#define DOUT 40
#define NBUCK 391          // ceil(NN/256): bucket = 256 consecutive nodes
#define CHUNK 4096         // edges per binning workgroup
#define NCHUNK 391         // ceil(NE/CHUNK)

typedef __attribute__((ext_vector_type(8))) short short8v;   // 8 bf16 (4 VGPR)
typedef __attribute__((ext_vector_type(4))) float f32x4;

// f32 -> bf16 (rtne) bit pattern
__device__ __forceinline__ unsigned short f2bf(float f) {
  unsigned u = __float_as_uint(f);
  unsigned r = (u + 0x7fffu + ((u >> 16) & 1u)) >> 16;
  return (unsigned short)r;
}
__device__ __forceinline__ float bf2f(unsigned short s) {
  return __uint_as_float(((unsigned)s) << 16);
}
__device__ __forceinline__ float bflo(unsigned u) { return __uint_as_float(u << 16); }
__device__ __forceinline__ float bfhi(unsigned u) { return __uint_as_float(u & 0xffff0000u); }
__device__ __forceinline__ unsigned packbf(float a, float b) {
  return (unsigned)f2bf(a) | ((unsigned)f2bf(b) << 16);
}

// ---------------- x -> bf16 ----------------
__global__ __launch_bounds__(256) void cvt_bf16_kernel(const float* __restrict__ in,
                                                       unsigned short* __restrict__ out) {
  int i = (blockIdx.x * 256 + threadIdx.x) * 4;  // NN*D divisible by 4
  float4 v = *(const float4*)(in + i);
  uint2 o;
  o.x = packbf(v.x, v.y);
  o.y = packbf(v.z, v.w);
  *(uint2*)(out + i) = o;
}

// ---------------- CSR build: bucketed ----------------
__global__ __launch_bounds__(256) void bucket_hist_kernel(const int* __restrict__ dst,
                                                          int* __restrict__ bucket_cnt) {
  __shared__ int bc[NBUCK];
  int t = threadIdx.x;
  for (int i = t; i < NBUCK; i += 256) bc[i] = 0;
  __syncthreads();
  int e_base = blockIdx.x * CHUNK;
#pragma unroll
  for (int j = 0; j < 16; ++j) {
    int e = e_base + j * 256 + t;
    if (e < NE) atomicAdd(&bc[dst[e] >> 8], 1);
  }
  __syncthreads();
  for (int i = t; i < NBUCK; i += 256)
    if (bc[i]) atomicAdd(&bucket_cnt[i], bc[i]);
}

__global__ __launch_bounds__(512) void bucket_scan_kernel(const int* __restrict__ bucket_cnt,
                                                          int* __restrict__ bucket_base,
                                                          int* __restrict__ bucket_cursor) {
  __shared__ int s[512];
  int t = threadIdx.x;
  int c = (t < NBUCK) ? bucket_cnt[t] : 0;
  s[t] = c;
  __syncthreads();
  for (int off = 1; off < 512; off <<= 1) {
    int v = (t >= off) ? s[t - off] : 0;
    __syncthreads();
    s[t] += v;
    __syncthreads();
  }
  if (t < NBUCK) {
    int b = s[t] - c;
    bucket_base[t] = b;
    bucket_cursor[t] = b;
  }
  if (t == NBUCK) bucket_base[NBUCK] = s[NBUCK - 1];
}

// chunk-local LDS reorder, then bucket-contiguous coalesced writes of (src,dst)
__global__ __launch_bounds__(256) void binned_scatter_kernel(const int* __restrict__ src,
                                                             const int* __restrict__ dst,
                                                             int* __restrict__ bucket_cursor,
                                                             uint2* __restrict__ pairs) {
  __shared__ int lcnt[NBUCK];
  __shared__ int lscan[NBUCK];
  __shared__ int gb[NBUCK];
  __shared__ uint2 ebuf[CHUNK];
  int t = threadIdx.x;
  int e_base = blockIdx.x * CHUNK;
  for (int i = t; i < NBUCK; i += 256) lcnt[i] = 0;
  __syncthreads();

  int myb[16], myrank[16];
  uint2 mye[16];
#pragma unroll
  for (int j = 0; j < 16; ++j) {
    int e = e_base + j * 256 + t;
    if (e < NE) {
      int d = dst[e];
      mye[j] = make_uint2((unsigned)src[e], (unsigned)d);
      myb[j] = d >> 8;
      myrank[j] = atomicAdd(&lcnt[d >> 8], 1);
    } else {
      myb[j] = -1;
    }
  }
  __syncthreads();

  // inclusive Hillis-Steele scan of lcnt into lscan (391 entries, 2 per thread)
  lscan[t] = lcnt[t];
  if (256 + t < NBUCK) lscan[256 + t] = lcnt[256 + t];
  __syncthreads();
  for (int off = 1; off < 512; off <<= 1) {
    int v0 = (t >= off) ? lscan[t - off] : 0;
    int v1 = 0;
    int i1 = 256 + t;
    if (i1 < NBUCK) v1 = lscan[i1 - off];
    __syncthreads();
    if (t >= off) lscan[t] += v0;
    if (i1 < NBUCK) lscan[i1] += v1;
    __syncthreads();
  }

  // place into ebuf at chunk-local bucket-sorted position
#pragma unroll
  for (int j = 0; j < 16; ++j)
    if (myb[j] >= 0) {
      int b = myb[j];
      int lpos = lscan[b] - lcnt[b] + myrank[j];
      ebuf[lpos] = mye[j];
    }
  // reserve global space per bucket
  for (int i = t; i < NBUCK; i += 256)
    if (lcnt[i] > 0) gb[i] = atomicAdd(&bucket_cursor[i], lcnt[i]);
  __syncthreads();

  int chunk_n = min(CHUNK, NE - e_base);
  for (int s2 = t; s2 < chunk_n; s2 += 256) {
    uint2 e = ebuf[s2];
    int b = (int)(e.y >> 8);
    int g = gb[b] + (s2 - (lscan[b] - lcnt[b]));
    pairs[g] = e;
  }
}

// one workgroup per bucket: per-node count, local scan -> row_start, fine scatter
__global__ __launch_bounds__(256) void bucket_build_kernel(const uint2* __restrict__ pairs,
                                                           const int* __restrict__ bucket_base,
                                                           int* __restrict__ row_start,
                                                           int* __restrict__ nbr,
                                                           float* __restrict__ inv_deg) {
  __shared__ int cnt[256], loc[256], cur[256];
  int b = blockIdx.x;
  int t = threadIdx.x;
  int nbase = b << 8;
  int e0 = bucket_base[b], e1 = bucket_base[b + 1];
  cnt[t] = 0;
  __syncthreads();
  for (int e = e0 + t; e < e1; e += 256) {
    int d = (int)(pairs[e].y & 255u);
    atomicAdd(&cnt[d], 1);
  }
  __syncthreads();
  loc[t] = cnt[t];
  __syncthreads();
  for (int off = 1; off < 256; off <<= 1) {
    int v = (t >= off) ? loc[t - off] : 0;
    __syncthreads();
    loc[t] += v;
    __syncthreads();
  }
  int excl = loc[t] - cnt[t];
  int node = nbase + t;
  if (node < NN) {
    row_start[node] = e0 + excl;
    inv_deg[node] = 1.0f / (float)(cnt[t] > 1 ? cnt[t] : 1);
  }
  cur[t] = excl;
  if (b == NBUCK - 1 && t == 0) row_start[NN] = NE;
  __syncthreads();
  for (int e = e0 + t; e < e1; e += 256) {
    uint2 pr = pairs[e];
    int d = (int)(pr.y & 255u);
    int p = atomicAdd(&cur[d], 1);
    nbr[e0 + p] = (int)pr.x;
  }
}

// ---------------- mean aggregation (bf16 rows, 16 lanes/node) ----------------
__global__ __launch_bounds__(256) void agg_kernel(const unsigned short* __restrict__ X,
                                                  unsigned short* __restrict__ out,
                                                  const int* __restrict__ row_start,
                                                  const int* __restrict__ nbr,
                                                  const float* __restrict__ inv_deg) {
  int g = blockIdx.x * 16 + (threadIdx.x >> 4);
  int lane = threadIdx.x & 15;
  if (g >= NN) return;
  int p0 = row_start[g];
  int p1 = row_start[g + 1];
  const uint4* base = (const uint4*)X;  // row = 16 uint4
  float a0 = 0.f, a1 = 0.f, a2 = 0.f, a3 = 0.f, a4 = 0.f, a5 = 0.f, a6 = 0.f, a7 = 0.f;
  for (int p = p0; p < p1; ++p) {
    int s = nbr[p];
    uint4 v = base[(size_t)s * 16 + lane];
    a0 += bflo(v.x); a1 += bfhi(v.x);
    a2 += bflo(v.y); a3 += bfhi(v.y);
    a4 += bflo(v.z); a5 += bfhi(v.z);
    a6 += bflo(v.w); a7 += bfhi(v.w);
  }
  float id = inv_deg[g];
  uint4 o;
  o.x = packbf(a0 * id, a1 * id);
  o.y = packbf(a2 * id, a3 * id);
  o.z = packbf(a4 * id, a5 * id);
  o.w = packbf(a6 * id, a7 * id);
  ((uint4*)out)[(size_t)g * 16 + lane] = o;
}

// ---------------- weight prep: fragment-ordered hi/lo bf16 planes ----------------
// Bcat[k][c] = (k<128 ? Wl[c][k] : Wr[c][k-128]);
// plane[((s*8+n)*64+l)] = Bcat[s*32 + (l>>4)*8 + i][n*16 + (l&15)]
__global__ __launch_bounds__(64) void prep_w_kernel(const float* __restrict__ Wl,
                                                    const float* __restrict__ Wr,
                                                    short8v* __restrict__ hi,
                                                    short8v* __restrict__ lo) {
  int s = blockIdx.x >> 3;
  int n = blockIdx.x & 7;
  int l = threadIdx.x;
  int k0 = s * 32 + (l >> 4) * 8;
  int c = n * 16 + (l & 15);
  const float* W = (k0 < 128) ? Wl : Wr;
  int kb = (k0 < 128) ? k0 : k0 - 128;
  short hv[8], lv[8];
#pragma unroll
  for (int i = 0; i < 8; ++i) {
    float v = W[c * 128 + kb + i];
    unsigned short h = f2bf(v);
    hv[i] = (short)h;
    lv[i] = (short)f2bf(v - bf2f(h));
  }
  int idx = blockIdx.x * 64 + l;
  hi[idx] = (short8v){hv[0], hv[1], hv[2], hv[3], hv[4], hv[5], hv[6], hv[7]};
  lo[idx] = (short8v){lv[0], lv[1], lv[2], lv[3], lv[4], lv[5], lv[6], lv[7]};
}

__global__ __launch_bounds__(64) void prep_w2_kernel(const float* __restrict__ Wl,
                                                     const float* __restrict__ Wr,
                                                     short8v* __restrict__ hi,
                                                     short8v* __restrict__ lo) {
  int s = blockIdx.x / 3;
  int n = blockIdx.x % 3;
  int l = threadIdx.x;
  int k0 = s * 32 + (l >> 4) * 8;
  int c = n * 16 + (l & 15);
  const float* W = (k0 < 128) ? Wl : Wr;
  int kb = (k0 < 128) ? k0 : k0 - 128;
  short hv[8], lv[8];
#pragma unroll
  for (int i = 0; i < 8; ++i) {
    float v = (c < DOUT) ? W[c * 128 + kb + i] : 0.f;
    unsigned short h = f2bf(v);
    hv[i] = (short)h;
    lv[i] = (short)f2bf(v - bf2f(h));
  }
  int idx = blockIdx.x * 64 + l;
  hi[idx] = (short8v){hv[0], hv[1], hv[2], hv[3], hv[4], hv[5], hv[6], hv[7]};
  lo[idx] = (short8v){lv[0], lv[1], lv[2], lv[3], lv[4], lv[5], lv[6], lv[7]};
}

// ---------------- layers 0/1: out = relu([A|H] @ Bcat + b), bf16 A x (hi/lo B) ----------------
// block 256 = 4 waves; tile 128 rows x 128 cols; wave: 2 row-frags x 8 col-frags
__global__ __launch_bounds__(256) void mfma_gemm_kernel(
    const unsigned short* __restrict__ A, const unsigned short* __restrict__ H,
    const short8v* __restrict__ Bhi, const short8v* __restrict__ Blo,
    const float* __restrict__ bias, unsigned short* __restrict__ out) {
  __shared__ unsigned short As[128 * 40];  // row stride 40 ushorts (80B)

  int t = threadIdx.x;
  int w = t >> 6, l = t & 63;
  int R0 = blockIdx.x * 128;
  int lc = l & 15;
  int lg = l >> 4;

  f32x4 acc[2][8];
#pragma unroll
  for (int m = 0; m < 2; ++m)
#pragma unroll
    for (int n = 0; n < 8; ++n) acc[m][n] = (f32x4){0.f, 0.f, 0.f, 0.f};

  for (int s = 0; s < 8; ++s) {
    const unsigned short* src = (s < 4) ? A : H;
    int koff = (s & 3) * 32;
    // stage 128 rows x 32 k (bf16): 512 chunks of 16B, 2 per thread
#pragma unroll
    for (int c = 0; c < 2; ++c) {
      int chunk = t + c * 256;
      int row = chunk >> 2, seg = chunk & 3;
      int gr = R0 + row;
      uint4 v = make_uint4(0, 0, 0, 0);
      if (gr < NN) v = *(const uint4*)(src + (size_t)gr * D + koff + seg * 8);
      *(uint4*)&As[row * 40 + seg * 8] = v;
    }
    __syncthreads();

    short8v bh[8], bl[8];
#pragma unroll
    for (int n = 0; n < 8; ++n) {
      int idx = (s * 8 + n) * 64 + l;
      bh[n] = Bhi[idx];
      bl[n] = Blo[idx];
    }

    short8v ah[2];
#pragma unroll
    for (int m = 0; m < 2; ++m) {
      int r = w * 32 + m * 16 + lc;
      ah[m] = *(const short8v*)&As[r * 40 + lg * 8];
    }

#pragma unroll
    for (int n = 0; n < 8; ++n)
#pragma unroll
      for (int m = 0; m < 2; ++m) {
        acc[m][n] = __builtin_amdgcn_mfma_f32_16x16x32_bf16(ah[m], bh[n], acc[m][n], 0, 0, 0);
        acc[m][n] = __builtin_amdgcn_mfma_f32_16x16x32_bf16(ah[m], bl[n], acc[m][n], 0, 0, 0);
      }
    __syncthreads();
  }

  float bcol[8];
#pragma unroll
  for (int n = 0; n < 8; ++n) bcol[n] = bias[n * 16 + lc];
#pragma unroll
  for (int m = 0; m < 2; ++m)
#pragma unroll
    for (int n = 0; n < 8; ++n) {
      int col = n * 16 + lc;
#pragma unroll
      for (int j = 0; j < 4; ++j) {
        int gr = R0 + w * 32 + m * 16 + lg * 4 + j;
        if (gr < NN)
          out[(size_t)gr * D + col] = f2bf(fmaxf(acc[m][n][j] + bcol[n], 0.f));
      }
    }
}

// ---------------- layer 2: z = [A|H] @ Bcat2 + b2, fused log_softmax ----------------
__global__ __launch_bounds__(256) void mfma_out_kernel(
    const unsigned short* __restrict__ A, const unsigned short* __restrict__ H,
    const short8v* __restrict__ Bhi, const short8v* __restrict__ Blo,
    const float* __restrict__ bias, float* __restrict__ out) {
  __shared__ unsigned short As[128 * 40];

  int t = threadIdx.x;
  int w = t >> 6, l = t & 63;
  int R0 = blockIdx.x * 128;
  int lc = l & 15;
  int lg = l >> 4;

  f32x4 acc[2][3];
#pragma unroll
  for (int m = 0; m < 2; ++m)
#pragma unroll
    for (int n = 0; n < 3; ++n) acc[m][n] = (f32x4){0.f, 0.f, 0.f, 0.f};

  for (int s = 0; s < 8; ++s) {
    const unsigned short* src = (s < 4) ? A : H;
    int koff = (s & 3) * 32;
#pragma unroll
    for (int c = 0; c < 2; ++c) {
      int chunk = t + c * 256;
      int row = chunk >> 2, seg = chunk & 3;
      int gr = R0 + row;
      uint4 v = make_uint4(0, 0, 0, 0);
      if (gr < NN) v = *(const uint4*)(src + (size_t)gr * D + koff + seg * 8);
      *(uint4*)&As[row * 40 + seg * 8] = v;
    }
    __syncthreads();

    short8v bh[3], bl[3];
#pragma unroll
    for (int n = 0; n < 3; ++n) {
      int idx = (s * 3 + n) * 64 + l;
      bh[n] = Bhi[idx];
      bl[n] = Blo[idx];
    }

    short8v ah[2];
#pragma unroll
    for (int m = 0; m < 2; ++m) {
      int r = w * 32 + m * 16 + lc;
      ah[m] = *(const short8v*)&As[r * 40 + lg * 8];
    }

#pragma unroll
    for (int n = 0; n < 3; ++n)
#pragma unroll
      for (int m = 0; m < 2; ++m) {
        acc[m][n] = __builtin_amdgcn_mfma_f32_16x16x32_bf16(ah[m], bh[n], acc[m][n], 0, 0, 0);
        acc[m][n] = __builtin_amdgcn_mfma_f32_16x16x32_bf16(ah[m], bl[n], acc[m][n], 0, 0, 0);
      }
    __syncthreads();
  }

  float bcol[3];
#pragma unroll
  for (int n = 0; n < 3; ++n) {
    int col = n * 16 + lc;
    bcol[n] = (col < DOUT) ? bias[col] : 0.f;
  }
#pragma unroll
  for (int m = 0; m < 2; ++m)
#pragma unroll
    for (int j = 0; j < 4; ++j) {
      int r = R0 + w * 32 + m * 16 + lg * 4 + j;
      float z[3];
      float zm = -INFINITY;
#pragma unroll
      for (int n = 0; n < 3; ++n) {
        int col = n * 16 + lc;
        z[n] = acc[m][n][j] + bcol[n];
        if (col < DOUT) zm = fmaxf(zm, z[n]);
      }
#pragma unroll
      for (int off = 1; off < 16; off <<= 1) zm = fmaxf(zm, __shfl_xor(zm, off));
      float ssum = 0.f;
#pragma unroll
      for (int n = 0; n < 3; ++n) {
        int col = n * 16 + lc;
        if (col < DOUT) ssum += expf(z[n] - zm);
      }
#pragma unroll
      for (int off = 1; off < 16; off <<= 1) ssum += __shfl_xor(ssum, off);
      float lse = zm + logf(ssum);
      if (r < NN) {
#pragma unroll
        for (int n = 0; n < 3; ++n) {
          int col = n * 16 + lc;
          if (col < DOUT) out[(size_t)r * DOUT + col] = z[n] - lse;
        }
      }
    }
}

// ---------------- launch ----------------
extern "C" void kernel_launch(void* const* d_in, const int* in_sizes, int n_in,
                              void* d_out, int out_size, void* d_ws, size_t ws_size,
                              hipStream_t stream) {
  const float* x   = (const float*)d_in[0];
  const int* esrc  = (const int*)d_in[1];
  const int* edst  = (const int*)d_in[2];
  const float* Wl0 = (const float*)d_in[3];
  const float* Wr0 = (const float*)d_in[4];
  const float* b0  = (const float*)d_in[5];
  const float* Wl1 = (const float*)d_in[6];
  const float* Wr1 = (const float*)d_in[7];
  const float* b1  = (const float*)d_in[8];
  const float* Wl2 = (const float*)d_in[9];
  const float* Wr2 = (const float*)d_in[10];
  const float* b2  = (const float*)d_in[11];
  float* out = (float*)d_out;

  char* ws = (char*)d_ws;
  size_t off = 0;
  auto carve = [&](size_t bytes) -> char* {
    char* p = ws + off;
    off = (off + bytes + 255) & ~(size_t)255;
    return p;
  };
  int* bucket_cnt    = (int*)carve((size_t)NBUCK * 4);
  int* bucket_base   = (int*)carve((size_t)(NBUCK + 1) * 4);
  int* bucket_cursor = (int*)carve((size_t)NBUCK * 4);
  int* row_start     = (int*)carve((size_t)(NN + 1) * 4);
  int* nbr           = (int*)carve((size_t)NE * 4);
  float* inv_deg     = (float*)carve((size_t)NN * 4);
  uint2* pairs       = (uint2*)carve((size_t)NE * 8);
  short8v* B0hi      = (short8v*)carve((size_t)64 * 64 * 16);
  short8v* B0lo      = (short8v*)carve((size_t)64 * 64 * 16);
  short8v* B1hi      = (short8v*)carve((size_t)64 * 64 * 16);
  short8v* B1lo      = (short8v*)carve((size_t)64 * 64 * 16);
  short8v* B2hi      = (short8v*)carve((size_t)24 * 64 * 16);
  short8v* B2lo      = (short8v*)carve((size_t)24 * 64 * 16);
  unsigned short* xb   = (unsigned short*)carve((size_t)NN * D * 2);
  unsigned short* bufA = (unsigned short*)carve((size_t)NN * D * 2);
  unsigned short* bufB = (unsigned short*)carve((size_t)NN * D * 2);
  unsigned short* bufC = (unsigned short*)carve((size_t)NN * D * 2);
  if (off > ws_size) return;

  const int GRID_AGG = (NN + 15) / 16;       // 6250
  const int GRID_GEMM = (NN + 127) / 128;    // 782
  const int GRID_CVT = NN * D / 4 / 256;     // 12500

  // CSR build (bucketed)
  hipMemsetAsync(bucket_cnt, 0, (size_t)NBUCK * 4, stream);
  bucket_hist_kernel<<<NCHUNK, 256, 0, stream>>>(edst, bucket_cnt);
  bucket_scan_kernel<<<1, 512, 0, stream>>>(bucket_cnt, bucket_base, bucket_cursor);
  binned_scatter_kernel<<<NCHUNK, 256, 0, stream>>>(esrc, edst, bucket_cursor, pairs);
  bucket_build_kernel<<<NBUCK, 256, 0, stream>>>(pairs, bucket_base, row_start, nbr, inv_deg);

  // feature prep
  cvt_bf16_kernel<<<GRID_CVT, 256, 0, stream>>>(x, xb);
  prep_w_kernel<<<64, 64, 0, stream>>>(Wl0, Wr0, B0hi, B0lo);
  prep_w_kernel<<<64, 64, 0, stream>>>(Wl1, Wr1, B1hi, B1lo);
  prep_w2_kernel<<<24, 64, 0, stream>>>(Wl2, Wr2, B2hi, B2lo);

  // layer 0
  agg_kernel<<<GRID_AGG, 256, 0, stream>>>(xb, bufA, row_start, nbr, inv_deg);
  mfma_gemm_kernel<<<GRID_GEMM, 256, 0, stream>>>(bufA, xb, B0hi, B0lo, b0, bufB);
  // layer 1
  agg_kernel<<<GRID_AGG, 256, 0, stream>>>(bufB, bufA, row_start, nbr, inv_deg);
  mfma_gemm_kernel<<<GRID_GEMM, 256, 0, stream>>>(bufA, bufB, B1hi, B1lo, b1, bufC);
  // layer 2 + log_softmax
  agg_kernel<<<GRID_AGG, 256, 0, stream>>>(bufC, bufA, row_start, nbr, inv_deg);
  mfma_out_kernel<<<GRID_GEMM, 256, 0, stream>>>(bufA, bufC, B2hi, B2lo, b2, out);
}

// Round 5
// 346.348 us; speedup vs baseline: 3.7624x; 1.1928x over previous
//
#include <hip/hip_runtime.h>
#include <math.h>

#define NN 100000
#define NE 1600000
#define D 128
#define DOUT 40
#define NBUCK 391          // ceil(NN/256): bucket = 256 consecutive nodes
#define CHUNK 4096         // edges per binning workgroup
#define NCHUNK 391         // ceil(NE/CHUNK)

typedef __attribute__((ext_vector_type(8))) short short8v;   // 8 bf16 (4 VGPR)
typedef __attribute__((ext_vector_type(4))) float f32x4;

// f32 -> bf16 (rtne) bit pattern
__device__ __forceinline__ unsigned short f2bf(float f) {
  unsigned u = __float_as_uint(f);
  unsigned r = (u + 0x7fffu + ((u >> 16) & 1u)) >> 16;
  return (unsigned short)r;
}
__device__ __forceinline__ float bf2f(unsigned short s) {
  return __uint_as_float(((unsigned)s) << 16);
}
__device__ __forceinline__ float bflo(unsigned u) { return __uint_as_float(u << 16); }
__device__ __forceinline__ float bfhi(unsigned u) { return __uint_as_float(u & 0xffff0000u); }
__device__ __forceinline__ unsigned packbf(float a, float b) {
  return (unsigned)f2bf(a) | ((unsigned)f2bf(b) << 16);
}

// ---------------- x -> bf16 ----------------
__global__ __launch_bounds__(256) void cvt_bf16_kernel(const float* __restrict__ in,
                                                       unsigned short* __restrict__ out) {
  int i = (blockIdx.x * 256 + threadIdx.x) * 4;
  float4 v = *(const float4*)(in + i);
  uint2 o;
  o.x = packbf(v.x, v.y);
  o.y = packbf(v.z, v.w);
  *(uint2*)(out + i) = o;
}

// ---------------- CSR build: bucketed ----------------
__global__ __launch_bounds__(256) void bucket_hist_kernel(const int* __restrict__ dst,
                                                          int* __restrict__ bucket_cnt) {
  __shared__ int bc[NBUCK];
  int t = threadIdx.x;
  for (int i = t; i < NBUCK; i += 256) bc[i] = 0;
  __syncthreads();
  int e_base = blockIdx.x * CHUNK;
#pragma unroll
  for (int j = 0; j < 16; ++j) {
    int e = e_base + j * 256 + t;
    if (e < NE) atomicAdd(&bc[dst[e] >> 8], 1);
  }
  __syncthreads();
  for (int i = t; i < NBUCK; i += 256)
    if (bc[i]) atomicAdd(&bucket_cnt[i], bc[i]);
}

__global__ __launch_bounds__(512) void bucket_scan_kernel(const int* __restrict__ bucket_cnt,
                                                          int* __restrict__ bucket_base,
                                                          int* __restrict__ bucket_cursor) {
  __shared__ int s[512];
  int t = threadIdx.x;
  int c = (t < NBUCK) ? bucket_cnt[t] : 0;
  s[t] = c;
  __syncthreads();
  for (int off = 1; off < 512; off <<= 1) {
    int v = (t >= off) ? s[t - off] : 0;
    __syncthreads();
    s[t] += v;
    __syncthreads();
  }
  if (t < NBUCK) {
    int b = s[t] - c;
    bucket_base[t] = b;
    bucket_cursor[t] = b;
  }
  if (t == NBUCK) bucket_base[NBUCK] = s[NBUCK - 1];
}

// chunk-local LDS reorder, then bucket-contiguous coalesced writes
// payload: word = (dst&255)<<24 | src   (src < 2^24)
__global__ __launch_bounds__(256) void binned_scatter_kernel(const int* __restrict__ src,
                                                             const int* __restrict__ dst,
                                                             int* __restrict__ bucket_cursor,
                                                             unsigned* __restrict__ pairs) {
  __shared__ int lcnt[NBUCK];
  __shared__ int lscan[NBUCK];
  __shared__ int gb[NBUCK];
  __shared__ unsigned ebuf[CHUNK];
  __shared__ unsigned short bbuf[CHUNK];
  int t = threadIdx.x;
  int e_base = blockIdx.x * CHUNK;
  for (int i = t; i < NBUCK; i += 256) lcnt[i] = 0;
  __syncthreads();

  int myb[16], myrank[16];
  unsigned mye[16];
#pragma unroll
  for (int j = 0; j < 16; ++j) {
    int e = e_base + j * 256 + t;
    if (e < NE) {
      int d = dst[e];
      mye[j] = (unsigned)src[e] | ((unsigned)(d & 255) << 24);
      myb[j] = d >> 8;
      myrank[j] = atomicAdd(&lcnt[d >> 8], 1);
    } else {
      myb[j] = -1;
    }
  }
  __syncthreads();

  // inclusive scan of lcnt into lscan (391 entries, 2 per thread)
  lscan[t] = lcnt[t];
  if (256 + t < NBUCK) lscan[256 + t] = lcnt[256 + t];
  __syncthreads();
  for (int off = 1; off < 512; off <<= 1) {
    int v0 = (t >= off) ? lscan[t - off] : 0;
    int v1 = 0;
    int i1 = 256 + t;
    if (i1 < NBUCK) v1 = lscan[i1 - off];
    __syncthreads();
    if (t >= off) lscan[t] += v0;
    if (i1 < NBUCK) lscan[i1] += v1;
    __syncthreads();
  }

#pragma unroll
  for (int j = 0; j < 16; ++j)
    if (myb[j] >= 0) {
      int b = myb[j];
      int lpos = lscan[b] - lcnt[b] + myrank[j];
      ebuf[lpos] = mye[j];
      bbuf[lpos] = (unsigned short)b;
    }
  for (int i = t; i < NBUCK; i += 256)
    if (lcnt[i] > 0) gb[i] = atomicAdd(&bucket_cursor[i], lcnt[i]);
  __syncthreads();

  int chunk_n = min(CHUNK, NE - e_base);
  for (int s2 = t; s2 < chunk_n; s2 += 256) {
    int b = bbuf[s2];
    int g = gb[b] + (s2 - (lscan[b] - lcnt[b]));
    pairs[g] = ebuf[s2];
  }
}

// one workgroup per bucket: per-node count, local scan -> row_start, fine scatter
__global__ __launch_bounds__(256) void bucket_build_kernel(const unsigned* __restrict__ pairs,
                                                           const int* __restrict__ bucket_base,
                                                           int* __restrict__ row_start,
                                                           int* __restrict__ nbr,
                                                           float* __restrict__ inv_deg) {
  __shared__ int cnt[256], loc[256], cur[256];
  int b = blockIdx.x;
  int t = threadIdx.x;
  int nbase = b << 8;
  int e0 = bucket_base[b], e1 = bucket_base[b + 1];
  cnt[t] = 0;
  __syncthreads();
  for (int e = e0 + t; e < e1; e += 256) {
    int d = (int)(pairs[e] >> 24);
    atomicAdd(&cnt[d], 1);
  }
  __syncthreads();
  loc[t] = cnt[t];
  __syncthreads();
  for (int off = 1; off < 256; off <<= 1) {
    int v = (t >= off) ? loc[t - off] : 0;
    __syncthreads();
    loc[t] += v;
    __syncthreads();
  }
  int excl = loc[t] - cnt[t];
  int node = nbase + t;
  if (node < NN) {
    row_start[node] = e0 + excl;
    inv_deg[node] = 1.0f / (float)(cnt[t] > 1 ? cnt[t] : 1);
  }
  cur[t] = excl;
  if (b == NBUCK - 1 && t == 0) row_start[NN] = NE;
  __syncthreads();
  for (int e = e0 + t; e < e1; e += 256) {
    unsigned pr = pairs[e];
    int d = (int)(pr >> 24);
    int p = atomicAdd(&cur[d], 1);
    nbr[e0 + p] = (int)(pr & 0xFFFFFFu);
  }
}

// ---------------- mean aggregation (bf16 rows, 16 lanes/node, unroll 4) ----------------
__global__ __launch_bounds__(256) void agg_kernel(const unsigned short* __restrict__ X,
                                                  unsigned short* __restrict__ out,
                                                  const int* __restrict__ row_start,
                                                  const int* __restrict__ nbr,
                                                  const float* __restrict__ inv_deg) {
  int g = blockIdx.x * 16 + (threadIdx.x >> 4);
  int lane = threadIdx.x & 15;
  if (g >= NN) return;
  int p0 = row_start[g];
  int p1 = row_start[g + 1];
  const uint4* base = (const uint4*)X;  // row = 16 uint4
  float a0 = 0.f, a1 = 0.f, a2 = 0.f, a3 = 0.f, a4 = 0.f, a5 = 0.f, a6 = 0.f, a7 = 0.f;
  int p = p0;
  for (; p + 3 < p1; p += 4) {
    int s0 = nbr[p], s1 = nbr[p + 1], s2 = nbr[p + 2], s3 = nbr[p + 3];
    uint4 v0 = base[(size_t)s0 * 16 + lane];
    uint4 v1 = base[(size_t)s1 * 16 + lane];
    uint4 v2 = base[(size_t)s2 * 16 + lane];
    uint4 v3 = base[(size_t)s3 * 16 + lane];
    a0 += bflo(v0.x) + bflo(v1.x) + bflo(v2.x) + bflo(v3.x);
    a1 += bfhi(v0.x) + bfhi(v1.x) + bfhi(v2.x) + bfhi(v3.x);
    a2 += bflo(v0.y) + bflo(v1.y) + bflo(v2.y) + bflo(v3.y);
    a3 += bfhi(v0.y) + bfhi(v1.y) + bfhi(v2.y) + bfhi(v3.y);
    a4 += bflo(v0.z) + bflo(v1.z) + bflo(v2.z) + bflo(v3.z);
    a5 += bfhi(v0.z) + bfhi(v1.z) + bfhi(v2.z) + bfhi(v3.z);
    a6 += bflo(v0.w) + bflo(v1.w) + bflo(v2.w) + bflo(v3.w);
    a7 += bfhi(v0.w) + bfhi(v1.w) + bfhi(v2.w) + bfhi(v3.w);
  }
  for (; p < p1; ++p) {
    int s = nbr[p];
    uint4 v = base[(size_t)s * 16 + lane];
    a0 += bflo(v.x); a1 += bfhi(v.x);
    a2 += bflo(v.y); a3 += bfhi(v.y);
    a4 += bflo(v.z); a5 += bfhi(v.z);
    a6 += bflo(v.w); a7 += bfhi(v.w);
  }
  float id = inv_deg[g];
  uint4 o;
  o.x = packbf(a0 * id, a1 * id);
  o.y = packbf(a2 * id, a3 * id);
  o.z = packbf(a4 * id, a5 * id);
  o.w = packbf(a6 * id, a7 * id);
  ((uint4*)out)[(size_t)g * 16 + lane] = o;
}

// ---------------- weight prep: fragment-ordered hi/lo bf16 planes (layers 0/1) ----------------
__global__ __launch_bounds__(64) void prep_w_kernel(const float* __restrict__ Wl,
                                                    const float* __restrict__ Wr,
                                                    short8v* __restrict__ hi,
                                                    short8v* __restrict__ lo) {
  int s = blockIdx.x >> 3;
  int n = blockIdx.x & 7;
  int l = threadIdx.x;
  int k0 = s * 32 + (l >> 4) * 8;
  int c = n * 16 + (l & 15);
  const float* W = (k0 < 128) ? Wl : Wr;
  int kb = (k0 < 128) ? k0 : k0 - 128;
  short hv[8], lv[8];
#pragma unroll
  for (int i = 0; i < 8; ++i) {
    float v = W[c * 128 + kb + i];
    unsigned short h = f2bf(v);
    hv[i] = (short)h;
    lv[i] = (short)f2bf(v - bf2f(h));
  }
  int idx = blockIdx.x * 64 + l;
  hi[idx] = (short8v){hv[0], hv[1], hv[2], hv[3], hv[4], hv[5], hv[6], hv[7]};
  lo[idx] = (short8v){lv[0], lv[1], lv[2], lv[3], lv[4], lv[5], lv[6], lv[7]};
}

// ---------------- weight prep layer 2: cols 0..39 = Wl2, 40..79 = Wr2 (K=128) ----------------
// plane[((s*5+n)*64+l)], s in [0,4), n in [0,5)
__global__ __launch_bounds__(64) void prep_wy2_kernel(const float* __restrict__ Wl,
                                                      const float* __restrict__ Wr,
                                                      short8v* __restrict__ hi,
                                                      short8v* __restrict__ lo) {
  int s = blockIdx.x / 5;
  int n = blockIdx.x % 5;
  int l = threadIdx.x;
  int k0 = s * 32 + (l >> 4) * 8;
  int c = n * 16 + (l & 15);          // 0..79
  const float* W = (c < DOUT) ? Wl : Wr;
  int row = (c < DOUT) ? c : c - DOUT;
  short hv[8], lv[8];
#pragma unroll
  for (int i = 0; i < 8; ++i) {
    float v = W[row * 128 + k0 + i];
    unsigned short h = f2bf(v);
    hv[i] = (short)h;
    lv[i] = (short)f2bf(v - bf2f(h));
  }
  int idx = blockIdx.x * 64 + l;
  hi[idx] = (short8v){hv[0], hv[1], hv[2], hv[3], hv[4], hv[5], hv[6], hv[7]};
  lo[idx] = (short8v){lv[0], lv[1], lv[2], lv[3], lv[4], lv[5], lv[6], lv[7]};
}

// ---------------- layers 0/1: out = relu([A|H] @ Bcat + b) ----------------
__global__ __launch_bounds__(256) void mfma_gemm_kernel(
    const unsigned short* __restrict__ A, const unsigned short* __restrict__ H,
    const short8v* __restrict__ Bhi, const short8v* __restrict__ Blo,
    const float* __restrict__ bias, unsigned short* __restrict__ out) {
  __shared__ unsigned short As[128 * 40];

  int t = threadIdx.x;
  int w = t >> 6, l = t & 63;
  int R0 = blockIdx.x * 128;
  int lc = l & 15;
  int lg = l >> 4;

  f32x4 acc[2][8];
#pragma unroll
  for (int m = 0; m < 2; ++m)
#pragma unroll
    for (int n = 0; n < 8; ++n) acc[m][n] = (f32x4){0.f, 0.f, 0.f, 0.f};

  for (int s = 0; s < 8; ++s) {
    const unsigned short* src = (s < 4) ? A : H;
    int koff = (s & 3) * 32;
#pragma unroll
    for (int c = 0; c < 2; ++c) {
      int chunk = t + c * 256;
      int row = chunk >> 2, seg = chunk & 3;
      int gr = R0 + row;
      uint4 v = make_uint4(0, 0, 0, 0);
      if (gr < NN) v = *(const uint4*)(src + (size_t)gr * D + koff + seg * 8);
      *(uint4*)&As[row * 40 + seg * 8] = v;
    }
    __syncthreads();

    short8v bh[8], bl[8];
#pragma unroll
    for (int n = 0; n < 8; ++n) {
      int idx = (s * 8 + n) * 64 + l;
      bh[n] = Bhi[idx];
      bl[n] = Blo[idx];
    }

    short8v ah[2];
#pragma unroll
    for (int m = 0; m < 2; ++m) {
      int r = w * 32 + m * 16 + lc;
      ah[m] = *(const short8v*)&As[r * 40 + lg * 8];
    }

#pragma unroll
    for (int n = 0; n < 8; ++n)
#pragma unroll
      for (int m = 0; m < 2; ++m) {
        acc[m][n] = __builtin_amdgcn_mfma_f32_16x16x32_bf16(ah[m], bh[n], acc[m][n], 0, 0, 0);
        acc[m][n] = __builtin_amdgcn_mfma_f32_16x16x32_bf16(ah[m], bl[n], acc[m][n], 0, 0, 0);
      }
    __syncthreads();
  }

  float bcol[8];
#pragma unroll
  for (int n = 0; n < 8; ++n) bcol[n] = bias[n * 16 + lc];
#pragma unroll
  for (int m = 0; m < 2; ++m)
#pragma unroll
    for (int n = 0; n < 8; ++n) {
      int col = n * 16 + lc;
#pragma unroll
      for (int j = 0; j < 4; ++j) {
        int gr = R0 + w * 32 + m * 16 + lg * 4 + j;
        if (gr < NN)
          out[(size_t)gr * D + col] = f2bf(fmaxf(acc[m][n][j] + bcol[n], 0.f));
      }
    }
}

// ---------------- layer 2 GEMM: y = h2 @ [Wl2|Wr2]^T; y_l bf16 N x 64 (pad), y_r f32 N x 40 (+b2) ----------------
__global__ __launch_bounds__(256) void mfma_y2_kernel(
    const unsigned short* __restrict__ H,
    const short8v* __restrict__ Bhi, const short8v* __restrict__ Blo,
    const float* __restrict__ b2,
    unsigned short* __restrict__ yl, float* __restrict__ yr) {
  __shared__ unsigned short As[128 * 40];

  int t = threadIdx.x;
  int w = t >> 6, l = t & 63;
  int R0 = blockIdx.x * 128;
  int lc = l & 15;
  int lg = l >> 4;

  f32x4 acc[2][5];
#pragma unroll
  for (int m = 0; m < 2; ++m)
#pragma unroll
    for (int n = 0; n < 5; ++n) acc[m][n] = (f32x4){0.f, 0.f, 0.f, 0.f};

  for (int s = 0; s < 4; ++s) {
    int koff = s * 32;
#pragma unroll
    for (int c = 0; c < 2; ++c) {
      int chunk = t + c * 256;
      int row = chunk >> 2, seg = chunk & 3;
      int gr = R0 + row;
      uint4 v = make_uint4(0, 0, 0, 0);
      if (gr < NN) v = *(const uint4*)(H + (size_t)gr * D + koff + seg * 8);
      *(uint4*)&As[row * 40 + seg * 8] = v;
    }
    __syncthreads();

    short8v bh[5], bl[5];
#pragma unroll
    for (int n = 0; n < 5; ++n) {
      int idx = (s * 5 + n) * 64 + l;
      bh[n] = Bhi[idx];
      bl[n] = Blo[idx];
    }

    short8v ah[2];
#pragma unroll
    for (int m = 0; m < 2; ++m) {
      int r = w * 32 + m * 16 + lc;
      ah[m] = *(const short8v*)&As[r * 40 + lg * 8];
    }

#pragma unroll
    for (int n = 0; n < 5; ++n)
#pragma unroll
      for (int m = 0; m < 2; ++m) {
        acc[m][n] = __builtin_amdgcn_mfma_f32_16x16x32_bf16(ah[m], bh[n], acc[m][n], 0, 0, 0);
        acc[m][n] = __builtin_amdgcn_mfma_f32_16x16x32_bf16(ah[m], bl[n], acc[m][n], 0, 0, 0);
      }
    __syncthreads();
  }

#pragma unroll
  for (int m = 0; m < 2; ++m)
#pragma unroll
    for (int n = 0; n < 5; ++n) {
      int col = n * 16 + lc;
#pragma unroll
      for (int j = 0; j < 4; ++j) {
        int gr = R0 + w * 32 + m * 16 + lg * 4 + j;
        if (gr < NN) {
          if (col < DOUT) {
            yl[(size_t)gr * 64 + col] = f2bf(acc[m][n][j]);
          } else if (col >= 40 && col < 80) {
            yr[(size_t)gr * DOUT + (col - DOUT)] = acc[m][n][j] + b2[col - DOUT];
          }
        }
      }
    }
}

// ---------------- fused layer-2 agg + log_softmax: 8 lanes/node on 64-col padded y_l ----------------
__global__ __launch_bounds__(256) void agg_out_kernel(const unsigned short* __restrict__ yl,
                                                      const float* __restrict__ yr,
                                                      const int* __restrict__ row_start,
                                                      const int* __restrict__ nbr,
                                                      const float* __restrict__ inv_deg,
                                                      float* __restrict__ out) {
  int g = blockIdx.x * 32 + (threadIdx.x >> 3);
  int ln = threadIdx.x & 7;
  if (g >= NN) return;
  int p0 = row_start[g];
  int p1 = row_start[g + 1];
  const uint4* base = (const uint4*)yl;  // row = 8 uint4
  float a0 = 0.f, a1 = 0.f, a2 = 0.f, a3 = 0.f, a4 = 0.f, a5 = 0.f, a6 = 0.f, a7 = 0.f;
  int p = p0;
  for (; p + 3 < p1; p += 4) {
    int s0 = nbr[p], s1 = nbr[p + 1], s2 = nbr[p + 2], s3 = nbr[p + 3];
    uint4 v0 = base[(size_t)s0 * 8 + ln];
    uint4 v1 = base[(size_t)s1 * 8 + ln];
    uint4 v2 = base[(size_t)s2 * 8 + ln];
    uint4 v3 = base[(size_t)s3 * 8 + ln];
    a0 += bflo(v0.x) + bflo(v1.x) + bflo(v2.x) + bflo(v3.x);
    a1 += bfhi(v0.x) + bfhi(v1.x) + bfhi(v2.x) + bfhi(v3.x);
    a2 += bflo(v0.y) + bflo(v1.y) + bflo(v2.y) + bflo(v3.y);
    a3 += bfhi(v0.y) + bfhi(v1.y) + bfhi(v2.y) + bfhi(v3.y);
    a4 += bflo(v0.z) + bflo(v1.z) + bflo(v2.z) + bflo(v3.z);
    a5 += bfhi(v0.z) + bfhi(v1.z) + bfhi(v2.z) + bfhi(v3.z);
    a6 += bflo(v0.w) + bflo(v1.w) + bflo(v2.w) + bflo(v3.w);
    a7 += bfhi(v0.w) + bfhi(v1.w) + bfhi(v2.w) + bfhi(v3.w);
  }
  for (; p < p1; ++p) {
    int s = nbr[p];
    uint4 v = base[(size_t)s * 8 + ln];
    a0 += bflo(v.x); a1 += bfhi(v.x);
    a2 += bflo(v.y); a3 += bfhi(v.y);
    a4 += bflo(v.z); a5 += bfhi(v.z);
    a6 += bflo(v.w); a7 += bfhi(v.w);
  }
  float id = inv_deg[g];
  float z[8] = {a0 * id, a1 * id, a2 * id, a3 * id, a4 * id, a5 * id, a6 * id, a7 * id};
  bool valid = (ln < 5);  // lanes 0..4 own cols ln*8..ln*8+7 (40 total)
  if (valid) {
    float4 r0 = *(const float4*)(yr + (size_t)g * DOUT + ln * 8);
    float4 r1 = *(const float4*)(yr + (size_t)g * DOUT + ln * 8 + 4);
    z[0] += r0.x; z[1] += r0.y; z[2] += r0.z; z[3] += r0.w;
    z[4] += r1.x; z[5] += r1.y; z[6] += r1.z; z[7] += r1.w;
  }
  float zm = -INFINITY;
  if (valid)
#pragma unroll
    for (int i = 0; i < 8; ++i) zm = fmaxf(zm, z[i]);
#pragma unroll
  for (int off = 1; off < 8; off <<= 1) zm = fmaxf(zm, __shfl_xor(zm, off, 8));
  float ssum = 0.f;
  if (valid)
#pragma unroll
    for (int i = 0; i < 8; ++i) ssum += expf(z[i] - zm);
#pragma unroll
  for (int off = 1; off < 8; off <<= 1) ssum += __shfl_xor(ssum, off, 8);
  float lse = zm + logf(ssum);
  if (valid) {
    float4 o0 = make_float4(z[0] - lse, z[1] - lse, z[2] - lse, z[3] - lse);
    float4 o1 = make_float4(z[4] - lse, z[5] - lse, z[6] - lse, z[7] - lse);
    *(float4*)(out + (size_t)g * DOUT + ln * 8) = o0;
    *(float4*)(out + (size_t)g * DOUT + ln * 8 + 4) = o1;
  }
}

// ---------------- launch ----------------
extern "C" void kernel_launch(void* const* d_in, const int* in_sizes, int n_in,
                              void* d_out, int out_size, void* d_ws, size_t ws_size,
                              hipStream_t stream) {
  const float* x   = (const float*)d_in[0];
  const int* esrc  = (const int*)d_in[1];
  const int* edst  = (const int*)d_in[2];
  const float* Wl0 = (const float*)d_in[3];
  const float* Wr0 = (const float*)d_in[4];
  const float* b0  = (const float*)d_in[5];
  const float* Wl1 = (const float*)d_in[6];
  const float* Wr1 = (const float*)d_in[7];
  const float* b1  = (const float*)d_in[8];
  const float* Wl2 = (const float*)d_in[9];
  const float* Wr2 = (const float*)d_in[10];
  const float* b2  = (const float*)d_in[11];
  float* out = (float*)d_out;

  char* ws = (char*)d_ws;
  size_t off = 0;
  auto carve = [&](size_t bytes) -> char* {
    char* p = ws + off;
    off = (off + bytes + 255) & ~(size_t)255;
    return p;
  };
  int* bucket_cnt    = (int*)carve((size_t)NBUCK * 4);
  int* bucket_base   = (int*)carve((size_t)(NBUCK + 1) * 4);
  int* bucket_cursor = (int*)carve((size_t)NBUCK * 4);
  int* row_start     = (int*)carve((size_t)(NN + 1) * 4);
  int* nbr           = (int*)carve((size_t)NE * 4);
  float* inv_deg     = (float*)carve((size_t)NN * 4);
  unsigned* pairs    = (unsigned*)carve((size_t)NE * 4);
  short8v* B0hi      = (short8v*)carve((size_t)64 * 64 * 16);
  short8v* B0lo      = (short8v*)carve((size_t)64 * 64 * 16);
  short8v* B1hi      = (short8v*)carve((size_t)64 * 64 * 16);
  short8v* B1lo      = (short8v*)carve((size_t)64 * 64 * 16);
  short8v* By2hi     = (short8v*)carve((size_t)20 * 64 * 16);
  short8v* By2lo     = (short8v*)carve((size_t)20 * 64 * 16);
  unsigned short* xb   = (unsigned short*)carve((size_t)NN * D * 2);
  unsigned short* bufA = (unsigned short*)carve((size_t)NN * D * 2);
  unsigned short* bufB = (unsigned short*)carve((size_t)NN * D * 2);
  unsigned short* bufC = (unsigned short*)carve((size_t)NN * D * 2);
  unsigned short* yl   = (unsigned short*)carve((size_t)NN * 64 * 2);
  float* yr            = (float*)carve((size_t)NN * DOUT * 4);
  if (off > ws_size) return;

  const int GRID_AGG = (NN + 15) / 16;       // 6250
  const int GRID_GEMM = (NN + 127) / 128;    // 782
  const int GRID_CVT = NN * D / 4 / 256;     // 12500
  const int GRID_AO = (NN + 31) / 32;        // 3125

  // CSR build (bucketed)
  hipMemsetAsync(bucket_cnt, 0, (size_t)NBUCK * 4, stream);
  bucket_hist_kernel<<<NCHUNK, 256, 0, stream>>>(edst, bucket_cnt);
  bucket_scan_kernel<<<1, 512, 0, stream>>>(bucket_cnt, bucket_base, bucket_cursor);
  binned_scatter_kernel<<<NCHUNK, 256, 0, stream>>>(esrc, edst, bucket_cursor, pairs);
  bucket_build_kernel<<<NBUCK, 256, 0, stream>>>(pairs, bucket_base, row_start, nbr, inv_deg);

  // feature / weight prep
  cvt_bf16_kernel<<<GRID_CVT, 256, 0, stream>>>(x, xb);
  prep_w_kernel<<<64, 64, 0, stream>>>(Wl0, Wr0, B0hi, B0lo);
  prep_w_kernel<<<64, 64, 0, stream>>>(Wl1, Wr1, B1hi, B1lo);
  prep_wy2_kernel<<<20, 64, 0, stream>>>(Wl2, Wr2, By2hi, By2lo);
  hipMemsetAsync(yl, 0, (size_t)NN * 64 * 2, stream);  // pad cols 40..63 stay zero

  // layer 0
  agg_kernel<<<GRID_AGG, 256, 0, stream>>>(xb, bufA, row_start, nbr, inv_deg);
  mfma_gemm_kernel<<<GRID_GEMM, 256, 0, stream>>>(bufA, xb, B0hi, B0lo, b0, bufB);
  // layer 1
  agg_kernel<<<GRID_AGG, 256, 0, stream>>>(bufB, bufA, row_start, nbr, inv_deg);
  mfma_gemm_kernel<<<GRID_GEMM, 256, 0, stream>>>(bufA, bufB, B1hi, B1lo, b1, bufC);
  // layer 2: transform-then-aggregate (agg commutes with the linear map)
  mfma_y2_kernel<<<GRID_GEMM, 256, 0, stream>>>(bufC, By2hi, By2lo, b2, yl, yr);
  agg_out_kernel<<<GRID_AO, 256, 0, stream>>>(yl, yr, row_start, nbr, inv_deg, out);
}

// Round 6
// 321.336 us; speedup vs baseline: 4.0553x; 1.0778x over previous
//
#include <hip/hip_runtime.h>
#include <hip/hip_fp16.h>
#include <math.h>

#define NN 100000
#define NE 1600000
#define D 128
#define DOUT 40
#define NBUCK 391          // ceil(NN/256): bucket = 256 consecutive nodes
#define CHUNK 4096         // edges per binning workgroup
#define NCHUNK 391         // ceil(NE/CHUNK)

typedef _Float16 half8v __attribute__((ext_vector_type(8)));   // 8 f16 (4 VGPR)
typedef __attribute__((ext_vector_type(4))) float f32x4;

__device__ __forceinline__ float h2f_lo(unsigned u) {
  return __half2float(__ushort_as_half((unsigned short)(u & 0xffffu)));
}
__device__ __forceinline__ float h2f_hi(unsigned u) {
  return __half2float(__ushort_as_half((unsigned short)(u >> 16)));
}
__device__ __forceinline__ unsigned packh(float a, float b) {
  return (unsigned)__half_as_ushort(__float2half_rn(a)) |
         ((unsigned)__half_as_ushort(__float2half_rn(b)) << 16);
}

// ---------------- x -> f16 ----------------
__global__ __launch_bounds__(256) void cvt_f16_kernel(const float* __restrict__ in,
                                                      _Float16* __restrict__ out) {
  int i = (blockIdx.x * 256 + threadIdx.x) * 8;
  float4 v0 = *(const float4*)(in + i);
  float4 v1 = *(const float4*)(in + i + 4);
  uint4 o;
  o.x = packh(v0.x, v0.y);
  o.y = packh(v0.z, v0.w);
  o.z = packh(v1.x, v1.y);
  o.w = packh(v1.z, v1.w);
  *(uint4*)(out + i) = o;
}

// ---------------- CSR build: bucketed ----------------
__global__ __launch_bounds__(256) void bucket_hist_kernel(const int* __restrict__ dst,
                                                          int* __restrict__ bucket_cnt) {
  __shared__ int bc[NBUCK];
  int t = threadIdx.x;
  for (int i = t; i < NBUCK; i += 256) bc[i] = 0;
  __syncthreads();
  int e_base = blockIdx.x * CHUNK;
#pragma unroll
  for (int j = 0; j < 16; ++j) {
    int e = e_base + j * 256 + t;
    if (e < NE) atomicAdd(&bc[dst[e] >> 8], 1);
  }
  __syncthreads();
  for (int i = t; i < NBUCK; i += 256)
    if (bc[i]) atomicAdd(&bucket_cnt[i], bc[i]);
}

__global__ __launch_bounds__(512) void bucket_scan_kernel(const int* __restrict__ bucket_cnt,
                                                          int* __restrict__ bucket_base,
                                                          int* __restrict__ bucket_cursor) {
  __shared__ int s[512];
  int t = threadIdx.x;
  int c = (t < NBUCK) ? bucket_cnt[t] : 0;
  s[t] = c;
  __syncthreads();
  for (int off = 1; off < 512; off <<= 1) {
    int v = (t >= off) ? s[t - off] : 0;
    __syncthreads();
    s[t] += v;
    __syncthreads();
  }
  if (t < NBUCK) {
    int b = s[t] - c;
    bucket_base[t] = b;
    bucket_cursor[t] = b;
  }
  if (t == NBUCK) bucket_base[NBUCK] = s[NBUCK - 1];
}

// chunk-local LDS reorder, then bucket-contiguous coalesced writes
// payload: word = (dst&255)<<24 | src   (src < 2^24)
__global__ __launch_bounds__(256) void binned_scatter_kernel(const int* __restrict__ src,
                                                             const int* __restrict__ dst,
                                                             int* __restrict__ bucket_cursor,
                                                             unsigned* __restrict__ pairs) {
  __shared__ int lcnt[NBUCK];
  __shared__ int lscan[NBUCK];
  __shared__ int gb[NBUCK];
  __shared__ unsigned ebuf[CHUNK];
  __shared__ unsigned short bbuf[CHUNK];
  int t = threadIdx.x;
  int e_base = blockIdx.x * CHUNK;
  for (int i = t; i < NBUCK; i += 256) lcnt[i] = 0;
  __syncthreads();

  int myb[16], myrank[16];
  unsigned mye[16];
#pragma unroll
  for (int j = 0; j < 16; ++j) {
    int e = e_base + j * 256 + t;
    if (e < NE) {
      int d = dst[e];
      mye[j] = (unsigned)src[e] | ((unsigned)(d & 255) << 24);
      myb[j] = d >> 8;
      myrank[j] = atomicAdd(&lcnt[d >> 8], 1);
    } else {
      myb[j] = -1;
    }
  }
  __syncthreads();

  lscan[t] = lcnt[t];
  if (256 + t < NBUCK) lscan[256 + t] = lcnt[256 + t];
  __syncthreads();
  for (int off = 1; off < 512; off <<= 1) {
    int v0 = (t >= off) ? lscan[t - off] : 0;
    int v1 = 0;
    int i1 = 256 + t;
    if (i1 < NBUCK) v1 = lscan[i1 - off];
    __syncthreads();
    if (t >= off) lscan[t] += v0;
    if (i1 < NBUCK) lscan[i1] += v1;
    __syncthreads();
  }

#pragma unroll
  for (int j = 0; j < 16; ++j)
    if (myb[j] >= 0) {
      int b = myb[j];
      int lpos = lscan[b] - lcnt[b] + myrank[j];
      ebuf[lpos] = mye[j];
      bbuf[lpos] = (unsigned short)b;
    }
  for (int i = t; i < NBUCK; i += 256)
    if (lcnt[i] > 0) gb[i] = atomicAdd(&bucket_cursor[i], lcnt[i]);
  __syncthreads();

  int chunk_n = min(CHUNK, NE - e_base);
  for (int s2 = t; s2 < chunk_n; s2 += 256) {
    int b = bbuf[s2];
    int g = gb[b] + (s2 - (lscan[b] - lcnt[b]));
    pairs[g] = ebuf[s2];
  }
}

// one workgroup per bucket: per-node count, local scan -> row_start, fine scatter
__global__ __launch_bounds__(256) void bucket_build_kernel(const unsigned* __restrict__ pairs,
                                                           const int* __restrict__ bucket_base,
                                                           int* __restrict__ row_start,
                                                           int* __restrict__ nbr,
                                                           float* __restrict__ inv_deg) {
  __shared__ int cnt[256], loc[256], cur[256];
  int b = blockIdx.x;
  int t = threadIdx.x;
  int nbase = b << 8;
  int e0 = bucket_base[b], e1 = bucket_base[b + 1];
  cnt[t] = 0;
  __syncthreads();
  for (int e = e0 + t; e < e1; e += 256) {
    int d = (int)(pairs[e] >> 24);
    atomicAdd(&cnt[d], 1);
  }
  __syncthreads();
  loc[t] = cnt[t];
  __syncthreads();
  for (int off = 1; off < 256; off <<= 1) {
    int v = (t >= off) ? loc[t - off] : 0;
    __syncthreads();
    loc[t] += v;
    __syncthreads();
  }
  int excl = loc[t] - cnt[t];
  int node = nbase + t;
  if (node < NN) {
    row_start[node] = e0 + excl;
    inv_deg[node] = 1.0f / (float)(cnt[t] > 1 ? cnt[t] : 1);
  }
  cur[t] = excl;
  if (b == NBUCK - 1 && t == 0) row_start[NN] = NE;
  __syncthreads();
  for (int e = e0 + t; e < e1; e += 256) {
    unsigned pr = pairs[e];
    int d = (int)(pr >> 24);
    int p = atomicAdd(&cur[d], 1);
    nbr[e0 + p] = (int)(pr & 0xFFFFFFu);
  }
}

// ---------------- mean aggregation (f16 rows, 16 lanes/node, unroll 8) ----------------
#define ACC8(v)                                   \
  a0 += h2f_lo((v).x); a1 += h2f_hi((v).x);       \
  a2 += h2f_lo((v).y); a3 += h2f_hi((v).y);       \
  a4 += h2f_lo((v).z); a5 += h2f_hi((v).z);       \
  a6 += h2f_lo((v).w); a7 += h2f_hi((v).w);

__global__ __launch_bounds__(256) void agg_kernel(const _Float16* __restrict__ X,
                                                  _Float16* __restrict__ out,
                                                  const int* __restrict__ row_start,
                                                  const int* __restrict__ nbr,
                                                  const float* __restrict__ inv_deg) {
  int g = blockIdx.x * 16 + (threadIdx.x >> 4);
  int lane = threadIdx.x & 15;
  if (g >= NN) return;
  int p0 = row_start[g];
  int p1 = row_start[g + 1];
  const uint4* base = (const uint4*)X;  // row = 16 uint4
  float a0 = 0.f, a1 = 0.f, a2 = 0.f, a3 = 0.f, a4 = 0.f, a5 = 0.f, a6 = 0.f, a7 = 0.f;
  int p = p0;
  for (; p + 7 < p1; p += 8) {
    int s0 = nbr[p], s1 = nbr[p + 1], s2 = nbr[p + 2], s3 = nbr[p + 3];
    int s4 = nbr[p + 4], s5 = nbr[p + 5], s6 = nbr[p + 6], s7 = nbr[p + 7];
    uint4 v0 = base[(size_t)s0 * 16 + lane];
    uint4 v1 = base[(size_t)s1 * 16 + lane];
    uint4 v2 = base[(size_t)s2 * 16 + lane];
    uint4 v3 = base[(size_t)s3 * 16 + lane];
    uint4 v4 = base[(size_t)s4 * 16 + lane];
    uint4 v5 = base[(size_t)s5 * 16 + lane];
    uint4 v6 = base[(size_t)s6 * 16 + lane];
    uint4 v7 = base[(size_t)s7 * 16 + lane];
    ACC8(v0) ACC8(v1) ACC8(v2) ACC8(v3) ACC8(v4) ACC8(v5) ACC8(v6) ACC8(v7)
  }
  for (; p + 3 < p1; p += 4) {
    int s0 = nbr[p], s1 = nbr[p + 1], s2 = nbr[p + 2], s3 = nbr[p + 3];
    uint4 v0 = base[(size_t)s0 * 16 + lane];
    uint4 v1 = base[(size_t)s1 * 16 + lane];
    uint4 v2 = base[(size_t)s2 * 16 + lane];
    uint4 v3 = base[(size_t)s3 * 16 + lane];
    ACC8(v0) ACC8(v1) ACC8(v2) ACC8(v3)
  }
  for (; p < p1; ++p) {
    uint4 v = base[(size_t)nbr[p] * 16 + lane];
    ACC8(v)
  }
  float id = inv_deg[g];
  uint4 o;
  o.x = packh(a0 * id, a1 * id);
  o.y = packh(a2 * id, a3 * id);
  o.z = packh(a4 * id, a5 * id);
  o.w = packh(a6 * id, a7 * id);
  ((uint4*)out)[(size_t)g * 16 + lane] = o;
}

// ---------------- weight prep: fragment-ordered f16 planes (layers 0/1) ----------------
// Bcat[k][c] = (k<128 ? Wl[c][k] : Wr[c][k-128]);
// plane[((s*8+n)*64+l)] = Bcat[s*32 + (l>>4)*8 + i][n*16 + (l&15)]
__global__ __launch_bounds__(64) void prep_w_kernel(const float* __restrict__ Wl,
                                                    const float* __restrict__ Wr,
                                                    half8v* __restrict__ P) {
  int s = blockIdx.x >> 3;
  int n = blockIdx.x & 7;
  int l = threadIdx.x;
  int k0 = s * 32 + (l >> 4) * 8;
  int c = n * 16 + (l & 15);
  const float* W = (k0 < 128) ? Wl : Wr;
  int kb = (k0 < 128) ? k0 : k0 - 128;
  half8v h;
#pragma unroll
  for (int i = 0; i < 8; ++i) h[i] = (_Float16)W[c * 128 + kb + i];
  P[blockIdx.x * 64 + l] = h;
}

// layer 2: cols 0..39 = Wl2 rows, 40..79 = Wr2 rows (K=128); plane[((s*5+n)*64+l)]
__global__ __launch_bounds__(64) void prep_wy2_kernel(const float* __restrict__ Wl,
                                                      const float* __restrict__ Wr,
                                                      half8v* __restrict__ P) {
  int s = blockIdx.x / 5;
  int n = blockIdx.x % 5;
  int l = threadIdx.x;
  int k0 = s * 32 + (l >> 4) * 8;
  int c = n * 16 + (l & 15);  // 0..79
  const float* W = (c < DOUT) ? Wl : Wr;
  int row = (c < DOUT) ? c : c - DOUT;
  half8v h;
#pragma unroll
  for (int i = 0; i < 8; ++i) h[i] = (_Float16)W[row * 128 + k0 + i];
  P[blockIdx.x * 64 + l] = h;
}

// ---------------- layers 0/1: out = relu([A|H] @ Bcat + b), f16 MFMA ----------------
__global__ __launch_bounds__(256) void mfma_gemm_kernel(
    const _Float16* __restrict__ A, const _Float16* __restrict__ H,
    const half8v* __restrict__ B, const float* __restrict__ bias,
    _Float16* __restrict__ out) {
  __shared__ _Float16 As[128 * 40];  // row stride 40 halfs (80B)

  int t = threadIdx.x;
  int w = t >> 6, l = t & 63;
  int R0 = blockIdx.x * 128;
  int lc = l & 15;
  int lg = l >> 4;

  f32x4 acc[2][8];
#pragma unroll
  for (int m = 0; m < 2; ++m)
#pragma unroll
    for (int n = 0; n < 8; ++n) acc[m][n] = (f32x4){0.f, 0.f, 0.f, 0.f};

  for (int s = 0; s < 8; ++s) {
    const _Float16* src = (s < 4) ? A : H;
    int koff = (s & 3) * 32;
#pragma unroll
    for (int c = 0; c < 2; ++c) {
      int chunk = t + c * 256;
      int row = chunk >> 2, seg = chunk & 3;
      int gr = R0 + row;
      uint4 v = make_uint4(0, 0, 0, 0);
      if (gr < NN) v = *(const uint4*)(src + (size_t)gr * D + koff + seg * 8);
      *(uint4*)&As[row * 40 + seg * 8] = v;
    }
    __syncthreads();

    half8v bh[8];
#pragma unroll
    for (int n = 0; n < 8; ++n) bh[n] = B[(s * 8 + n) * 64 + l];

    half8v ah[2];
#pragma unroll
    for (int m = 0; m < 2; ++m) {
      int r = w * 32 + m * 16 + lc;
      ah[m] = *(const half8v*)&As[r * 40 + lg * 8];
    }

#pragma unroll
    for (int n = 0; n < 8; ++n)
#pragma unroll
      for (int m = 0; m < 2; ++m)
        acc[m][n] = __builtin_amdgcn_mfma_f32_16x16x32_f16(ah[m], bh[n], acc[m][n], 0, 0, 0);
    __syncthreads();
  }

  float bcol[8];
#pragma unroll
  for (int n = 0; n < 8; ++n) bcol[n] = bias[n * 16 + lc];
#pragma unroll
  for (int m = 0; m < 2; ++m)
#pragma unroll
    for (int n = 0; n < 8; ++n) {
      int col = n * 16 + lc;
#pragma unroll
      for (int j = 0; j < 4; ++j) {
        int gr = R0 + w * 32 + m * 16 + lg * 4 + j;
        if (gr < NN)
          out[(size_t)gr * D + col] = (_Float16)fmaxf(acc[m][n][j] + bcol[n], 0.f);
      }
    }
}

// ---------------- layer 2 GEMM: y = h2 @ [Wl2|Wr2]^T; y_l f16 N x 64 (pad), y_r f32 N x 40 (+b2) ----------------
__global__ __launch_bounds__(256) void mfma_y2_kernel(
    const _Float16* __restrict__ H, const half8v* __restrict__ B,
    const float* __restrict__ b2,
    _Float16* __restrict__ yl, float* __restrict__ yr) {
  __shared__ _Float16 As[128 * 40];

  int t = threadIdx.x;
  int w = t >> 6, l = t & 63;
  int R0 = blockIdx.x * 128;
  int lc = l & 15;
  int lg = l >> 4;

  f32x4 acc[2][5];
#pragma unroll
  for (int m = 0; m < 2; ++m)
#pragma unroll
    for (int n = 0; n < 5; ++n) acc[m][n] = (f32x4){0.f, 0.f, 0.f, 0.f};

  for (int s = 0; s < 4; ++s) {
    int koff = s * 32;
#pragma unroll
    for (int c = 0; c < 2; ++c) {
      int chunk = t + c * 256;
      int row = chunk >> 2, seg = chunk & 3;
      int gr = R0 + row;
      uint4 v = make_uint4(0, 0, 0, 0);
      if (gr < NN) v = *(const uint4*)(H + (size_t)gr * D + koff + seg * 8);
      *(uint4*)&As[row * 40 + seg * 8] = v;
    }
    __syncthreads();

    half8v bh[5];
#pragma unroll
    for (int n = 0; n < 5; ++n) bh[n] = B[(s * 5 + n) * 64 + l];

    half8v ah[2];
#pragma unroll
    for (int m = 0; m < 2; ++m) {
      int r = w * 32 + m * 16 + lc;
      ah[m] = *(const half8v*)&As[r * 40 + lg * 8];
    }

#pragma unroll
    for (int n = 0; n < 5; ++n)
#pragma unroll
      for (int m = 0; m < 2; ++m)
        acc[m][n] = __builtin_amdgcn_mfma_f32_16x16x32_f16(ah[m], bh[n], acc[m][n], 0, 0, 0);
    __syncthreads();
  }

#pragma unroll
  for (int m = 0; m < 2; ++m)
#pragma unroll
    for (int n = 0; n < 5; ++n) {
      int col = n * 16 + lc;
#pragma unroll
      for (int j = 0; j < 4; ++j) {
        int gr = R0 + w * 32 + m * 16 + lg * 4 + j;
        if (gr < NN) {
          if (col < DOUT) {
            yl[(size_t)gr * 64 + col] = (_Float16)acc[m][n][j];
          } else if (col >= 40 && col < 80) {
            yr[(size_t)gr * DOUT + (col - DOUT)] = acc[m][n][j] + b2[col - DOUT];
          }
        }
      }
    }
}

// ---------------- fused layer-2 agg + log_softmax: 8 lanes/node on 64-col padded y_l ----------------
__global__ __launch_bounds__(256) void agg_out_kernel(const _Float16* __restrict__ yl,
                                                      const float* __restrict__ yr,
                                                      const int* __restrict__ row_start,
                                                      const int* __restrict__ nbr,
                                                      const float* __restrict__ inv_deg,
                                                      float* __restrict__ out) {
  int g = blockIdx.x * 32 + (threadIdx.x >> 3);
  int ln = threadIdx.x & 7;
  if (g >= NN) return;
  int p0 = row_start[g];
  int p1 = row_start[g + 1];
  const uint4* base = (const uint4*)yl;  // row = 8 uint4
  float a0 = 0.f, a1 = 0.f, a2 = 0.f, a3 = 0.f, a4 = 0.f, a5 = 0.f, a6 = 0.f, a7 = 0.f;
  int p = p0;
  for (; p + 7 < p1; p += 8) {
    int s0 = nbr[p], s1 = nbr[p + 1], s2 = nbr[p + 2], s3 = nbr[p + 3];
    int s4 = nbr[p + 4], s5 = nbr[p + 5], s6 = nbr[p + 6], s7 = nbr[p + 7];
    uint4 v0 = base[(size_t)s0 * 8 + ln];
    uint4 v1 = base[(size_t)s1 * 8 + ln];
    uint4 v2 = base[(size_t)s2 * 8 + ln];
    uint4 v3 = base[(size_t)s3 * 8 + ln];
    uint4 v4 = base[(size_t)s4 * 8 + ln];
    uint4 v5 = base[(size_t)s5 * 8 + ln];
    uint4 v6 = base[(size_t)s6 * 8 + ln];
    uint4 v7 = base[(size_t)s7 * 8 + ln];
    ACC8(v0) ACC8(v1) ACC8(v2) ACC8(v3) ACC8(v4) ACC8(v5) ACC8(v6) ACC8(v7)
  }
  for (; p + 3 < p1; p += 4) {
    int s0 = nbr[p], s1 = nbr[p + 1], s2 = nbr[p + 2], s3 = nbr[p + 3];
    uint4 v0 = base[(size_t)s0 * 8 + ln];
    uint4 v1 = base[(size_t)s1 * 8 + ln];
    uint4 v2 = base[(size_t)s2 * 8 + ln];
    uint4 v3 = base[(size_t)s3 * 8 + ln];
    ACC8(v0) ACC8(v1) ACC8(v2) ACC8(v3)
  }
  for (; p < p1; ++p) {
    uint4 v = base[(size_t)nbr[p] * 8 + ln];
    ACC8(v)
  }
  float id = inv_deg[g];
  float z[8] = {a0 * id, a1 * id, a2 * id, a3 * id, a4 * id, a5 * id, a6 * id, a7 * id};
  bool valid = (ln < 5);  // lanes 0..4 own cols ln*8..ln*8+7 (40 total)
  if (valid) {
    float4 r0 = *(const float4*)(yr + (size_t)g * DOUT + ln * 8);
    float4 r1 = *(const float4*)(yr + (size_t)g * DOUT + ln * 8 + 4);
    z[0] += r0.x; z[1] += r0.y; z[2] += r0.z; z[3] += r0.w;
    z[4] += r1.x; z[5] += r1.y; z[6] += r1.z; z[7] += r1.w;
  }
  float zm = -INFINITY;
  if (valid)
#pragma unroll
    for (int i = 0; i < 8; ++i) zm = fmaxf(zm, z[i]);
#pragma unroll
  for (int off = 1; off < 8; off <<= 1) zm = fmaxf(zm, __shfl_xor(zm, off, 8));
  float ssum = 0.f;
  if (valid)
#pragma unroll
    for (int i = 0; i < 8; ++i) ssum += expf(z[i] - zm);
#pragma unroll
  for (int off = 1; off < 8; off <<= 1) ssum += __shfl_xor(ssum, off, 8);
  float lse = zm + logf(ssum);
  if (valid) {
    float4 o0 = make_float4(z[0] - lse, z[1] - lse, z[2] - lse, z[3] - lse);
    float4 o1 = make_float4(z[4] - lse, z[5] - lse, z[6] - lse, z[7] - lse);
    *(float4*)(out + (size_t)g * DOUT + ln * 8) = o0;
    *(float4*)(out + (size_t)g * DOUT + ln * 8 + 4) = o1;
  }
}

// ---------------- launch ----------------
extern "C" void kernel_launch(void* const* d_in, const int* in_sizes, int n_in,
                              void* d_out, int out_size, void* d_ws, size_t ws_size,
                              hipStream_t stream) {
  const float* x   = (const float*)d_in[0];
  const int* esrc  = (const int*)d_in[1];
  const int* edst  = (const int*)d_in[2];
  const float* Wl0 = (const float*)d_in[3];
  const float* Wr0 = (const float*)d_in[4];
  const float* b0  = (const float*)d_in[5];
  const float* Wl1 = (const float*)d_in[6];
  const float* Wr1 = (const float*)d_in[7];
  const float* b1  = (const float*)d_in[8];
  const float* Wl2 = (const float*)d_in[9];
  const float* Wr2 = (const float*)d_in[10];
  const float* b2  = (const float*)d_in[11];
  float* out = (float*)d_out;

  char* ws = (char*)d_ws;
  size_t off = 0;
  auto carve = [&](size_t bytes) -> char* {
    char* p = ws + off;
    off = (off + bytes + 255) & ~(size_t)255;
    return p;
  };
  int* bucket_cnt    = (int*)carve((size_t)NBUCK * 4);
  int* bucket_base   = (int*)carve((size_t)(NBUCK + 1) * 4);
  int* bucket_cursor = (int*)carve((size_t)NBUCK * 4);
  int* row_start     = (int*)carve((size_t)(NN + 1) * 4);
  int* nbr           = (int*)carve((size_t)NE * 4);
  float* inv_deg     = (float*)carve((size_t)NN * 4);
  unsigned* pairs    = (unsigned*)carve((size_t)NE * 4);
  half8v* B0         = (half8v*)carve((size_t)64 * 64 * 16);
  half8v* B1         = (half8v*)carve((size_t)64 * 64 * 16);
  half8v* By2        = (half8v*)carve((size_t)20 * 64 * 16);
  _Float16* xb   = (_Float16*)carve((size_t)NN * D * 2);
  _Float16* bufA = (_Float16*)carve((size_t)NN * D * 2);
  _Float16* bufB = (_Float16*)carve((size_t)NN * D * 2);
  _Float16* bufC = (_Float16*)carve((size_t)NN * D * 2);
  _Float16* yl   = (_Float16*)carve((size_t)NN * 64 * 2);
  float* yr      = (float*)carve((size_t)NN * DOUT * 4);
  if (off > ws_size) return;

  const int GRID_AGG = (NN + 15) / 16;       // 6250
  const int GRID_GEMM = (NN + 127) / 128;    // 782
  const int GRID_CVT = NN * D / 8 / 256;     // 6250
  const int GRID_AO = (NN + 31) / 32;        // 3125

  // CSR build (bucketed)
  hipMemsetAsync(bucket_cnt, 0, (size_t)NBUCK * 4, stream);
  bucket_hist_kernel<<<NCHUNK, 256, 0, stream>>>(edst, bucket_cnt);
  bucket_scan_kernel<<<1, 512, 0, stream>>>(bucket_cnt, bucket_base, bucket_cursor);
  binned_scatter_kernel<<<NCHUNK, 256, 0, stream>>>(esrc, edst, bucket_cursor, pairs);
  bucket_build_kernel<<<NBUCK, 256, 0, stream>>>(pairs, bucket_base, row_start, nbr, inv_deg);

  // feature / weight prep
  cvt_f16_kernel<<<GRID_CVT, 256, 0, stream>>>(x, xb);
  prep_w_kernel<<<64, 64, 0, stream>>>(Wl0, Wr0, B0);
  prep_w_kernel<<<64, 64, 0, stream>>>(Wl1, Wr1, B1);
  prep_wy2_kernel<<<20, 64, 0, stream>>>(Wl2, Wr2, By2);
  hipMemsetAsync(yl, 0, (size_t)NN * 64 * 2, stream);  // pad cols 40..63 stay zero

  // layer 0
  agg_kernel<<<GRID_AGG, 256, 0, stream>>>(xb, bufA, row_start, nbr, inv_deg);
  mfma_gemm_kernel<<<GRID_GEMM, 256, 0, stream>>>(bufA, xb, B0, b0, bufB);
  // layer 1
  agg_kernel<<<GRID_AGG, 256, 0, stream>>>(bufB, bufA, row_start, nbr, inv_deg);
  mfma_gemm_kernel<<<GRID_GEMM, 256, 0, stream>>>(bufA, bufB, B1, b1, bufC);
  // layer 2: transform-then-aggregate (agg commutes with the linear map)
  mfma_y2_kernel<<<GRID_GEMM, 256, 0, stream>>>(bufC, By2, b2, yl, yr);
  agg_out_kernel<<<GRID_AO, 256, 0, stream>>>(yl, yr, row_start, nbr, inv_deg, out);
}

// Round 7
// 273.704 us; speedup vs baseline: 4.7610x; 1.1740x over previous
//
#include <hip/hip_runtime.h>
#include <hip/hip_fp16.h>
#include <math.h>

#define NN 100000
#define NE 1600000
#define D 128
#define DOUT 40
#define NBUCK 391          // ceil(NN/256): bucket = 256 consecutive nodes
#define CHUNK 4096         // edges per binning workgroup
#define NCHUNK 391         // ceil(NE/CHUNK)

typedef _Float16 half8v __attribute__((ext_vector_type(8)));   // 8 f16 (4 VGPR)
typedef __attribute__((ext_vector_type(4))) float f32x4;

__device__ __forceinline__ unsigned packh(float a, float b) {
  return (unsigned)__half_as_ushort(__float2half_rn(a)) |
         ((unsigned)__half_as_ushort(__float2half_rn(b)) << 16);
}
// fp8 e4m3 (OCP) helpers — HW converts on gfx950
__device__ __forceinline__ unsigned char f2fp8(float v) {
  return (unsigned char)(__builtin_amdgcn_cvt_pk_fp8_f32(v, v, 0, 0) & 0xff);
}
#define CVT2(u, s) __builtin_amdgcn_cvt_pk_f32_fp8((int)(u), s)
// accumulate 16 fp8 (one uint4) into a[0..15]
#define ACCR(v) { auto q = CVT2((v).x, 0); a[0] += q[0]; a[1] += q[1];   \
  q = CVT2((v).x, 1); a[2] += q[0];  a[3] += q[1];                        \
  q = CVT2((v).y, 0); a[4] += q[0];  a[5] += q[1];                        \
  q = CVT2((v).y, 1); a[6] += q[0];  a[7] += q[1];                        \
  q = CVT2((v).z, 0); a[8] += q[0];  a[9] += q[1];                        \
  q = CVT2((v).z, 1); a[10] += q[0]; a[11] += q[1];                       \
  q = CVT2((v).w, 0); a[12] += q[0]; a[13] += q[1];                       \
  q = CVT2((v).w, 1); a[14] += q[0]; a[15] += q[1]; }
// accumulate 8 fp8 (one uint2) into a[0..7]
#define ACCR8(v) { auto q = CVT2((v).x, 0); a[0] += q[0]; a[1] += q[1];  \
  q = CVT2((v).x, 1); a[2] += q[0]; a[3] += q[1];                         \
  q = CVT2((v).y, 0); a[4] += q[0]; a[5] += q[1];                         \
  q = CVT2((v).y, 1); a[6] += q[0]; a[7] += q[1]; }

// ---------------- x -> f16 + fp8 ----------------
__global__ __launch_bounds__(256) void cvt_kernel(const float* __restrict__ in,
                                                  _Float16* __restrict__ outh,
                                                  unsigned char* __restrict__ out8) {
  int i = (blockIdx.x * 256 + threadIdx.x) * 8;
  float4 v0 = *(const float4*)(in + i);
  float4 v1 = *(const float4*)(in + i + 4);
  uint4 oh;
  oh.x = packh(v0.x, v0.y);
  oh.y = packh(v0.z, v0.w);
  oh.z = packh(v1.x, v1.y);
  oh.w = packh(v1.z, v1.w);
  *(uint4*)(outh + i) = oh;
  unsigned w0 = __builtin_amdgcn_cvt_pk_fp8_f32(v0.x, v0.y, 0, 0);
  w0 = __builtin_amdgcn_cvt_pk_fp8_f32(v0.z, v0.w, w0, 1);
  unsigned w1 = __builtin_amdgcn_cvt_pk_fp8_f32(v1.x, v1.y, 0, 0);
  w1 = __builtin_amdgcn_cvt_pk_fp8_f32(v1.z, v1.w, w1, 1);
  *(uint2*)(out8 + i) = make_uint2(w0, w1);
}

// ---------------- CSR build: bucketed ----------------
__global__ __launch_bounds__(256) void bucket_hist_kernel(const int* __restrict__ dst,
                                                          int* __restrict__ bucket_cnt) {
  __shared__ int bc[NBUCK];
  int t = threadIdx.x;
  for (int i = t; i < NBUCK; i += 256) bc[i] = 0;
  __syncthreads();
  int e_base = blockIdx.x * CHUNK;
#pragma unroll
  for (int j = 0; j < 16; ++j) {
    int e = e_base + j * 256 + t;
    if (e < NE) atomicAdd(&bc[dst[e] >> 8], 1);
  }
  __syncthreads();
  for (int i = t; i < NBUCK; i += 256)
    if (bc[i]) atomicAdd(&bucket_cnt[i], bc[i]);
}

__global__ __launch_bounds__(512) void bucket_scan_kernel(const int* __restrict__ bucket_cnt,
                                                          int* __restrict__ bucket_base,
                                                          int* __restrict__ bucket_cursor) {
  __shared__ int s[512];
  int t = threadIdx.x;
  int c = (t < NBUCK) ? bucket_cnt[t] : 0;
  s[t] = c;
  __syncthreads();
  for (int off = 1; off < 512; off <<= 1) {
    int v = (t >= off) ? s[t - off] : 0;
    __syncthreads();
    s[t] += v;
    __syncthreads();
  }
  if (t < NBUCK) {
    int b = s[t] - c;
    bucket_base[t] = b;
    bucket_cursor[t] = b;
  }
  if (t == NBUCK) bucket_base[NBUCK] = s[NBUCK - 1];
}

// chunk-local LDS reorder, then bucket-contiguous coalesced writes
// payload: word = (dst&255)<<24 | src   (src < 2^24)
__global__ __launch_bounds__(256) void binned_scatter_kernel(const int* __restrict__ src,
                                                             const int* __restrict__ dst,
                                                             int* __restrict__ bucket_cursor,
                                                             unsigned* __restrict__ pairs) {
  __shared__ int lcnt[NBUCK];
  __shared__ int lscan[NBUCK];
  __shared__ int gb[NBUCK];
  __shared__ unsigned ebuf[CHUNK];
  __shared__ unsigned short bbuf[CHUNK];
  int t = threadIdx.x;
  int e_base = blockIdx.x * CHUNK;
  for (int i = t; i < NBUCK; i += 256) lcnt[i] = 0;
  __syncthreads();

  int myb[16], myrank[16];
  unsigned mye[16];
#pragma unroll
  for (int j = 0; j < 16; ++j) {
    int e = e_base + j * 256 + t;
    if (e < NE) {
      int d = dst[e];
      mye[j] = (unsigned)src[e] | ((unsigned)(d & 255) << 24);
      myb[j] = d >> 8;
      myrank[j] = atomicAdd(&lcnt[d >> 8], 1);
    } else {
      myb[j] = -1;
    }
  }
  __syncthreads();

  lscan[t] = lcnt[t];
  if (256 + t < NBUCK) lscan[256 + t] = lcnt[256 + t];
  __syncthreads();
  for (int off = 1; off < 512; off <<= 1) {
    int v0 = (t >= off) ? lscan[t - off] : 0;
    int v1 = 0;
    int i1 = 256 + t;
    if (i1 < NBUCK) v1 = lscan[i1 - off];
    __syncthreads();
    if (t >= off) lscan[t] += v0;
    if (i1 < NBUCK) lscan[i1] += v1;
    __syncthreads();
  }

#pragma unroll
  for (int j = 0; j < 16; ++j)
    if (myb[j] >= 0) {
      int b = myb[j];
      int lpos = lscan[b] - lcnt[b] + myrank[j];
      ebuf[lpos] = mye[j];
      bbuf[lpos] = (unsigned short)b;
    }
  for (int i = t; i < NBUCK; i += 256)
    if (lcnt[i] > 0) gb[i] = atomicAdd(&bucket_cursor[i], lcnt[i]);
  __syncthreads();

  int chunk_n = min(CHUNK, NE - e_base);
  for (int s2 = t; s2 < chunk_n; s2 += 256) {
    int b = bbuf[s2];
    int g = gb[b] + (s2 - (lscan[b] - lcnt[b]));
    pairs[g] = ebuf[s2];
  }
}

// one workgroup per bucket: per-node count, local scan -> row_start, fine scatter
__global__ __launch_bounds__(256) void bucket_build_kernel(const unsigned* __restrict__ pairs,
                                                           const int* __restrict__ bucket_base,
                                                           int* __restrict__ row_start,
                                                           int* __restrict__ nbr,
                                                           float* __restrict__ inv_deg) {
  __shared__ int cnt[256], loc[256], cur[256];
  int b = blockIdx.x;
  int t = threadIdx.x;
  int nbase = b << 8;
  int e0 = bucket_base[b], e1 = bucket_base[b + 1];
  cnt[t] = 0;
  __syncthreads();
  for (int e = e0 + t; e < e1; e += 256) {
    int d = (int)(pairs[e] >> 24);
    atomicAdd(&cnt[d], 1);
  }
  __syncthreads();
  loc[t] = cnt[t];
  __syncthreads();
  for (int off = 1; off < 256; off <<= 1) {
    int v = (t >= off) ? loc[t - off] : 0;
    __syncthreads();
    loc[t] += v;
    __syncthreads();
  }
  int excl = loc[t] - cnt[t];
  int node = nbase + t;
  if (node < NN) {
    row_start[node] = e0 + excl;
    inv_deg[node] = 1.0f / (float)(cnt[t] > 1 ? cnt[t] : 1);
  }
  cur[t] = excl;
  if (b == NBUCK - 1 && t == 0) row_start[NN] = NE;
  __syncthreads();
  for (int e = e0 + t; e < e1; e += 256) {
    unsigned pr = pairs[e];
    int d = (int)(pr >> 24);
    int p = atomicAdd(&cur[d], 1);
    nbr[e0 + p] = (int)(pr & 0xFFFFFFu);
  }
}

// ---------------- mean aggregation: fp8 in (128B rows), f16 out; 8 lanes/node ----------------
__global__ __launch_bounds__(256) void agg_kernel(const unsigned char* __restrict__ X8,
                                                  _Float16* __restrict__ out,
                                                  const int* __restrict__ row_start,
                                                  const int* __restrict__ nbr,
                                                  const float* __restrict__ inv_deg) {
  int g = blockIdx.x * 32 + (threadIdx.x >> 3);
  int ln = threadIdx.x & 7;
  if (g >= NN) return;
  int p0 = row_start[g];
  int p1 = row_start[g + 1];
  const uint4* base = (const uint4*)X8;  // row = 8 uint4 (128 B)
  float a[16];
#pragma unroll
  for (int i = 0; i < 16; ++i) a[i] = 0.f;
  int p = p0;
  for (; p + 3 < p1; p += 4) {
    int s0 = nbr[p], s1 = nbr[p + 1], s2 = nbr[p + 2], s3 = nbr[p + 3];
    uint4 v0 = base[(size_t)s0 * 8 + ln];
    uint4 v1 = base[(size_t)s1 * 8 + ln];
    uint4 v2 = base[(size_t)s2 * 8 + ln];
    uint4 v3 = base[(size_t)s3 * 8 + ln];
    ACCR(v0) ACCR(v1) ACCR(v2) ACCR(v3)
  }
  for (; p < p1; ++p) {
    uint4 v = base[(size_t)nbr[p] * 8 + ln];
    ACCR(v)
  }
  float id = inv_deg[g];
  uint4 o0, o1;
  o0.x = packh(a[0] * id, a[1] * id);
  o0.y = packh(a[2] * id, a[3] * id);
  o0.z = packh(a[4] * id, a[5] * id);
  o0.w = packh(a[6] * id, a[7] * id);
  o1.x = packh(a[8] * id, a[9] * id);
  o1.y = packh(a[10] * id, a[11] * id);
  o1.z = packh(a[12] * id, a[13] * id);
  o1.w = packh(a[14] * id, a[15] * id);
  uint4* ob = (uint4*)out;
  ob[(size_t)g * 16 + ln * 2] = o0;
  ob[(size_t)g * 16 + ln * 2 + 1] = o1;
}

// ---------------- weight prep: fragment-ordered f16 planes ----------------
__global__ __launch_bounds__(64) void prep_w_kernel(const float* __restrict__ Wl,
                                                    const float* __restrict__ Wr,
                                                    half8v* __restrict__ P) {
  int s = blockIdx.x >> 3;
  int n = blockIdx.x & 7;
  int l = threadIdx.x;
  int k0 = s * 32 + (l >> 4) * 8;
  int c = n * 16 + (l & 15);
  const float* W = (k0 < 128) ? Wl : Wr;
  int kb = (k0 < 128) ? k0 : k0 - 128;
  half8v h;
#pragma unroll
  for (int i = 0; i < 8; ++i) h[i] = (_Float16)W[c * 128 + kb + i];
  P[blockIdx.x * 64 + l] = h;
}

// layer 2: cols 0..39 = Wl2 rows, 40..79 = Wr2 rows (K=128)
__global__ __launch_bounds__(64) void prep_wy2_kernel(const float* __restrict__ Wl,
                                                      const float* __restrict__ Wr,
                                                      half8v* __restrict__ P) {
  int s = blockIdx.x / 5;
  int n = blockIdx.x % 5;
  int l = threadIdx.x;
  int k0 = s * 32 + (l >> 4) * 8;
  int c = n * 16 + (l & 15);  // 0..79
  const float* W = (c < DOUT) ? Wl : Wr;
  int row = (c < DOUT) ? c : c - DOUT;
  half8v h;
#pragma unroll
  for (int i = 0; i < 8; ++i) h[i] = (_Float16)W[row * 128 + k0 + i];
  P[blockIdx.x * 64 + l] = h;
}

// ---------------- layers 0/1: out = relu([A|H] @ Bcat + b); optional fp8 copy ----------------
__global__ __launch_bounds__(256) void mfma_gemm_kernel(
    const _Float16* __restrict__ A, const _Float16* __restrict__ H,
    const half8v* __restrict__ B, const float* __restrict__ bias,
    _Float16* __restrict__ out, unsigned char* __restrict__ out8) {
  __shared__ _Float16 As[128 * 40];

  int t = threadIdx.x;
  int w = t >> 6, l = t & 63;
  int R0 = blockIdx.x * 128;
  int lc = l & 15;
  int lg = l >> 4;

  f32x4 acc[2][8];
#pragma unroll
  for (int m = 0; m < 2; ++m)
#pragma unroll
    for (int n = 0; n < 8; ++n) acc[m][n] = (f32x4){0.f, 0.f, 0.f, 0.f};

  for (int s = 0; s < 8; ++s) {
    const _Float16* src = (s < 4) ? A : H;
    int koff = (s & 3) * 32;
#pragma unroll
    for (int c = 0; c < 2; ++c) {
      int chunk = t + c * 256;
      int row = chunk >> 2, seg = chunk & 3;
      int gr = R0 + row;
      uint4 v = make_uint4(0, 0, 0, 0);
      if (gr < NN) v = *(const uint4*)(src + (size_t)gr * D + koff + seg * 8);
      *(uint4*)&As[row * 40 + seg * 8] = v;
    }
    __syncthreads();

    half8v bh[8];
#pragma unroll
    for (int n = 0; n < 8; ++n) bh[n] = B[(s * 8 + n) * 64 + l];

    half8v ah[2];
#pragma unroll
    for (int m = 0; m < 2; ++m) {
      int r = w * 32 + m * 16 + lc;
      ah[m] = *(const half8v*)&As[r * 40 + lg * 8];
    }

#pragma unroll
    for (int n = 0; n < 8; ++n)
#pragma unroll
      for (int m = 0; m < 2; ++m)
        acc[m][n] = __builtin_amdgcn_mfma_f32_16x16x32_f16(ah[m], bh[n], acc[m][n], 0, 0, 0);
    __syncthreads();
  }

  float bcol[8];
#pragma unroll
  for (int n = 0; n < 8; ++n) bcol[n] = bias[n * 16 + lc];
#pragma unroll
  for (int m = 0; m < 2; ++m)
#pragma unroll
    for (int n = 0; n < 8; ++n) {
      int col = n * 16 + lc;
#pragma unroll
      for (int j = 0; j < 4; ++j) {
        int gr = R0 + w * 32 + m * 16 + lg * 4 + j;
        if (gr < NN) {
          float v = fmaxf(acc[m][n][j] + bcol[n], 0.f);
          out[(size_t)gr * D + col] = (_Float16)v;
          if (out8) out8[(size_t)gr * D + col] = f2fp8(v);
        }
      }
    }
}

// ---------------- layer 2 GEMM: y = h2 @ [Wl2|Wr2]^T; yl fp8 N x 48 (pad 0), yr f32 N x 40 (+b2) ----------------
__global__ __launch_bounds__(256) void mfma_y2_kernel(
    const _Float16* __restrict__ H, const half8v* __restrict__ B,
    const float* __restrict__ b2,
    unsigned char* __restrict__ yl8, float* __restrict__ yr) {
  __shared__ _Float16 As[128 * 40];

  int t = threadIdx.x;
  int w = t >> 6, l = t & 63;
  int R0 = blockIdx.x * 128;
  int lc = l & 15;
  int lg = l >> 4;

  f32x4 acc[2][5];
#pragma unroll
  for (int m = 0; m < 2; ++m)
#pragma unroll
    for (int n = 0; n < 5; ++n) acc[m][n] = (f32x4){0.f, 0.f, 0.f, 0.f};

  for (int s = 0; s < 4; ++s) {
    int koff = s * 32;
#pragma unroll
    for (int c = 0; c < 2; ++c) {
      int chunk = t + c * 256;
      int row = chunk >> 2, seg = chunk & 3;
      int gr = R0 + row;
      uint4 v = make_uint4(0, 0, 0, 0);
      if (gr < NN) v = *(const uint4*)(H + (size_t)gr * D + koff + seg * 8);
      *(uint4*)&As[row * 40 + seg * 8] = v;
    }
    __syncthreads();

    half8v bh[5];
#pragma unroll
    for (int n = 0; n < 5; ++n) bh[n] = B[(s * 5 + n) * 64 + l];

    half8v ah[2];
#pragma unroll
    for (int m = 0; m < 2; ++m) {
      int r = w * 32 + m * 16 + lc;
      ah[m] = *(const half8v*)&As[r * 40 + lg * 8];
    }

#pragma unroll
    for (int n = 0; n < 5; ++n)
#pragma unroll
      for (int m = 0; m < 2; ++m)
        acc[m][n] = __builtin_amdgcn_mfma_f32_16x16x32_f16(ah[m], bh[n], acc[m][n], 0, 0, 0);
    __syncthreads();
  }

#pragma unroll
  for (int m = 0; m < 2; ++m)
#pragma unroll
    for (int n = 0; n < 5; ++n) {
      int col = n * 16 + lc;
#pragma unroll
      for (int j = 0; j < 4; ++j) {
        int gr = R0 + w * 32 + m * 16 + lg * 4 + j;
        if (gr < NN) {
          float v = acc[m][n][j];
          if (col < DOUT) {
            yl8[(size_t)gr * 48 + col] = f2fp8(v);
          } else {
            if (col < 48) yl8[(size_t)gr * 48 + col] = 0;  // pad
            yr[(size_t)gr * DOUT + (col - DOUT)] = v + b2[col - DOUT];
          }
        }
      }
    }
}

// ---------------- fused layer-2 agg + log_softmax: fp8 48B rows, 8 lanes/node ----------------
__global__ __launch_bounds__(256) void agg_out_kernel(const unsigned char* __restrict__ yl8,
                                                      const float* __restrict__ yr,
                                                      const int* __restrict__ row_start,
                                                      const int* __restrict__ nbr,
                                                      const float* __restrict__ inv_deg,
                                                      float* __restrict__ out) {
  int g = blockIdx.x * 32 + (threadIdx.x >> 3);
  int ln = threadIdx.x & 7;
  if (g >= NN) return;
  int lnc = (ln < 6) ? ln : 5;  // lanes 6,7 duplicate lane 5 (harmless)
  int p0 = row_start[g];
  int p1 = row_start[g + 1];
  const uint2* base = (const uint2*)yl8;  // row = 6 uint2 (48 B)
  float a[8];
#pragma unroll
  for (int i = 0; i < 8; ++i) a[i] = 0.f;
  int p = p0;
  for (; p + 3 < p1; p += 4) {
    int s0 = nbr[p], s1 = nbr[p + 1], s2 = nbr[p + 2], s3 = nbr[p + 3];
    uint2 v0 = base[(size_t)s0 * 6 + lnc];
    uint2 v1 = base[(size_t)s1 * 6 + lnc];
    uint2 v2 = base[(size_t)s2 * 6 + lnc];
    uint2 v3 = base[(size_t)s3 * 6 + lnc];
    ACCR8(v0) ACCR8(v1) ACCR8(v2) ACCR8(v3)
  }
  for (; p < p1; ++p) {
    uint2 v = base[(size_t)nbr[p] * 6 + lnc];
    ACCR8(v)
  }
  float id = inv_deg[g];
  float z[8];
#pragma unroll
  for (int i = 0; i < 8; ++i) z[i] = a[i] * id;
  bool valid = (ln < 5);  // lanes 0..4 own cols ln*8..ln*8+7 (40 total)
  if (valid) {
    float4 r0 = *(const float4*)(yr + (size_t)g * DOUT + ln * 8);
    float4 r1 = *(const float4*)(yr + (size_t)g * DOUT + ln * 8 + 4);
    z[0] += r0.x; z[1] += r0.y; z[2] += r0.z; z[3] += r0.w;
    z[4] += r1.x; z[5] += r1.y; z[6] += r1.z; z[7] += r1.w;
  }
  float zm = -INFINITY;
  if (valid)
#pragma unroll
    for (int i = 0; i < 8; ++i) zm = fmaxf(zm, z[i]);
#pragma unroll
  for (int off = 1; off < 8; off <<= 1) zm = fmaxf(zm, __shfl_xor(zm, off, 8));
  float ssum = 0.f;
  if (valid)
#pragma unroll
    for (int i = 0; i < 8; ++i) ssum += expf(z[i] - zm);
#pragma unroll
  for (int off = 1; off < 8; off <<= 1) ssum += __shfl_xor(ssum, off, 8);
  float lse = zm + logf(ssum);
  if (valid) {
    float4 o0 = make_float4(z[0] - lse, z[1] - lse, z[2] - lse, z[3] - lse);
    float4 o1 = make_float4(z[4] - lse, z[5] - lse, z[6] - lse, z[7] - lse);
    *(float4*)(out + (size_t)g * DOUT + ln * 8) = o0;
    *(float4*)(out + (size_t)g * DOUT + ln * 8 + 4) = o1;
  }
}

// ---------------- launch ----------------
extern "C" void kernel_launch(void* const* d_in, const int* in_sizes, int n_in,
                              void* d_out, int out_size, void* d_ws, size_t ws_size,
                              hipStream_t stream) {
  const float* x   = (const float*)d_in[0];
  const int* esrc  = (const int*)d_in[1];
  const int* edst  = (const int*)d_in[2];
  const float* Wl0 = (const float*)d_in[3];
  const float* Wr0 = (const float*)d_in[4];
  const float* b0  = (const float*)d_in[5];
  const float* Wl1 = (const float*)d_in[6];
  const float* Wr1 = (const float*)d_in[7];
  const float* b1  = (const float*)d_in[8];
  const float* Wl2 = (const float*)d_in[9];
  const float* Wr2 = (const float*)d_in[10];
  const float* b2  = (const float*)d_in[11];
  float* out = (float*)d_out;

  char* ws = (char*)d_ws;
  size_t off = 0;
  auto carve = [&](size_t bytes) -> char* {
    char* p = ws + off;
    off = (off + bytes + 255) & ~(size_t)255;
    return p;
  };
  int* bucket_cnt    = (int*)carve((size_t)NBUCK * 4);
  int* bucket_base   = (int*)carve((size_t)(NBUCK + 1) * 4);
  int* bucket_cursor = (int*)carve((size_t)NBUCK * 4);
  int* row_start     = (int*)carve((size_t)(NN + 1) * 4);
  int* nbr           = (int*)carve((size_t)NE * 4);
  float* inv_deg     = (float*)carve((size_t)NN * 4);
  unsigned* pairs    = (unsigned*)carve((size_t)NE * 4);
  half8v* B0         = (half8v*)carve((size_t)64 * 64 * 16);
  half8v* B1         = (half8v*)carve((size_t)64 * 64 * 16);
  half8v* By2        = (half8v*)carve((size_t)20 * 64 * 16);
  _Float16* xb   = (_Float16*)carve((size_t)NN * D * 2);
  unsigned char* x8    = (unsigned char*)carve((size_t)NN * D);
  _Float16* bufA = (_Float16*)carve((size_t)NN * D * 2);
  _Float16* bufB = (_Float16*)carve((size_t)NN * D * 2);
  unsigned char* bufB8 = (unsigned char*)carve((size_t)NN * D);
  _Float16* bufC = (_Float16*)carve((size_t)NN * D * 2);
  unsigned char* yl8   = (unsigned char*)carve((size_t)NN * 48);
  float* yr      = (float*)carve((size_t)NN * DOUT * 4);
  if (off > ws_size) return;

  const int GRID_AGG = (NN + 31) / 32;       // 3125
  const int GRID_GEMM = (NN + 127) / 128;    // 782
  const int GRID_CVT = NN * D / 8 / 256;     // 6250
  const int GRID_AO = (NN + 31) / 32;        // 3125

  // CSR build (bucketed)
  hipMemsetAsync(bucket_cnt, 0, (size_t)NBUCK * 4, stream);
  bucket_hist_kernel<<<NCHUNK, 256, 0, stream>>>(edst, bucket_cnt);
  bucket_scan_kernel<<<1, 512, 0, stream>>>(bucket_cnt, bucket_base, bucket_cursor);
  binned_scatter_kernel<<<NCHUNK, 256, 0, stream>>>(esrc, edst, bucket_cursor, pairs);
  bucket_build_kernel<<<NBUCK, 256, 0, stream>>>(pairs, bucket_base, row_start, nbr, inv_deg);

  // feature / weight prep
  cvt_kernel<<<GRID_CVT, 256, 0, stream>>>(x, xb, x8);
  prep_w_kernel<<<64, 64, 0, stream>>>(Wl0, Wr0, B0);
  prep_w_kernel<<<64, 64, 0, stream>>>(Wl1, Wr1, B1);
  prep_wy2_kernel<<<20, 64, 0, stream>>>(Wl2, Wr2, By2);

  // layer 0
  agg_kernel<<<GRID_AGG, 256, 0, stream>>>(x8, bufA, row_start, nbr, inv_deg);
  mfma_gemm_kernel<<<GRID_GEMM, 256, 0, stream>>>(bufA, xb, B0, b0, bufB, bufB8);
  // layer 1
  agg_kernel<<<GRID_AGG, 256, 0, stream>>>(bufB8, bufA, row_start, nbr, inv_deg);
  mfma_gemm_kernel<<<GRID_GEMM, 256, 0, stream>>>(bufA, bufB, B1, b1, bufC, nullptr);
  // layer 2: transform-then-aggregate (agg commutes with the linear map)
  mfma_y2_kernel<<<GRID_GEMM, 256, 0, stream>>>(bufC, By2, b2, yl8, yr);
  agg_out_kernel<<<GRID_AO, 256, 0, stream>>>(yl8, yr, row_start, nbr, inv_deg, out);
}

// Round 9
// 261.673 us; speedup vs baseline: 4.9799x; 1.0460x over previous
//
#include <hip/hip_runtime.h>
#include <hip/hip_fp16.h>
#include <math.h>

#define NN 100000
#define NE 1600000
#define D 128
#define DOUT 40
#define NBUCK 391          // ceil(NN/256): bucket = 256 consecutive nodes
#define CHUNK 4096         // edges per binning workgroup
#define NCHUNK 391         // ceil(NE/CHUNK)
#define LSTR 136           // LDS row stride in f16: 272B = 17*16B (aligned, 2-way max)

typedef _Float16 half8v __attribute__((ext_vector_type(8)));   // 8 f16 (4 VGPR)
typedef __attribute__((ext_vector_type(4))) float f32x4;

__device__ __forceinline__ unsigned packh(float a, float b) {
  return (unsigned)__half_as_ushort(__float2half_rn(a)) |
         ((unsigned)__half_as_ushort(__float2half_rn(b)) << 16);
}
// fp8 e4m3 (OCP) helpers — HW converts on gfx950
__device__ __forceinline__ unsigned char f2fp8(float v) {
  return (unsigned char)(__builtin_amdgcn_cvt_pk_fp8_f32(v, v, 0, 0) & 0xff);
}
#define CVT2(u, s) __builtin_amdgcn_cvt_pk_f32_fp8((int)(u), s)
// accumulate 16 fp8 (one uint4) into a[0..15]
#define ACCR(v) { auto q = CVT2((v).x, 0); a[0] += q[0]; a[1] += q[1];   \
  q = CVT2((v).x, 1); a[2] += q[0];  a[3] += q[1];                        \
  q = CVT2((v).y, 0); a[4] += q[0];  a[5] += q[1];                        \
  q = CVT2((v).y, 1); a[6] += q[0];  a[7] += q[1];                        \
  q = CVT2((v).z, 0); a[8] += q[0];  a[9] += q[1];                        \
  q = CVT2((v).z, 1); a[10] += q[0]; a[11] += q[1];                       \
  q = CVT2((v).w, 0); a[12] += q[0]; a[13] += q[1];                       \
  q = CVT2((v).w, 1); a[14] += q[0]; a[15] += q[1]; }
// accumulate 8 fp8 (one uint2) into a[0..7]
#define ACCR8(v) { auto q = CVT2((v).x, 0); a[0] += q[0]; a[1] += q[1];  \
  q = CVT2((v).x, 1); a[2] += q[0]; a[3] += q[1];                         \
  q = CVT2((v).y, 0); a[4] += q[0]; a[5] += q[1];                         \
  q = CVT2((v).y, 1); a[6] += q[0]; a[7] += q[1]; }

// ---------------- x -> f16 + fp8 ----------------
__global__ __launch_bounds__(256) void cvt_kernel(const float* __restrict__ in,
                                                  _Float16* __restrict__ outh,
                                                  unsigned char* __restrict__ out8) {
  int i = (blockIdx.x * 256 + threadIdx.x) * 8;
  float4 v0 = *(const float4*)(in + i);
  float4 v1 = *(const float4*)(in + i + 4);
  uint4 oh;
  oh.x = packh(v0.x, v0.y);
  oh.y = packh(v0.z, v0.w);
  oh.z = packh(v1.x, v1.y);
  oh.w = packh(v1.z, v1.w);
  *(uint4*)(outh + i) = oh;
  unsigned w0 = __builtin_amdgcn_cvt_pk_fp8_f32(v0.x, v0.y, 0, 0);
  w0 = __builtin_amdgcn_cvt_pk_fp8_f32(v0.z, v0.w, w0, 1);
  unsigned w1 = __builtin_amdgcn_cvt_pk_fp8_f32(v1.x, v1.y, 0, 0);
  w1 = __builtin_amdgcn_cvt_pk_fp8_f32(v1.z, v1.w, w1, 1);
  *(uint2*)(out8 + i) = make_uint2(w0, w1);
}

// ---------------- CSR build: bucketed ----------------
__global__ __launch_bounds__(256) void bucket_hist_kernel(const int* __restrict__ dst,
                                                          int* __restrict__ bucket_cnt) {
  __shared__ int bc[NBUCK];
  int t = threadIdx.x;
  for (int i = t; i < NBUCK; i += 256) bc[i] = 0;
  __syncthreads();
  int e_base = blockIdx.x * CHUNK;
#pragma unroll
  for (int j = 0; j < 16; ++j) {
    int e = e_base + j * 256 + t;
    if (e < NE) atomicAdd(&bc[dst[e] >> 8], 1);
  }
  __syncthreads();
  for (int i = t; i < NBUCK; i += 256)
    if (bc[i]) atomicAdd(&bucket_cnt[i], bc[i]);
}

__global__ __launch_bounds__(512) void bucket_scan_kernel(const int* __restrict__ bucket_cnt,
                                                          int* __restrict__ bucket_base,
                                                          int* __restrict__ bucket_cursor) {
  __shared__ int s[512];
  int t = threadIdx.x;
  int c = (t < NBUCK) ? bucket_cnt[t] : 0;
  s[t] = c;
  __syncthreads();
  for (int off = 1; off < 512; off <<= 1) {
    int v = (t >= off) ? s[t - off] : 0;
    __syncthreads();
    s[t] += v;
    __syncthreads();
  }
  if (t < NBUCK) {
    int b = s[t] - c;
    bucket_base[t] = b;
    bucket_cursor[t] = b;
  }
  if (t == NBUCK) bucket_base[NBUCK] = s[NBUCK - 1];
}

// chunk-local LDS reorder, then bucket-contiguous coalesced writes
// payload: word = (dst&255)<<24 | src   (src < 2^24)
__global__ __launch_bounds__(256) void binned_scatter_kernel(const int* __restrict__ src,
                                                             const int* __restrict__ dst,
                                                             int* __restrict__ bucket_cursor,
                                                             unsigned* __restrict__ pairs) {
  __shared__ int lcnt[NBUCK];
  __shared__ int lscan[NBUCK];
  __shared__ int gb[NBUCK];
  __shared__ unsigned ebuf[CHUNK];
  __shared__ unsigned short bbuf[CHUNK];
  int t = threadIdx.x;
  int e_base = blockIdx.x * CHUNK;
  for (int i = t; i < NBUCK; i += 256) lcnt[i] = 0;
  __syncthreads();

  int myb[16], myrank[16];
  unsigned mye[16];
#pragma unroll
  for (int j = 0; j < 16; ++j) {
    int e = e_base + j * 256 + t;
    if (e < NE) {
      int d = dst[e];
      mye[j] = (unsigned)src[e] | ((unsigned)(d & 255) << 24);
      myb[j] = d >> 8;
      myrank[j] = atomicAdd(&lcnt[d >> 8], 1);
    } else {
      myb[j] = -1;
    }
  }
  __syncthreads();

  lscan[t] = lcnt[t];
  if (256 + t < NBUCK) lscan[256 + t] = lcnt[256 + t];
  __syncthreads();
  for (int off = 1; off < 512; off <<= 1) {
    int v0 = (t >= off) ? lscan[t - off] : 0;
    int v1 = 0;
    int i1 = 256 + t;
    if (i1 < NBUCK) v1 = lscan[i1 - off];
    __syncthreads();
    if (t >= off) lscan[t] += v0;
    if (i1 < NBUCK) lscan[i1] += v1;
    __syncthreads();
  }

#pragma unroll
  for (int j = 0; j < 16; ++j)
    if (myb[j] >= 0) {
      int b = myb[j];
      int lpos = lscan[b] - lcnt[b] + myrank[j];
      ebuf[lpos] = mye[j];
      bbuf[lpos] = (unsigned short)b;
    }
  for (int i = t; i < NBUCK; i += 256)
    if (lcnt[i] > 0) gb[i] = atomicAdd(&bucket_cursor[i], lcnt[i]);
  __syncthreads();

  int chunk_n = min(CHUNK, NE - e_base);
  for (int s2 = t; s2 < chunk_n; s2 += 256) {
    int b = bbuf[s2];
    int g = gb[b] + (s2 - (lscan[b] - lcnt[b]));
    pairs[g] = ebuf[s2];
  }
}

// one workgroup per bucket: per-node count, local scan -> row_start, fine scatter
__global__ __launch_bounds__(256) void bucket_build_kernel(const unsigned* __restrict__ pairs,
                                                           const int* __restrict__ bucket_base,
                                                           int* __restrict__ row_start,
                                                           int* __restrict__ nbr,
                                                           float* __restrict__ inv_deg) {
  __shared__ int cnt[256], loc[256], cur[256];
  int b = blockIdx.x;
  int t = threadIdx.x;
  int nbase = b << 8;
  int e0 = bucket_base[b], e1 = bucket_base[b + 1];
  cnt[t] = 0;
  __syncthreads();
  for (int e = e0 + t; e < e1; e += 256) {
    int d = (int)(pairs[e] >> 24);
    atomicAdd(&cnt[d], 1);
  }
  __syncthreads();
  loc[t] = cnt[t];
  __syncthreads();
  for (int off = 1; off < 256; off <<= 1) {
    int v = (t >= off) ? loc[t - off] : 0;
    __syncthreads();
    loc[t] += v;
    __syncthreads();
  }
  int excl = loc[t] - cnt[t];
  int node = nbase + t;
  if (node < NN) {
    row_start[node] = e0 + excl;
    inv_deg[node] = 1.0f / (float)(cnt[t] > 1 ? cnt[t] : 1);
  }
  cur[t] = excl;
  if (b == NBUCK - 1 && t == 0) row_start[NN] = NE;
  __syncthreads();
  for (int e = e0 + t; e < e1; e += 256) {
    unsigned pr = pairs[e];
    int d = (int)(pr >> 24);
    int p = atomicAdd(&cur[d], 1);
    nbr[e0 + p] = (int)(pr & 0xFFFFFFu);
  }
}

// ---------------- mean aggregation: fp8 in (128B rows), f16 out; 8 lanes/node ----------------
__global__ __launch_bounds__(256) void agg_kernel(const unsigned char* __restrict__ X8,
                                                  _Float16* __restrict__ out,
                                                  const int* __restrict__ row_start,
                                                  const int* __restrict__ nbr,
                                                  const float* __restrict__ inv_deg) {
  int g = blockIdx.x * 32 + (threadIdx.x >> 3);
  int ln = threadIdx.x & 7;
  if (g >= NN) return;
  int p0 = row_start[g];
  int p1 = row_start[g + 1];
  const uint4* base = (const uint4*)X8;  // row = 8 uint4 (128 B)
  float a[16];
#pragma unroll
  for (int i = 0; i < 16; ++i) a[i] = 0.f;
  int p = p0;
  for (; p + 3 < p1; p += 4) {
    int s0 = nbr[p], s1 = nbr[p + 1], s2 = nbr[p + 2], s3 = nbr[p + 3];
    uint4 v0 = base[(size_t)s0 * 8 + ln];
    uint4 v1 = base[(size_t)s1 * 8 + ln];
    uint4 v2 = base[(size_t)s2 * 8 + ln];
    uint4 v3 = base[(size_t)s3 * 8 + ln];
    ACCR(v0) ACCR(v1) ACCR(v2) ACCR(v3)
  }
  for (; p < p1; ++p) {
    uint4 v = base[(size_t)nbr[p] * 8 + ln];
    ACCR(v)
  }
  float id = inv_deg[g];
  uint4 o0, o1;
  o0.x = packh(a[0] * id, a[1] * id);
  o0.y = packh(a[2] * id, a[3] * id);
  o0.z = packh(a[4] * id, a[5] * id);
  o0.w = packh(a[6] * id, a[7] * id);
  o1.x = packh(a[8] * id, a[9] * id);
  o1.y = packh(a[10] * id, a[11] * id);
  o1.z = packh(a[12] * id, a[13] * id);
  o1.w = packh(a[14] * id, a[15] * id);
  uint4* ob = (uint4*)out;
  ob[(size_t)g * 16 + ln * 2] = o0;
  ob[(size_t)g * 16 + ln * 2 + 1] = o1;
}

// ---------------- weight prep: fragment-ordered f16 planes ----------------
__global__ __launch_bounds__(64) void prep_w_kernel(const float* __restrict__ Wl,
                                                    const float* __restrict__ Wr,
                                                    half8v* __restrict__ P) {
  int s = blockIdx.x >> 3;
  int n = blockIdx.x & 7;
  int l = threadIdx.x;
  int k0 = s * 32 + (l >> 4) * 8;
  int c = n * 16 + (l & 15);
  const float* W = (k0 < 128) ? Wl : Wr;
  int kb = (k0 < 128) ? k0 : k0 - 128;
  half8v h;
#pragma unroll
  for (int i = 0; i < 8; ++i) h[i] = (_Float16)W[c * 128 + kb + i];
  P[blockIdx.x * 64 + l] = h;
}

// layer 2: cols 0..39 = Wl2 rows, 40..79 = Wr2 rows (K=128)
__global__ __launch_bounds__(64) void prep_wy2_kernel(const float* __restrict__ Wl,
                                                      const float* __restrict__ Wr,
                                                      half8v* __restrict__ P) {
  int s = blockIdx.x / 5;
  int n = blockIdx.x % 5;
  int l = threadIdx.x;
  int k0 = s * 32 + (l >> 4) * 8;
  int c = n * 16 + (l & 15);  // 0..79
  const float* W = (c < DOUT) ? Wl : Wr;
  int row = (c < DOUT) ? c : c - DOUT;
  half8v h;
#pragma unroll
  for (int i = 0; i < 8; ++i) h[i] = (_Float16)W[row * 128 + k0 + i];
  P[blockIdx.x * 64 + l] = h;
}

// ---------------- layers 0/1: out = relu([A|H] @ Bcat + b); single-barrier full staging ----------------
__global__ __launch_bounds__(256) void mfma_gemm_kernel(
    const _Float16* __restrict__ A, const _Float16* __restrict__ H,
    const half8v* __restrict__ B, const float* __restrict__ bias,
    _Float16* __restrict__ out, unsigned char* __restrict__ out8) {
  __shared__ _Float16 AH[2][128][LSTR];  // 2 x 34KB

  int t = threadIdx.x;
  int w = t >> 6, l = t & 63;
  int R0 = blockIdx.x * 128;
  int lc = l & 15;
  int lg = l >> 4;

  // stage full A and H tiles (128 rows x 128 f16 each) with linear coalesced uint4s
#pragma unroll
  for (int i = 0; i < 8; ++i) {
    int u = t + 256 * i;          // uint4 index in [0,2048)
    int row = u >> 4, seg = u & 15;
    int gr = R0 + row;
    uint4 va = make_uint4(0, 0, 0, 0), vh = va;
    if (gr < NN) {
      va = *(const uint4*)(A + (size_t)gr * D + seg * 8);
      vh = *(const uint4*)(H + (size_t)gr * D + seg * 8);
    }
    *(uint4*)&AH[0][row][seg * 8] = va;
    *(uint4*)&AH[1][row][seg * 8] = vh;
  }
  __syncthreads();

  f32x4 acc[2][8];
#pragma unroll
  for (int m = 0; m < 2; ++m)
#pragma unroll
    for (int n = 0; n < 8; ++n) acc[m][n] = (f32x4){0.f, 0.f, 0.f, 0.f};

#pragma unroll
  for (int s = 0; s < 8; ++s) {
    int half = s >> 2;
    int koff = (s & 3) * 32;
    half8v bh[8];
#pragma unroll
    for (int n = 0; n < 8; ++n) bh[n] = B[(s * 8 + n) * 64 + l];
    half8v ah[2];
#pragma unroll
    for (int m = 0; m < 2; ++m) {
      int r = w * 32 + m * 16 + lc;
      ah[m] = *(const half8v*)&AH[half][r][koff + lg * 8];
    }
#pragma unroll
    for (int n = 0; n < 8; ++n)
#pragma unroll
      for (int m = 0; m < 2; ++m)
        acc[m][n] = __builtin_amdgcn_mfma_f32_16x16x32_f16(ah[m], bh[n], acc[m][n], 0, 0, 0);
  }

  float bcol[8];
#pragma unroll
  for (int n = 0; n < 8; ++n) bcol[n] = bias[n * 16 + lc];
#pragma unroll
  for (int m = 0; m < 2; ++m)
#pragma unroll
    for (int n = 0; n < 8; ++n) {
      int col = n * 16 + lc;
#pragma unroll
      for (int j = 0; j < 4; ++j) {
        int gr = R0 + w * 32 + m * 16 + lg * 4 + j;
        if (gr < NN) {
          float v = fmaxf(acc[m][n][j] + bcol[n], 0.f);
          out[(size_t)gr * D + col] = (_Float16)v;
          if (out8) out8[(size_t)gr * D + col] = f2fp8(v);
        }
      }
    }
}

// ---------------- layer 2 GEMM: y = h2 @ [Wl2|Wr2]^T; yl fp8 N x 48 (pad 0), yr f32 N x 40 (+b2) ----------------
__global__ __launch_bounds__(256) void mfma_y2_kernel(
    const _Float16* __restrict__ H, const half8v* __restrict__ B,
    const float* __restrict__ b2,
    unsigned char* __restrict__ yl8, float* __restrict__ yr) {
  __shared__ _Float16 Hs[128][LSTR];  // 34KB

  int t = threadIdx.x;
  int w = t >> 6, l = t & 63;
  int R0 = blockIdx.x * 128;
  int lc = l & 15;
  int lg = l >> 4;

  // stage full H tile: 128 rows x 128 f16 = 2048 uint4, 8 per thread
#pragma unroll
  for (int i = 0; i < 8; ++i) {
    int u = t + 256 * i;          // uint4 index in [0,2048)
    int row = u >> 4, seg = u & 15;
    int gr = R0 + row;
    uint4 v = make_uint4(0, 0, 0, 0);
    if (gr < NN) v = *(const uint4*)(H + (size_t)gr * D + seg * 8);
    *(uint4*)&Hs[row][seg * 8] = v;
  }
  __syncthreads();

  f32x4 acc[2][5];
#pragma unroll
  for (int m = 0; m < 2; ++m)
#pragma unroll
    for (int n = 0; n < 5; ++n) acc[m][n] = (f32x4){0.f, 0.f, 0.f, 0.f};

#pragma unroll
  for (int s = 0; s < 4; ++s) {
    int koff = s * 32;
    half8v bh[5];
#pragma unroll
    for (int n = 0; n < 5; ++n) bh[n] = B[(s * 5 + n) * 64 + l];
    half8v ah[2];
#pragma unroll
    for (int m = 0; m < 2; ++m) {
      int r = w * 32 + m * 16 + lc;
      ah[m] = *(const half8v*)&Hs[r][koff + lg * 8];
    }
#pragma unroll
    for (int n = 0; n < 5; ++n)
#pragma unroll
      for (int m = 0; m < 2; ++m)
        acc[m][n] = __builtin_amdgcn_mfma_f32_16x16x32_f16(ah[m], bh[n], acc[m][n], 0, 0, 0);
  }

#pragma unroll
  for (int m = 0; m < 2; ++m)
#pragma unroll
    for (int n = 0; n < 5; ++n) {
      int col = n * 16 + lc;
#pragma unroll
      for (int j = 0; j < 4; ++j) {
        int gr = R0 + w * 32 + m * 16 + lg * 4 + j;
        if (gr < NN) {
          float v = acc[m][n][j];
          if (col < DOUT) {
            yl8[(size_t)gr * 48 + col] = f2fp8(v);
          } else {
            if (col < 48) yl8[(size_t)gr * 48 + col] = 0;  // pad
            yr[(size_t)gr * DOUT + (col - DOUT)] = v + b2[col - DOUT];
          }
        }
      }
    }
}

// ---------------- fused layer-2 agg + log_softmax: fp8 48B rows, 8 lanes/node ----------------
__global__ __launch_bounds__(256) void agg_out_kernel(const unsigned char* __restrict__ yl8,
                                                      const float* __restrict__ yr,
                                                      const int* __restrict__ row_start,
                                                      const int* __restrict__ nbr,
                                                      const float* __restrict__ inv_deg,
                                                      float* __restrict__ out) {
  int g = blockIdx.x * 32 + (threadIdx.x >> 3);
  int ln = threadIdx.x & 7;
  if (g >= NN) return;
  int lnc = (ln < 6) ? ln : 5;  // lanes 6,7 duplicate lane 5 (harmless)
  int p0 = row_start[g];
  int p1 = row_start[g + 1];
  const uint2* base = (const uint2*)yl8;  // row = 6 uint2 (48 B)
  float a[8];
#pragma unroll
  for (int i = 0; i < 8; ++i) a[i] = 0.f;
  int p = p0;
  for (; p + 3 < p1; p += 4) {
    int s0 = nbr[p], s1 = nbr[p + 1], s2 = nbr[p + 2], s3 = nbr[p + 3];
    uint2 v0 = base[(size_t)s0 * 6 + lnc];
    uint2 v1 = base[(size_t)s1 * 6 + lnc];
    uint2 v2 = base[(size_t)s2 * 6 + lnc];
    uint2 v3 = base[(size_t)s3 * 6 + lnc];
    ACCR8(v0) ACCR8(v1) ACCR8(v2) ACCR8(v3)
  }
  for (; p < p1; ++p) {
    uint2 v = base[(size_t)nbr[p] * 6 + lnc];
    ACCR8(v)
  }
  float id = inv_deg[g];
  float z[8];
#pragma unroll
  for (int i = 0; i < 8; ++i) z[i] = a[i] * id;
  bool valid = (ln < 5);  // lanes 0..4 own cols ln*8..ln*8+7 (40 total)
  if (valid) {
    float4 r0 = *(const float4*)(yr + (size_t)g * DOUT + ln * 8);
    float4 r1 = *(const float4*)(yr + (size_t)g * DOUT + ln * 8 + 4);
    z[0] += r0.x; z[1] += r0.y; z[2] += r0.z; z[3] += r0.w;
    z[4] += r1.x; z[5] += r1.y; z[6] += r1.z; z[7] += r1.w;
  }
  float zm = -INFINITY;
  if (valid)
#pragma unroll
    for (int i = 0; i < 8; ++i) zm = fmaxf(zm, z[i]);
#pragma unroll
  for (int off = 1; off < 8; off <<= 1) zm = fmaxf(zm, __shfl_xor(zm, off, 8));
  float ssum = 0.f;
  if (valid)
#pragma unroll
    for (int i = 0; i < 8; ++i) ssum += expf(z[i] - zm);
#pragma unroll
  for (int off = 1; off < 8; off <<= 1) ssum += __shfl_xor(ssum, off, 8);
  float lse = zm + logf(ssum);
  if (valid) {
    float4 o0 = make_float4(z[0] - lse, z[1] - lse, z[2] - lse, z[3] - lse);
    float4 o1 = make_float4(z[4] - lse, z[5] - lse, z[6] - lse, z[7] - lse);
    *(float4*)(out + (size_t)g * DOUT + ln * 8) = o0;
    *(float4*)(out + (size_t)g * DOUT + ln * 8 + 4) = o1;
  }
}

// ---------------- launch ----------------
extern "C" void kernel_launch(void* const* d_in, const int* in_sizes, int n_in,
                              void* d_out, int out_size, void* d_ws, size_t ws_size,
                              hipStream_t stream) {
  const float* x   = (const float*)d_in[0];
  const int* esrc  = (const int*)d_in[1];
  const int* edst  = (const int*)d_in[2];
  const float* Wl0 = (const float*)d_in[3];
  const float* Wr0 = (const float*)d_in[4];
  const float* b0  = (const float*)d_in[5];
  const float* Wl1 = (const float*)d_in[6];
  const float* Wr1 = (const float*)d_in[7];
  const float* b1  = (const float*)d_in[8];
  const float* Wl2 = (const float*)d_in[9];
  const float* Wr2 = (const float*)d_in[10];
  const float* b2  = (const float*)d_in[11];
  float* out = (float*)d_out;

  char* ws = (char*)d_ws;
  size_t off = 0;
  auto carve = [&](size_t bytes) -> char* {
    char* p = ws + off;
    off = (off + bytes + 255) & ~(size_t)255;
    return p;
  };
  int* bucket_cnt    = (int*)carve((size_t)NBUCK * 4);
  int* bucket_base   = (int*)carve((size_t)(NBUCK + 1) * 4);
  int* bucket_cursor = (int*)carve((size_t)NBUCK * 4);
  int* row_start     = (int*)carve((size_t)(NN + 1) * 4);
  int* nbr           = (int*)carve((size_t)NE * 4);
  float* inv_deg     = (float*)carve((size_t)NN * 4);
  unsigned* pairs    = (unsigned*)carve((size_t)NE * 4);
  half8v* B0         = (half8v*)carve((size_t)64 * 64 * 16);
  half8v* B1         = (half8v*)carve((size_t)64 * 64 * 16);
  half8v* By2        = (half8v*)carve((size_t)20 * 64 * 16);
  _Float16* xb   = (_Float16*)carve((size_t)NN * D * 2);
  unsigned char* x8    = (unsigned char*)carve((size_t)NN * D);
  _Float16* bufA = (_Float16*)carve((size_t)NN * D * 2);
  _Float16* bufB = (_Float16*)carve((size_t)NN * D * 2);
  unsigned char* bufB8 = (unsigned char*)carve((size_t)NN * D);
  _Float16* bufC = (_Float16*)carve((size_t)NN * D * 2);
  unsigned char* yl8   = (unsigned char*)carve((size_t)NN * 48);
  float* yr      = (float*)carve((size_t)NN * DOUT * 4);
  if (off > ws_size) return;

  const int GRID_AGG = (NN + 31) / 32;       // 3125
  const int GRID_GEMM = (NN + 127) / 128;    // 782
  const int GRID_CVT = NN * D / 8 / 256;     // 6250
  const int GRID_AO = (NN + 31) / 32;        // 3125

  // CSR build (bucketed)
  hipMemsetAsync(bucket_cnt, 0, (size_t)NBUCK * 4, stream);
  bucket_hist_kernel<<<NCHUNK, 256, 0, stream>>>(edst, bucket_cnt);
  bucket_scan_kernel<<<1, 512, 0, stream>>>(bucket_cnt, bucket_base, bucket_cursor);
  binned_scatter_kernel<<<NCHUNK, 256, 0, stream>>>(esrc, edst, bucket_cursor, pairs);
  bucket_build_kernel<<<NBUCK, 256, 0, stream>>>(pairs, bucket_base, row_start, nbr, inv_deg);

  // feature / weight prep
  cvt_kernel<<<GRID_CVT, 256, 0, stream>>>(x, xb, x8);
  prep_w_kernel<<<64, 64, 0, stream>>>(Wl0, Wr0, B0);
  prep_w_kernel<<<64, 64, 0, stream>>>(Wl1, Wr1, B1);
  prep_wy2_kernel<<<20, 64, 0, stream>>>(Wl2, Wr2, By2);

  // layer 0
  agg_kernel<<<GRID_AGG, 256, 0, stream>>>(x8, bufA, row_start, nbr, inv_deg);
  mfma_gemm_kernel<<<GRID_GEMM, 256, 0, stream>>>(bufA, xb, B0, b0, bufB, bufB8);
  // layer 1
  agg_kernel<<<GRID_AGG, 256, 0, stream>>>(bufB8, bufA, row_start, nbr, inv_deg);
  mfma_gemm_kernel<<<GRID_GEMM, 256, 0, stream>>>(bufA, bufB, B1, b1, bufC, nullptr);
  // layer 2: transform-then-aggregate (agg commutes with the linear map)
  mfma_y2_kernel<<<GRID_GEMM, 256, 0, stream>>>(bufC, By2, b2, yl8, yr);
  agg_out_kernel<<<GRID_AO, 256, 0, stream>>>(yl8, yr, row_start, nbr, inv_deg, out);
}

// Round 11
// 231.738 us; speedup vs baseline: 5.6232x; 1.1292x over previous
//
#include <hip/hip_runtime.h>
#include <hip/hip_fp16.h>
#include <math.h>

#define NN 100000
#define NE 1600000
#define D 128
#define DOUT 40
#define NBUCK 391          // ceil(NN/256): bucket = 256 consecutive nodes
#define CHUNK 4096         // edges per binning workgroup
#define NCHUNK 391         // ceil(NE/CHUNK)
#define LSTR 136           // LDS row stride in f16: 272B = 17*16B (aligned, 2-way max)

typedef _Float16 half8v __attribute__((ext_vector_type(8)));   // 8 f16 (4 VGPR)
typedef __attribute__((ext_vector_type(4))) float f32x4;

__device__ __forceinline__ unsigned packh(float a, float b) {
  return (unsigned)__half_as_ushort(__float2half_rn(a)) |
         ((unsigned)__half_as_ushort(__float2half_rn(b)) << 16);
}
// fp8 e4m3 (OCP) helpers — HW converts on gfx950
__device__ __forceinline__ unsigned char f2fp8(float v) {
  return (unsigned char)(__builtin_amdgcn_cvt_pk_fp8_f32(v, v, 0, 0) & 0xff);
}
#define CVT2(u, s) __builtin_amdgcn_cvt_pk_f32_fp8((int)(u), s)
// accumulate 16 fp8 (one uint4) into a[0..15]
#define ACCR(v) { auto q = CVT2((v).x, 0); a[0] += q[0]; a[1] += q[1];   \
  q = CVT2((v).x, 1); a[2] += q[0];  a[3] += q[1];                        \
  q = CVT2((v).y, 0); a[4] += q[0];  a[5] += q[1];                        \
  q = CVT2((v).y, 1); a[6] += q[0];  a[7] += q[1];                        \
  q = CVT2((v).z, 0); a[8] += q[0];  a[9] += q[1];                        \
  q = CVT2((v).z, 1); a[10] += q[0]; a[11] += q[1];                       \
  q = CVT2((v).w, 0); a[12] += q[0]; a[13] += q[1];                       \
  q = CVT2((v).w, 1); a[14] += q[0]; a[15] += q[1]; }
// accumulate 8 fp8 (one uint2) into a[0..7]
#define ACCR8(v) { auto q = CVT2((v).x, 0); a[0] += q[0]; a[1] += q[1];  \
  q = CVT2((v).x, 1); a[2] += q[0]; a[3] += q[1];                         \
  q = CVT2((v).y, 0); a[4] += q[0]; a[5] += q[1];                         \
  q = CVT2((v).y, 1); a[6] += q[0]; a[7] += q[1]; }

// ---------------- small zero ----------------
__global__ void zero_kernel(int* __restrict__ p, int n) {
  int i = blockIdx.x * 256 + threadIdx.x;
  if (i < n) p[i] = 0;
}

// ---------------- x -> f16 + fp8 ----------------
__global__ __launch_bounds__(256) void cvt_kernel(const float* __restrict__ in,
                                                  _Float16* __restrict__ outh,
                                                  unsigned char* __restrict__ out8) {
  int i = (blockIdx.x * 256 + threadIdx.x) * 8;
  float4 v0 = *(const float4*)(in + i);
  float4 v1 = *(const float4*)(in + i + 4);
  uint4 oh;
  oh.x = packh(v0.x, v0.y);
  oh.y = packh(v0.z, v0.w);
  oh.z = packh(v1.x, v1.y);
  oh.w = packh(v1.z, v1.w);
  *(uint4*)(outh + i) = oh;
  unsigned w0 = __builtin_amdgcn_cvt_pk_fp8_f32(v0.x, v0.y, 0, 0);
  w0 = __builtin_amdgcn_cvt_pk_fp8_f32(v0.z, v0.w, w0, 1);
  unsigned w1 = __builtin_amdgcn_cvt_pk_fp8_f32(v1.x, v1.y, 0, 0);
  w1 = __builtin_amdgcn_cvt_pk_fp8_f32(v1.z, v1.w, w1, 1);
  *(uint2*)(out8 + i) = make_uint2(w0, w1);
}

// ---------------- CSR build: bucketed ----------------
__global__ __launch_bounds__(256) void bucket_hist_kernel(const int* __restrict__ dst,
                                                          int* __restrict__ bucket_cnt) {
  __shared__ int bc[NBUCK];
  int t = threadIdx.x;
  for (int i = t; i < NBUCK; i += 256) bc[i] = 0;
  __syncthreads();
  int e_base = blockIdx.x * CHUNK;
#pragma unroll
  for (int j = 0; j < 16; ++j) {
    int e = e_base + j * 256 + t;
    if (e < NE) atomicAdd(&bc[dst[e] >> 8], 1);
  }
  __syncthreads();
  for (int i = t; i < NBUCK; i += 256)
    if (bc[i]) atomicAdd(&bucket_cnt[i], bc[i]);
}

__global__ __launch_bounds__(512) void bucket_scan_kernel(const int* __restrict__ bucket_cnt,
                                                          int* __restrict__ bucket_base,
                                                          int* __restrict__ bucket_cursor) {
  __shared__ int s[512];
  int t = threadIdx.x;
  int c = (t < NBUCK) ? bucket_cnt[t] : 0;
  s[t] = c;
  __syncthreads();
  for (int off = 1; off < 512; off <<= 1) {
    int v = (t >= off) ? s[t - off] : 0;
    __syncthreads();
    s[t] += v;
    __syncthreads();
  }
  if (t < NBUCK) {
    int b = s[t] - c;
    bucket_base[t] = b;
    bucket_cursor[t] = b;
  }
  if (t == NBUCK) bucket_base[NBUCK] = s[NBUCK - 1];
}

// chunk-local LDS reorder, then bucket-contiguous coalesced writes
// payload: word = (dst&255)<<24 | src   (src < 2^24)
__global__ __launch_bounds__(256) void binned_scatter_kernel(const int* __restrict__ src,
                                                             const int* __restrict__ dst,
                                                             int* __restrict__ bucket_cursor,
                                                             unsigned* __restrict__ pairs) {
  __shared__ int lcnt[NBUCK];
  __shared__ int lscan[NBUCK];
  __shared__ int gb[NBUCK];
  __shared__ unsigned ebuf[CHUNK];
  __shared__ unsigned short bbuf[CHUNK];
  int t = threadIdx.x;
  int e_base = blockIdx.x * CHUNK;
  for (int i = t; i < NBUCK; i += 256) lcnt[i] = 0;
  __syncthreads();

  int myb[16], myrank[16];
  unsigned mye[16];
#pragma unroll
  for (int j = 0; j < 16; ++j) {
    int e = e_base + j * 256 + t;
    if (e < NE) {
      int d = dst[e];
      mye[j] = (unsigned)src[e] | ((unsigned)(d & 255) << 24);
      myb[j] = d >> 8;
      myrank[j] = atomicAdd(&lcnt[d >> 8], 1);
    } else {
      myb[j] = -1;
    }
  }
  __syncthreads();

  lscan[t] = lcnt[t];
  if (256 + t < NBUCK) lscan[256 + t] = lcnt[256 + t];
  __syncthreads();
  for (int off = 1; off < 512; off <<= 1) {
    int v0 = (t >= off) ? lscan[t - off] : 0;
    int v1 = 0;
    int i1 = 256 + t;
    if (i1 < NBUCK) v1 = lscan[i1 - off];
    __syncthreads();
    if (t >= off) lscan[t] += v0;
    if (i1 < NBUCK) lscan[i1] += v1;
    __syncthreads();
  }

#pragma unroll
  for (int j = 0; j < 16; ++j)
    if (myb[j] >= 0) {
      int b = myb[j];
      int lpos = lscan[b] - lcnt[b] + myrank[j];
      ebuf[lpos] = mye[j];
      bbuf[lpos] = (unsigned short)b;
    }
  for (int i = t; i < NBUCK; i += 256)
    if (lcnt[i] > 0) gb[i] = atomicAdd(&bucket_cursor[i], lcnt[i]);
  __syncthreads();

  int chunk_n = min(CHUNK, NE - e_base);
  for (int s2 = t; s2 < chunk_n; s2 += 256) {
    int b = bbuf[s2];
    int g = gb[b] + (s2 - (lscan[b] - lcnt[b]));
    pairs[g] = ebuf[s2];
  }
}

// one workgroup per bucket: per-node count, local scan -> row_start, fine scatter
__global__ __launch_bounds__(256) void bucket_build_kernel(const unsigned* __restrict__ pairs,
                                                           const int* __restrict__ bucket_base,
                                                           int* __restrict__ row_start,
                                                           int* __restrict__ nbr,
                                                           float* __restrict__ inv_deg) {
  __shared__ int cnt[256], loc[256], cur[256];
  int b = blockIdx.x;
  int t = threadIdx.x;
  int nbase = b << 8;
  int e0 = bucket_base[b], e1 = bucket_base[b + 1];
  cnt[t] = 0;
  __syncthreads();
  for (int e = e0 + t; e < e1; e += 256) {
    int d = (int)(pairs[e] >> 24);
    atomicAdd(&cnt[d], 1);
  }
  __syncthreads();
  loc[t] = cnt[t];
  __syncthreads();
  for (int off = 1; off < 256; off <<= 1) {
    int v = (t >= off) ? loc[t - off] : 0;
    __syncthreads();
    loc[t] += v;
    __syncthreads();
  }
  int excl = loc[t] - cnt[t];
  int node = nbase + t;
  if (node < NN) {
    row_start[node] = e0 + excl;
    inv_deg[node] = 1.0f / (float)(cnt[t] > 1 ? cnt[t] : 1);
  }
  cur[t] = excl;
  if (b == NBUCK - 1 && t == 0) row_start[NN] = NE;
  __syncthreads();
  for (int e = e0 + t; e < e1; e += 256) {
    unsigned pr = pairs[e];
    int d = (int)(pr >> 24);
    int p = atomicAdd(&cur[d], 1);
    nbr[e0 + p] = (int)(pr & 0xFFFFFFu);
  }
}

// ---------------- mean aggregation: fp8 in (128B rows), f16 out; 8 lanes/node ----------------
__global__ __launch_bounds__(256) void agg_kernel(const unsigned char* __restrict__ X8,
                                                  _Float16* __restrict__ out,
                                                  const int* __restrict__ row_start,
                                                  const int* __restrict__ nbr,
                                                  const float* __restrict__ inv_deg) {
  int g = blockIdx.x * 32 + (threadIdx.x >> 3);
  int ln = threadIdx.x & 7;
  if (g >= NN) return;
  int p0 = row_start[g];
  int p1 = row_start[g + 1];
  const uint4* base = (const uint4*)X8;  // row = 8 uint4 (128 B)
  float a[16];
#pragma unroll
  for (int i = 0; i < 16; ++i) a[i] = 0.f;
  int p = p0;
  for (; p + 3 < p1; p += 4) {
    int s0 = nbr[p], s1 = nbr[p + 1], s2 = nbr[p + 2], s3 = nbr[p + 3];
    uint4 v0 = base[(size_t)s0 * 8 + ln];
    uint4 v1 = base[(size_t)s1 * 8 + ln];
    uint4 v2 = base[(size_t)s2 * 8 + ln];
    uint4 v3 = base[(size_t)s3 * 8 + ln];
    ACCR(v0) ACCR(v1) ACCR(v2) ACCR(v3)
  }
  for (; p < p1; ++p) {
    uint4 v = base[(size_t)nbr[p] * 8 + ln];
    ACCR(v)
  }
  float id = inv_deg[g];
  uint4 o0, o1;
  o0.x = packh(a[0] * id, a[1] * id);
  o0.y = packh(a[2] * id, a[3] * id);
  o0.z = packh(a[4] * id, a[5] * id);
  o0.w = packh(a[6] * id, a[7] * id);
  o1.x = packh(a[8] * id, a[9] * id);
  o1.y = packh(a[10] * id, a[11] * id);
  o1.z = packh(a[12] * id, a[13] * id);
  o1.w = packh(a[14] * id, a[15] * id);
  uint4* ob = (uint4*)out;
  ob[(size_t)g * 16 + ln * 2] = o0;
  ob[(size_t)g * 16 + ln * 2 + 1] = o1;
}

// ---------------- weight prep: fragment-ordered f16 planes ----------------
__global__ __launch_bounds__(64) void prep_w_kernel(const float* __restrict__ Wl,
                                                    const float* __restrict__ Wr,
                                                    half8v* __restrict__ P) {
  int s = blockIdx.x >> 3;
  int n = blockIdx.x & 7;
  int l = threadIdx.x;
  int k0 = s * 32 + (l >> 4) * 8;
  int c = n * 16 + (l & 15);
  const float* W = (k0 < 128) ? Wl : Wr;
  int kb = (k0 < 128) ? k0 : k0 - 128;
  half8v h;
#pragma unroll
  for (int i = 0; i < 8; ++i) h[i] = (_Float16)W[c * 128 + kb + i];
  P[blockIdx.x * 64 + l] = h;
}

// layer 2: cols 0..39 = Wl2 rows, 40..79 = Wr2 rows (K=128)
__global__ __launch_bounds__(64) void prep_wy2_kernel(const float* __restrict__ Wl,
                                                      const float* __restrict__ Wr,
                                                      half8v* __restrict__ P) {
  int s = blockIdx.x / 5;
  int n = blockIdx.x % 5;
  int l = threadIdx.x;
  int k0 = s * 32 + (l >> 4) * 8;
  int c = n * 16 + (l & 15);  // 0..79
  const float* W = (c < DOUT) ? Wl : Wr;
  int row = (c < DOUT) ? c : c - DOUT;
  half8v h;
#pragma unroll
  for (int i = 0; i < 8; ++i) h[i] = (_Float16)W[row * 128 + k0 + i];
  P[blockIdx.x * 64 + l] = h;
}

// ---------------- layers 0/1: out = relu([A|H] @ Bcat + b) ----------------
// LDS-free operand loads (A rows have no cross-wave reuse); LDS used only to
// transpose the output tile for coalesced stores.
__global__ __launch_bounds__(256) void mfma_gemm_kernel(
    const _Float16* __restrict__ A, const _Float16* __restrict__ H,
    const half8v* __restrict__ B, const float* __restrict__ bias,
    _Float16* __restrict__ out, unsigned char* __restrict__ out8) {
  __shared__ _Float16 Os[128][LSTR];  // 34.8KB output transpose buffer

  int t = threadIdx.x;
  int w = t >> 6, l = t & 63;
  int R0 = blockIdx.x * 128;
  int lc = l & 15;
  int lg = l >> 4;

  // A-fragment row for this lane (clamped: rows >= NN produce discarded outputs)
  int frow = R0 + w * 32 + lc;           // + m*16
  int fr0 = min(frow, NN - 1);
  int fr1 = min(frow + 16, NN - 1);

  f32x4 acc[2][8];
#pragma unroll
  for (int m = 0; m < 2; ++m)
#pragma unroll
    for (int n = 0; n < 8; ++n) acc[m][n] = (f32x4){0.f, 0.f, 0.f, 0.f};

#pragma unroll
  for (int s = 0; s < 8; ++s) {
    const _Float16* src = (s < 4) ? A : H;
    int koff = (s & 3) * 32 + lg * 8;
    half8v ah0 = *(const half8v*)(src + (size_t)fr0 * D + koff);
    half8v ah1 = *(const half8v*)(src + (size_t)fr1 * D + koff);
    half8v bh[8];
#pragma unroll
    for (int n = 0; n < 8; ++n) bh[n] = B[(s * 8 + n) * 64 + l];
#pragma unroll
    for (int n = 0; n < 8; ++n) {
      acc[0][n] = __builtin_amdgcn_mfma_f32_16x16x32_f16(ah0, bh[n], acc[0][n], 0, 0, 0);
      acc[1][n] = __builtin_amdgcn_mfma_f32_16x16x32_f16(ah1, bh[n], acc[1][n], 0, 0, 0);
    }
  }

  // scatter into LDS (f16), then coalesced global stores
  float bcol[8];
#pragma unroll
  for (int n = 0; n < 8; ++n) bcol[n] = bias[n * 16 + lc];
#pragma unroll
  for (int m = 0; m < 2; ++m)
#pragma unroll
    for (int n = 0; n < 8; ++n) {
      int col = n * 16 + lc;
#pragma unroll
      for (int j = 0; j < 4; ++j) {
        int row = w * 32 + m * 16 + lg * 4 + j;
        Os[row][col] = (_Float16)fmaxf(acc[m][n][j] + bcol[n], 0.f);
      }
    }
  __syncthreads();

#pragma unroll
  for (int i = 0; i < 8; ++i) {
    int u = t + 256 * i;          // uint4 index in [0,2048)
    int row = u >> 4, seg = u & 15;
    int gr = R0 + row;
    if (gr < NN) {
      uint4 v = *(const uint4*)&Os[row][seg * 8];
      *(uint4*)(out + (size_t)gr * D + seg * 8) = v;
      if (out8) {
        unsigned w0 = __builtin_amdgcn_cvt_pk_fp8_f32(
            __half2float(__ushort_as_half((unsigned short)(v.x & 0xffff))),
            __half2float(__ushort_as_half((unsigned short)(v.x >> 16))), 0, 0);
        w0 = __builtin_amdgcn_cvt_pk_fp8_f32(
            __half2float(__ushort_as_half((unsigned short)(v.y & 0xffff))),
            __half2float(__ushort_as_half((unsigned short)(v.y >> 16))), w0, 1);
        unsigned w1 = __builtin_amdgcn_cvt_pk_fp8_f32(
            __half2float(__ushort_as_half((unsigned short)(v.z & 0xffff))),
            __half2float(__ushort_as_half((unsigned short)(v.z >> 16))), 0, 0);
        w1 = __builtin_amdgcn_cvt_pk_fp8_f32(
            __half2float(__ushort_as_half((unsigned short)(v.w & 0xffff))),
            __half2float(__ushort_as_half((unsigned short)(v.w >> 16))), w1, 1);
        *(uint2*)(out8 + (size_t)gr * D + seg * 8) = make_uint2(w0, w1);
      }
    }
  }
}

// ---------------- layer 2 GEMM: y = h2 @ [Wl2|Wr2]^T; yl fp8 N x 48 (pad 0), yr f32 N x 40 (+b2) ----------------
__global__ __launch_bounds__(256) void mfma_y2_kernel(
    const _Float16* __restrict__ H, const half8v* __restrict__ B,
    const float* __restrict__ b2,
    unsigned char* __restrict__ yl8, float* __restrict__ yr) {
  __shared__ unsigned char Y8[128][48];  // 6KB
  __shared__ float Yr[128][40];          // 20KB

  int t = threadIdx.x;
  int w = t >> 6, l = t & 63;
  int R0 = blockIdx.x * 128;
  int lc = l & 15;
  int lg = l >> 4;

  int frow = R0 + w * 32 + lc;
  int fr0 = min(frow, NN - 1);
  int fr1 = min(frow + 16, NN - 1);

  f32x4 acc[2][5];
#pragma unroll
  for (int m = 0; m < 2; ++m)
#pragma unroll
    for (int n = 0; n < 5; ++n) acc[m][n] = (f32x4){0.f, 0.f, 0.f, 0.f};

#pragma unroll
  for (int s = 0; s < 4; ++s) {
    int koff = s * 32 + lg * 8;
    half8v ah0 = *(const half8v*)(H + (size_t)fr0 * D + koff);
    half8v ah1 = *(const half8v*)(H + (size_t)fr1 * D + koff);
    half8v bh[5];
#pragma unroll
    for (int n = 0; n < 5; ++n) bh[n] = B[(s * 5 + n) * 64 + l];
#pragma unroll
    for (int n = 0; n < 5; ++n) {
      acc[0][n] = __builtin_amdgcn_mfma_f32_16x16x32_f16(ah0, bh[n], acc[0][n], 0, 0, 0);
      acc[1][n] = __builtin_amdgcn_mfma_f32_16x16x32_f16(ah1, bh[n], acc[1][n], 0, 0, 0);
    }
  }

  // scatter into LDS: cols 0..39 (Wl half) -> Y8 (fp8, aggregated later);
  // cols 40..79 (Wr half) -> Yr (+bias, root term)
#pragma unroll
  for (int m = 0; m < 2; ++m)
#pragma unroll
    for (int n = 0; n < 5; ++n) {
      int col = n * 16 + lc;
#pragma unroll
      for (int j = 0; j < 4; ++j) {
        int row = w * 32 + m * 16 + lg * 4 + j;
        float v = acc[m][n][j];
        if (col < DOUT) {
          Y8[row][col] = f2fp8(v);
        } else {
          Yr[row][col - DOUT] = v + b2[col - DOUT];
        }
      }
    }
  // zero pad cols 40..47 of Y8 (threads 0..127, one row each)
  if (t < 128) *(uint2*)&Y8[t][40] = make_uint2(0, 0);
  __syncthreads();

  // coalesced stores: yl8 = 768 uint2 (6 per row), yr = 1280 float4 (10 per row)
#pragma unroll
  for (int i = 0; i < 3; ++i) {
    int u = t + 256 * i;          // [0,768)
    int row = u / 6, seg = u % 6;
    int gr = R0 + row;
    if (gr < NN) *(uint2*)(yl8 + (size_t)gr * 48 + seg * 8) = *(const uint2*)&Y8[row][seg * 8];
  }
#pragma unroll
  for (int i = 0; i < 5; ++i) {
    int u = t + 256 * i;          // [0,1280)
    int row = u / 10, seg = u % 10;
    int gr = R0 + row;
    if (gr < NN) *(float4*)(yr + (size_t)gr * DOUT + seg * 4) = *(const float4*)&Yr[row][seg * 4];
  }
}

// ---------------- fused layer-2 agg + log_softmax: fp8 48B rows, 8 lanes/node ----------------
__global__ __launch_bounds__(256) void agg_out_kernel(const unsigned char* __restrict__ yl8,
                                                      const float* __restrict__ yr,
                                                      const int* __restrict__ row_start,
                                                      const int* __restrict__ nbr,
                                                      const float* __restrict__ inv_deg,
                                                      float* __restrict__ out) {
  int g = blockIdx.x * 32 + (threadIdx.x >> 3);
  int ln = threadIdx.x & 7;
  if (g >= NN) return;
  int lnc = (ln < 6) ? ln : 5;  // lanes 6,7 duplicate lane 5 (harmless)
  int p0 = row_start[g];
  int p1 = row_start[g + 1];
  const uint2* base = (const uint2*)yl8;  // row = 6 uint2 (48 B)
  float a[8];
#pragma unroll
  for (int i = 0; i < 8; ++i) a[i] = 0.f;
  int p = p0;
  for (; p + 3 < p1; p += 4) {
    int s0 = nbr[p], s1 = nbr[p + 1], s2 = nbr[p + 2], s3 = nbr[p + 3];
    uint2 v0 = base[(size_t)s0 * 6 + lnc];
    uint2 v1 = base[(size_t)s1 * 6 + lnc];
    uint2 v2 = base[(size_t)s2 * 6 + lnc];
    uint2 v3 = base[(size_t)s3 * 6 + lnc];
    ACCR8(v0) ACCR8(v1) ACCR8(v2) ACCR8(v3)
  }
  for (; p < p1; ++p) {
    uint2 v = base[(size_t)nbr[p] * 6 + lnc];
    ACCR8(v)
  }
  float id = inv_deg[g];
  float z[8];
#pragma unroll
  for (int i = 0; i < 8; ++i) z[i] = a[i] * id;
  bool valid = (ln < 5);  // lanes 0..4 own cols ln*8..ln*8+7 (40 total)
  if (valid) {
    float4 r0 = *(const float4*)(yr + (size_t)g * DOUT + ln * 8);
    float4 r1 = *(const float4*)(yr + (size_t)g * DOUT + ln * 8 + 4);
    z[0] += r0.x; z[1] += r0.y; z[2] += r0.z; z[3] += r0.w;
    z[4] += r1.x; z[5] += r1.y; z[6] += r1.z; z[7] += r1.w;
  }
  float zm = -INFINITY;
  if (valid)
#pragma unroll
    for (int i = 0; i < 8; ++i) zm = fmaxf(zm, z[i]);
#pragma unroll
  for (int off = 1; off < 8; off <<= 1) zm = fmaxf(zm, __shfl_xor(zm, off, 8));
  float ssum = 0.f;
  if (valid)
#pragma unroll
    for (int i = 0; i < 8; ++i) ssum += expf(z[i] - zm);
#pragma unroll
  for (int off = 1; off < 8; off <<= 1) ssum += __shfl_xor(ssum, off, 8);
  float lse = zm + logf(ssum);
  if (valid) {
    float4 o0 = make_float4(z[0] - lse, z[1] - lse, z[2] - lse, z[3] - lse);
    float4 o1 = make_float4(z[4] - lse, z[5] - lse, z[6] - lse, z[7] - lse);
    *(float4*)(out + (size_t)g * DOUT + ln * 8) = o0;
    *(float4*)(out + (size_t)g * DOUT + ln * 8 + 4) = o1;
  }
}

// ---------------- launch ----------------
extern "C" void kernel_launch(void* const* d_in, const int* in_sizes, int n_in,
                              void* d_out, int out_size, void* d_ws, size_t ws_size,
                              hipStream_t stream) {
  const float* x   = (const float*)d_in[0];
  const int* esrc  = (const int*)d_in[1];
  const int* edst  = (const int*)d_in[2];
  const float* Wl0 = (const float*)d_in[3];
  const float* Wr0 = (const float*)d_in[4];
  const float* b0  = (const float*)d_in[5];
  const float* Wl1 = (const float*)d_in[6];
  const float* Wr1 = (const float*)d_in[7];
  const float* b1  = (const float*)d_in[8];
  const float* Wl2 = (const float*)d_in[9];
  const float* Wr2 = (const float*)d_in[10];
  const float* b2  = (const float*)d_in[11];
  float* out = (float*)d_out;

  char* ws = (char*)d_ws;
  size_t off = 0;
  auto carve = [&](size_t bytes) -> char* {
    char* p = ws + off;
    off = (off + bytes + 255) & ~(size_t)255;
    return p;
  };
  int* bucket_cnt    = (int*)carve((size_t)NBUCK * 4);
  int* bucket_base   = (int*)carve((size_t)(NBUCK + 1) * 4);
  int* bucket_cursor = (int*)carve((size_t)NBUCK * 4);
  int* row_start     = (int*)carve((size_t)(NN + 1) * 4);
  int* nbr           = (int*)carve((size_t)NE * 4);
  float* inv_deg     = (float*)carve((size_t)NN * 4);
  unsigned* pairs    = (unsigned*)carve((size_t)NE * 4);
  half8v* B0         = (half8v*)carve((size_t)64 * 64 * 16);
  half8v* B1         = (half8v*)carve((size_t)64 * 64 * 16);
  half8v* By2        = (half8v*)carve((size_t)20 * 64 * 16);
  _Float16* xb   = (_Float16*)carve((size_t)NN * D * 2);
  unsigned char* x8    = (unsigned char*)carve((size_t)NN * D);
  _Float16* bufA = (_Float16*)carve((size_t)NN * D * 2);
  _Float16* bufB = (_Float16*)carve((size_t)NN * D * 2);
  unsigned char* bufB8 = (unsigned char*)carve((size_t)NN * D);
  _Float16* bufC = (_Float16*)carve((size_t)NN * D * 2);
  unsigned char* yl8   = (unsigned char*)carve((size_t)NN * 48);
  float* yr      = (float*)carve((size_t)NN * DOUT * 4);
  if (off > ws_size) return;

  const int GRID_AGG = (NN + 31) / 32;       // 3125
  const int GRID_GEMM = (NN + 127) / 128;    // 782
  const int GRID_CVT = NN * D / 8 / 256;     // 6250
  const int GRID_AO = (NN + 31) / 32;        // 3125

  // CSR build (bucketed)
  zero_kernel<<<2, 256, 0, stream>>>(bucket_cnt, NBUCK);
  bucket_hist_kernel<<<NCHUNK, 256, 0, stream>>>(edst, bucket_cnt);
  bucket_scan_kernel<<<1, 512, 0, stream>>>(bucket_cnt, bucket_base, bucket_cursor);
  binned_scatter_kernel<<<NCHUNK, 256, 0, stream>>>(esrc, edst, bucket_cursor, pairs);
  bucket_build_kernel<<<NBUCK, 256, 0, stream>>>(pairs, bucket_base, row_start, nbr, inv_deg);

  // feature / weight prep
  cvt_kernel<<<GRID_CVT, 256, 0, stream>>>(x, xb, x8);
  prep_w_kernel<<<64, 64, 0, stream>>>(Wl0, Wr0, B0);
  prep_w_kernel<<<64, 64, 0, stream>>>(Wl1, Wr1, B1);
  prep_wy2_kernel<<<20, 64, 0, stream>>>(Wl2, Wr2, By2);

  // layer 0
  agg_kernel<<<GRID_AGG, 256, 0, stream>>>(x8, bufA, row_start, nbr, inv_deg);
  mfma_gemm_kernel<<<GRID_GEMM, 256, 0, stream>>>(bufA, xb, B0, b0, bufB, bufB8);
  // layer 1
  agg_kernel<<<GRID_AGG, 256, 0, stream>>>(bufB8, bufA, row_start, nbr, inv_deg);
  mfma_gemm_kernel<<<GRID_GEMM, 256, 0, stream>>>(bufA, bufB, B1, b1, bufC, nullptr);
  // layer 2: transform-then-aggregate (agg commutes with the linear map)
  mfma_y2_kernel<<<GRID_GEMM, 256, 0, stream>>>(bufC, By2, b2, yl8, yr);
  agg_out_kernel<<<GRID_AO, 256, 0, stream>>>(yl8, yr, row_start, nbr, inv_deg, out);
}